// Round 1
// baseline (1502.162 us; speedup 1.0000x reference)
//
#include <hip/hip_runtime.h>
#include <hip/hip_bf16.h>

#define N_NODES 50000
#define N_EDGES 600000
#define TOT_EDGES (N_EDGES + N_NODES)
#define NPB 1000  // nodes per cond row (N/B)

__device__ __forceinline__ float gelu_exact(float v){
  return 0.5f * v * (1.f + erff(v * 0.70710678118654752f));
}
__device__ __forceinline__ float silu(float v){
  return v / (1.f + expf(-v));
}

// ---------------- CSR build ----------------
__global__ __launch_bounds__(256) void count_deg(const int* __restrict__ adj, int* __restrict__ counts){
  int j = blockIdx.x*256 + threadIdx.x;
  if (j >= TOT_EDGES) return;
  int d = (j < N_EDGES) ? adj[N_EDGES + j] : (j - N_EDGES);
  atomicAdd(&counts[d], 1);
}

__global__ __launch_bounds__(1024) void scan_kernel(const int* __restrict__ counts,
                                                    int* __restrict__ offsets,
                                                    int* __restrict__ cursor){
  const int tid = threadIdx.x;
  const int lane = tid & 63, wid = tid >> 6;
  __shared__ int wsum[16];
  __shared__ int carry_s;
  if (tid == 0) carry_s = 0;
  __syncthreads();
  for (int base = 0; base < N_NODES; base += 1024){
    int idx = base + tid;
    int v = (idx < N_NODES) ? counts[idx] : 0;
    int x = v;
    #pragma unroll
    for (int off = 1; off < 64; off <<= 1){
      int y = __shfl_up(x, off, 64);
      if (lane >= off) x += y;
    }
    if (lane == 63) wsum[wid] = x;
    __syncthreads();
    if (wid == 0){
      int s = (lane < 16) ? wsum[lane] : 0;
      #pragma unroll
      for (int off = 1; off < 16; off <<= 1){
        int y = __shfl_up(s, off, 64);
        if (lane >= off) s += y;
      }
      if (lane < 16) wsum[lane] = s;
    }
    __syncthreads();
    int wave_excl = wid ? wsum[wid-1] : 0;
    int excl = x - v + wave_excl + carry_s;
    if (idx < N_NODES){ offsets[idx] = excl; cursor[idx] = excl; }
    int total = wsum[15];
    __syncthreads();
    if (tid == 0) carry_s += total;
    __syncthreads();
  }
  if (tid == 0) offsets[N_NODES] = carry_s;
}

__global__ __launch_bounds__(256) void scatter_edges(const int* __restrict__ adj,
                                                     int* __restrict__ cursor,
                                                     int* __restrict__ srt_src){
  int j = blockIdx.x*256 + threadIdx.x;
  if (j >= TOT_EDGES) return;
  int s, d;
  if (j < N_EDGES){ s = adj[j]; d = adj[N_EDGES + j]; }
  else { s = j - N_EDGES; d = s; }
  int pos = atomicAdd(&cursor[d], 1);
  srt_src[pos] = s;
}

// ---------------- small precomputes ----------------
__global__ __launch_bounds__(128) void cond_proj_k(const float* __restrict__ cond,
                                                   const float* __restrict__ pcW,
                                                   const float* __restrict__ pcb,
                                                   float* __restrict__ cproj){
  int b = blockIdx.x, j = threadIdx.x;
  float acc = pcb[j];
  for (int k = 0; k < 32; k++) acc += cond[b*32+k]*pcW[k*128+j];
  cproj[b*128+j] = acc;
}

// u_l[k] = sum_j linW[l][k][j]*attS[l][j]  (and same with attD)
__global__ __launch_bounds__(128) void attvec_k(const float* __restrict__ linW,
                                                const float* __restrict__ attS,
                                                const float* __restrict__ attD,
                                                float* __restrict__ uv){
  int l = blockIdx.x >> 1, s = blockIdx.x & 1;
  const float* att = s ? (attD + l*128) : (attS + l*128);
  int k = threadIdx.x;
  const float* row = linW + (l*128 + k)*128;
  float acc = 0.f;
  for (int j = 0; j < 128; j++) acc += row[j]*att[j];
  uv[blockIdx.x*128 + k] = acc;
}

// ---------------- time embedding hidden: hid = silu(four @ tW1 + tb1) ----------------
__global__ __launch_bounds__(256) void temb_hidden(const float* __restrict__ timesteps,
                                                   const float* __restrict__ fw,
                                                   const float* __restrict__ tW1,
                                                   const float* __restrict__ tb1,
                                                   float* __restrict__ hid){
  __shared__ float sfour[32][17];
  __shared__ float sW[17][128];
  int tid = threadIdx.x;
  int row0 = blockIdx.x * 32;
  if (tid < 32){
    int gr = row0 + tid;
    float t = (gr < N_NODES) ? timesteps[gr] : 0.f;
    sfour[tid][0] = t;
    #pragma unroll
    for (int q = 0; q < 8; q++){
      float f = t * fw[q] * 6.2831853071795864769f;
      float sv, cv;
      sincosf(f, &sv, &cv);
      sfour[tid][1+q] = sv;
      sfour[tid][9+q] = cv;
    }
  }
  for (int i = tid; i < 17*128; i += 256) sW[i>>7][i&127] = tW1[i];
  __syncthreads();
  int j = tid & 127, rg = tid >> 7;
  float b = tb1[j];
  #pragma unroll
  for (int r = 0; r < 16; r++){
    int row = rg*16 + r;
    float acc = b;
    #pragma unroll
    for (int k = 0; k < 17; k++) acc += sfour[row][k]*sW[k][j];
    int gr = row0 + row;
    if (gr < N_NODES) hid[gr*128 + j] = silu(acc);
  }
}

// ---------------- h0 = hid@tW2 + tb2 + x@pxW + pxb + cproj[i/1000] ----------------
__global__ __launch_bounds__(256) void init_h(const float* __restrict__ hid,
                                              const float* __restrict__ x,
                                              const float* __restrict__ tW2,
                                              const float* __restrict__ tb2,
                                              const float* __restrict__ pxW,
                                              const float* __restrict__ pxb,
                                              const float* __restrict__ cproj,
                                              float* __restrict__ h){
  __shared__ float shid[32][128];
  __shared__ float sx[32][64];
  __shared__ float sW[32][128];
  int tid = threadIdx.x;
  int j = tid & 127, rg = tid >> 7;
  int row0 = blockIdx.x * 32;
  for (int i = tid; i < 32*128; i += 256){
    int r = i >> 7, k = i & 127; int gr = row0 + r;
    shid[r][k] = (gr < N_NODES) ? hid[gr*128 + k] : 0.f;
  }
  for (int i = tid; i < 32*64; i += 256){
    int r = i >> 6, k = i & 63; int gr = row0 + r;
    sx[r][k] = (gr < N_NODES) ? x[gr*64 + k] : 0.f;
  }
  float acc[16];
  float b = tb2[j] + pxb[j];
  #pragma unroll
  for (int r = 0; r < 16; r++) acc[r] = b;
  for (int k0 = 0; k0 < 128; k0 += 32){
    __syncthreads();
    for (int i = tid; i < 32*128; i += 256){
      int k = i >> 7, c = i & 127;
      sW[k][c] = tW2[(k0+k)*128 + c];
    }
    __syncthreads();
    for (int kk = 0; kk < 32; kk += 4){
      float wv[4];
      #pragma unroll
      for (int q = 0; q < 4; q++) wv[q] = sW[kk+q][j];
      #pragma unroll
      for (int r = 0; r < 16; r++){
        const float4 hv = *(const float4*)&shid[rg*16+r][k0+kk];
        acc[r] += hv.x*wv[0] + hv.y*wv[1] + hv.z*wv[2] + hv.w*wv[3];
      }
    }
  }
  for (int k0 = 0; k0 < 64; k0 += 32){
    __syncthreads();
    for (int i = tid; i < 32*128; i += 256){
      int k = i >> 7, c = i & 127;
      sW[k][c] = pxW[(k0+k)*128 + c];
    }
    __syncthreads();
    for (int kk = 0; kk < 32; kk += 4){
      float wv[4];
      #pragma unroll
      for (int q = 0; q < 4; q++) wv[q] = sW[kk+q][j];
      #pragma unroll
      for (int r = 0; r < 16; r++){
        const float4 xv = *(const float4*)&sx[rg*16+r][k0+kk];
        acc[r] += xv.x*wv[0] + xv.y*wv[1] + xv.z*wv[2] + xv.w*wv[3];
      }
    }
  }
  #pragma unroll
  for (int r = 0; r < 16; r++){
    int gr = row0 + rg*16 + r;
    if (gr < N_NODES) h[gr*128 + j] = acc[r] + cproj[(gr/NPB)*128 + j];
  }
}

// ---------------- xl = h@W1 ; hres = h@W2 ----------------
__global__ __launch_bounds__(256) void gemm_dual(const float* __restrict__ h,
                                                 const float* __restrict__ W1,
                                                 const float* __restrict__ W2,
                                                 float* __restrict__ xl,
                                                 float* __restrict__ hres){
  __shared__ float sh[32][128];
  __shared__ float sW1[32][128];
  __shared__ float sW2[32][128];
  int tid = threadIdx.x;
  int j = tid & 127, rg = tid >> 7;
  int row0 = blockIdx.x * 32;
  for (int i = tid; i < 32*128; i += 256){
    int r = i >> 7, k = i & 127; int gr = row0 + r;
    sh[r][k] = (gr < N_NODES) ? h[gr*128 + k] : 0.f;
  }
  float acc1[16], acc2[16];
  #pragma unroll
  for (int r = 0; r < 16; r++){ acc1[r] = 0.f; acc2[r] = 0.f; }
  for (int k0 = 0; k0 < 128; k0 += 32){
    __syncthreads();
    for (int i = tid; i < 32*128; i += 256){
      int k = i >> 7, c = i & 127;
      sW1[k][c] = W1[(k0+k)*128 + c];
      sW2[k][c] = W2[(k0+k)*128 + c];
    }
    __syncthreads();
    for (int kk = 0; kk < 32; kk += 4){
      float w1[4], w2[4];
      #pragma unroll
      for (int q = 0; q < 4; q++){ w1[q] = sW1[kk+q][j]; w2[q] = sW2[kk+q][j]; }
      #pragma unroll
      for (int r = 0; r < 16; r++){
        const float4 hv = *(const float4*)&sh[rg*16+r][k0+kk];
        acc1[r] += hv.x*w1[0] + hv.y*w1[1] + hv.z*w1[2] + hv.w*w1[3];
        acc2[r] += hv.x*w2[0] + hv.y*w2[1] + hv.z*w2[2] + hv.w*w2[3];
      }
    }
  }
  #pragma unroll
  for (int r = 0; r < 16; r++){
    int gr = row0 + rg*16 + r;
    if (gr < N_NODES){
      xl[gr*128 + j]   = acc1[r];
      hres[gr*128 + j] = acc2[r];
    }
  }
}

// ---------------- a_src/a_dst = h . u / h . v ----------------
__global__ __launch_bounds__(256) void dotpair(const float* __restrict__ h,
                                               const float* __restrict__ uv_l,
                                               float* __restrict__ a_src,
                                               float* __restrict__ a_dst){
  int lane = threadIdx.x & 63, wid = threadIdx.x >> 6;
  int i = blockIdx.x*4 + wid;
  if (i >= N_NODES) return;
  const float2 hv = *(const float2*)&h[i*128 + lane*2];
  float u0 = uv_l[lane*2], u1 = uv_l[lane*2+1];
  float v0 = uv_l[128 + lane*2], v1 = uv_l[128 + lane*2+1];
  float ps = hv.x*u0 + hv.y*u1;
  float pd = hv.x*v0 + hv.y*v1;
  #pragma unroll
  for (int off = 32; off; off >>= 1){
    ps += __shfl_xor(ps, off, 64);
    pd += __shfl_xor(pd, off, 64);
  }
  if (lane == 0){ a_src[i] = ps; a_dst[i] = pd; }
}

// ---------------- GAT aggregation + residual + gelu (in-place into h) ----------------
__global__ __launch_bounds__(256) void aggregate(const float* __restrict__ xl,
                                                 const float* __restrict__ a_src,
                                                 const float* __restrict__ a_dst,
                                                 const float* __restrict__ hres,
                                                 const float* __restrict__ gbias_l,
                                                 const int* __restrict__ offsets,
                                                 const int* __restrict__ srt_src,
                                                 float* __restrict__ h_out){
  int lane = threadIdx.x & 63, wid = threadIdx.x >> 6;
  int i = blockIdx.x*4 + wid;
  if (i >= N_NODES) return;
  int beg = offsets[i], end = offsets[i+1];
  float adst = a_dst[i];
  // phase 1: online softmax max + denominator over the segment
  float m = -INFINITY, den = 0.f;
  for (int e = beg; e < end; e += 64){
    int idx = e + lane;
    float ev = -INFINITY;
    if (idx < end){
      int s = srt_src[idx];
      float t = a_src[s] + adst;
      ev = (t > 0.f) ? t : 0.2f*t;
    }
    float cm = ev;
    #pragma unroll
    for (int off = 32; off; off >>= 1) cm = fmaxf(cm, __shfl_xor(cm, off, 64));
    if (cm > m){ den *= __expf(m - cm); m = cm; }
    float w = (idx < end) ? __expf(ev - m) : 0.f;
    #pragma unroll
    for (int off = 32; off; off >>= 1) w += __shfl_xor(w, off, 64);
    den += w;
  }
  // phase 2: weighted gather of xl rows
  float acc0 = 0.f, acc1 = 0.f;
  for (int e = beg; e < end; e++){
    int s = srt_src[e];
    float t = a_src[s] + adst;
    float ev = (t > 0.f) ? t : 0.2f*t;
    float w = __expf(ev - m);
    acc0 += w * xl[s*128 + lane];
    acc1 += w * xl[s*128 + 64 + lane];
  }
  float inv = 1.f / den;
  float r0 = acc0*inv + gbias_l[lane]      + hres[i*128 + lane];
  float r1 = acc1*inv + gbias_l[64 + lane] + hres[i*128 + 64 + lane];
  h_out[i*128 + lane]      = gelu_exact(r0);
  h_out[i*128 + 64 + lane] = gelu_exact(r1);
}

// ---------------- g = gelu(h@dW1 + db1) ----------------
__global__ __launch_bounds__(256) void gemm_bias_gelu(const float* __restrict__ h,
                                                      const float* __restrict__ W,
                                                      const float* __restrict__ bias,
                                                      float* __restrict__ g){
  __shared__ float sh[32][128];
  __shared__ float sW[32][128];
  int tid = threadIdx.x;
  int j = tid & 127, rg = tid >> 7;
  int row0 = blockIdx.x * 32;
  for (int i = tid; i < 32*128; i += 256){
    int r = i >> 7, k = i & 127; int gr = row0 + r;
    sh[r][k] = (gr < N_NODES) ? h[gr*128 + k] : 0.f;
  }
  float acc[16];
  float b = bias[j];
  #pragma unroll
  for (int r = 0; r < 16; r++) acc[r] = b;
  for (int k0 = 0; k0 < 128; k0 += 32){
    __syncthreads();
    for (int i = tid; i < 32*128; i += 256){
      int k = i >> 7, c = i & 127;
      sW[k][c] = W[(k0+k)*128 + c];
    }
    __syncthreads();
    for (int kk = 0; kk < 32; kk += 4){
      float wv[4];
      #pragma unroll
      for (int q = 0; q < 4; q++) wv[q] = sW[kk+q][j];
      #pragma unroll
      for (int r = 0; r < 16; r++){
        const float4 hv = *(const float4*)&sh[rg*16+r][k0+kk];
        acc[r] += hv.x*wv[0] + hv.y*wv[1] + hv.z*wv[2] + hv.w*wv[3];
      }
    }
  }
  #pragma unroll
  for (int r = 0; r < 16; r++){
    int gr = row0 + rg*16 + r;
    if (gr < N_NODES) g[gr*128 + j] = gelu_exact(acc[r]);
  }
}

// ---------------- out = g@dW2 + db2 ----------------
__global__ __launch_bounds__(256) void head2(const float* __restrict__ g,
                                             const float* __restrict__ dW2,
                                             const float* __restrict__ db2,
                                             float* __restrict__ out){
  int lane = threadIdx.x & 63, wid = threadIdx.x >> 6;
  int i = blockIdx.x*4 + wid;
  if (i >= N_NODES) return;
  const float2 gv = *(const float2*)&g[i*128 + lane*2];
  const float4 wv = *(const float4*)&dW2[lane*4]; // [k=2l][0],[k=2l][1],[k=2l+1][0],[k=2l+1][1]
  float p0 = gv.x*wv.x + gv.y*wv.z;
  float p1 = gv.x*wv.y + gv.y*wv.w;
  #pragma unroll
  for (int off = 32; off; off >>= 1){
    p0 += __shfl_xor(p0, off, 64);
    p1 += __shfl_xor(p1, off, 64);
  }
  if (lane == 0){
    out[i*2]   = p0 + db2[0];
    out[i*2+1] = p1 + db2[1];
  }
}

extern "C" void kernel_launch(void* const* d_in, const int* in_sizes, int n_in,
                              void* d_out, int out_size, void* d_ws, size_t ws_size,
                              hipStream_t stream) {
  const float* x   = (const float*)d_in[0];
  const int*   adj = (const int*)  d_in[1];
  // d_in[2] = ef — unused by the reference
  const float* timesteps = (const float*)d_in[3];
  const float* cond = (const float*)d_in[4];
  const float* fw   = (const float*)d_in[5];
  const float* tW1  = (const float*)d_in[6];
  const float* tb1  = (const float*)d_in[7];
  const float* tW2  = (const float*)d_in[8];
  const float* tb2  = (const float*)d_in[9];
  const float* pxW  = (const float*)d_in[10];
  const float* pxb  = (const float*)d_in[11];
  const float* pcW  = (const float*)d_in[12];
  const float* pcb  = (const float*)d_in[13];
  const float* linW = (const float*)d_in[14];
  const float* attS = (const float*)d_in[15];
  const float* attD = (const float*)d_in[16];
  const float* gbias= (const float*)d_in[17];
  const float* resW = (const float*)d_in[18];
  const float* dW1  = (const float*)d_in[19];
  const float* db1  = (const float*)d_in[20];
  const float* dW2  = (const float*)d_in[21];
  const float* db2  = (const float*)d_in[22];
  float* out = (float*)d_out;

  // workspace carve-up
  char* w = (char*)d_ws;
  size_t off = 0;
  auto carve = [&](size_t bytes) -> void* {
    void* p = w + off;
    off = (off + bytes + 255) & ~(size_t)255;
    return p;
  };
  float* h     = (float*)carve((size_t)N_NODES*128*4);
  float* xl    = (float*)carve((size_t)N_NODES*128*4);  // also hid, also g
  float* hres  = (float*)carve((size_t)N_NODES*128*4);
  float* a_src = (float*)carve((size_t)N_NODES*4);
  float* a_dst = (float*)carve((size_t)N_NODES*4);
  float* cproj = (float*)carve(50*128*4);
  float* uv    = (float*)carve(6*128*4);
  int* counts  = (int*)carve((size_t)N_NODES*4);
  int* cursor  = (int*)carve((size_t)N_NODES*4);
  int* offsets = (int*)carve((size_t)(N_NODES+1)*4);
  int* srt_src = (int*)carve((size_t)TOT_EDGES*4);
  (void)ws_size; (void)in_sizes; (void)n_in; (void)out_size;

  const int edge_blocks = (TOT_EDGES + 255)/256;
  const int gemm_blocks = (N_NODES + 31)/32;
  const int node_blocks = (N_NODES + 3)/4;

  // CSR build
  hipMemsetAsync(counts, 0, (size_t)N_NODES*4, stream);
  count_deg<<<edge_blocks, 256, 0, stream>>>(adj, counts);
  scan_kernel<<<1, 1024, 0, stream>>>(counts, offsets, cursor);
  scatter_edges<<<edge_blocks, 256, 0, stream>>>(adj, cursor, srt_src);

  // small precomputes
  cond_proj_k<<<50, 128, 0, stream>>>(cond, pcW, pcb, cproj);
  attvec_k<<<6, 128, 0, stream>>>(linW, attS, attD, uv);

  // initial h
  temb_hidden<<<gemm_blocks, 256, 0, stream>>>(timesteps, fw, tW1, tb1, xl /*hid*/);
  init_h<<<gemm_blocks, 256, 0, stream>>>(xl /*hid*/, x, tW2, tb2, pxW, pxb, cproj, h);

  // GAT layers
  for (int l = 0; l < 3; l++){
    dotpair<<<node_blocks, 256, 0, stream>>>(h, uv + l*256, a_src, a_dst);
    gemm_dual<<<gemm_blocks, 256, 0, stream>>>(h, linW + (size_t)l*128*128, resW + (size_t)l*128*128, xl, hres);
    aggregate<<<node_blocks, 256, 0, stream>>>(xl, a_src, a_dst, hres, gbias + l*128, offsets, srt_src, h);
  }

  // head
  gemm_bias_gelu<<<gemm_blocks, 256, 0, stream>>>(h, dW1, db1, xl /*g*/);
  head2<<<node_blocks, 256, 0, stream>>>(xl /*g*/, dW2, db2, out);
}

// Round 2
// 676.878 us; speedup vs baseline: 2.2192x; 2.2192x over previous
//
#include <hip/hip_runtime.h>
#include <hip/hip_bf16.h>

#define N_NODES 50000
#define N_EDGES 600000
#define TOT_EDGES (N_EDGES + N_NODES)
#define NPB 1000  // nodes per cond row (N/B)

typedef __bf16 bf16x8 __attribute__((ext_vector_type(8)));
typedef float f32x4 __attribute__((ext_vector_type(4)));
typedef unsigned short u16x8 __attribute__((ext_vector_type(8)));

__device__ __forceinline__ float gelu_exact(float v){
  return 0.5f * v * (1.f + erff(v * 0.70710678118654752f));
}
__device__ __forceinline__ float silu(float v){
  return v / (1.f + expf(-v));
}
__device__ __forceinline__ unsigned short f2bf(float f){
  unsigned u = __builtin_bit_cast(unsigned, f);
  unsigned r = (u + 0x7FFFu + ((u >> 16) & 1u)) >> 16;
  return (unsigned short)r;
}
__device__ __forceinline__ float bf2f(unsigned short u){
  return __builtin_bit_cast(float, ((unsigned)u) << 16);
}

// ---------------- CSR build ----------------
__global__ __launch_bounds__(256) void count_deg(const int* __restrict__ adj, int* __restrict__ counts){
  int j = blockIdx.x*256 + threadIdx.x;
  if (j >= TOT_EDGES) return;
  int d = (j < N_EDGES) ? adj[N_EDGES + j] : (j - N_EDGES);
  atomicAdd(&counts[d], 1);
}

__global__ __launch_bounds__(1024) void scan_kernel(const int* __restrict__ counts,
                                                    int* __restrict__ offsets,
                                                    int* __restrict__ cursor){
  const int tid = threadIdx.x;
  const int lane = tid & 63, wid = tid >> 6;
  __shared__ int wsum[16];
  __shared__ int carry_s;
  if (tid == 0) carry_s = 0;
  __syncthreads();
  for (int base = 0; base < N_NODES; base += 1024){
    int idx = base + tid;
    int v = (idx < N_NODES) ? counts[idx] : 0;
    int x = v;
    #pragma unroll
    for (int off = 1; off < 64; off <<= 1){
      int y = __shfl_up(x, off, 64);
      if (lane >= off) x += y;
    }
    if (lane == 63) wsum[wid] = x;
    __syncthreads();
    if (wid == 0){
      int s = (lane < 16) ? wsum[lane] : 0;
      #pragma unroll
      for (int off = 1; off < 16; off <<= 1){
        int y = __shfl_up(s, off, 64);
        if (lane >= off) s += y;
      }
      if (lane < 16) wsum[lane] = s;
    }
    __syncthreads();
    int wave_excl = wid ? wsum[wid-1] : 0;
    int excl = x - v + wave_excl + carry_s;
    if (idx < N_NODES){ offsets[idx] = excl; cursor[idx] = excl; }
    int total = wsum[15];
    __syncthreads();
    if (tid == 0) carry_s += total;
    __syncthreads();
  }
  if (tid == 0) offsets[N_NODES] = carry_s;
}

__global__ __launch_bounds__(256) void scatter_edges(const int* __restrict__ adj,
                                                     int* __restrict__ cursor,
                                                     int* __restrict__ srt_src){
  int j = blockIdx.x*256 + threadIdx.x;
  if (j >= TOT_EDGES) return;
  int s, d;
  if (j < N_EDGES){ s = adj[j]; d = adj[N_EDGES + j]; }
  else { s = j - N_EDGES; d = s; }
  int pos = atomicAdd(&cursor[d], 1);
  srt_src[pos] = s;
}

// ---------------- weight prep: transpose + cvt to bf16 ----------------
__global__ __launch_bounds__(256) void prep_weights(const float* __restrict__ linW,
                                                    const float* __restrict__ resW,
                                                    const float* __restrict__ tW2,
                                                    const float* __restrict__ pxW,
                                                    const float* __restrict__ dW1,
                                                    unsigned short* __restrict__ Bt2,
                                                    unsigned short* __restrict__ Bt_init,
                                                    unsigned short* __restrict__ Bt_d1){
  int idx = blockIdx.x*256 + threadIdx.x;
  if (idx < 98304){                      // 6 x 128x128: linW/resW per layer
    int j = idx >> 14, e = idx & 16383;
    int l = j >> 1, isres = j & 1;
    int k = e >> 7, c = e & 127;
    const float* src = (isres ? resW : linW) + l*16384;
    Bt2[(size_t)l*32768 + (size_t)(isres*128 + c)*128 + k] = f2bf(src[k*128 + c]);
  } else if (idx < 114688){              // tW2 128x128
    int e = idx - 98304; int k = e >> 7, c = e & 127;
    Bt_init[c*192 + k] = f2bf(tW2[k*128 + c]);
  } else if (idx < 122880){              // pxW 64x128
    int e = idx - 114688; int k = e >> 7, c = e & 127;
    Bt_init[c*192 + 128 + k] = f2bf(pxW[k*128 + c]);
  } else if (idx < 139264){              // dW1 128x128
    int e = idx - 122880; int k = e >> 7, c = e & 127;
    Bt_d1[c*128 + k] = f2bf(dW1[k*128 + c]);
  }
}

__global__ __launch_bounds__(256) void cvt_x(const float* __restrict__ x, unsigned short* __restrict__ xbf){
  int i = blockIdx.x*256 + threadIdx.x;   // covers N*64/4 exactly
  float4 v = ((const float4*)x)[i];
  ushort4 o;
  o.x = f2bf(v.x); o.y = f2bf(v.y); o.z = f2bf(v.z); o.w = f2bf(v.w);
  *(ushort4*)&xbf[(size_t)i*4] = o;
}

// ---------------- small precomputes ----------------
__global__ __launch_bounds__(128) void cond_proj_k(const float* __restrict__ cond,
                                                   const float* __restrict__ pcW,
                                                   const float* __restrict__ pcb,
                                                   float* __restrict__ cproj){
  int b = blockIdx.x, j = threadIdx.x;
  float acc = pcb[j];
  for (int k = 0; k < 32; k++) acc += cond[b*32+k]*pcW[k*128+j];
  cproj[b*128+j] = acc;
}

__global__ __launch_bounds__(128) void attvec_k(const float* __restrict__ linW,
                                                const float* __restrict__ attS,
                                                const float* __restrict__ attD,
                                                float* __restrict__ uv){
  int l = blockIdx.x >> 1, s = blockIdx.x & 1;
  const float* att = s ? (attD + l*128) : (attS + l*128);
  int k = threadIdx.x;
  const float* row = linW + (l*128 + k)*128;
  float acc = 0.f;
  for (int j = 0; j < 128; j++) acc += row[j]*att[j];
  uv[blockIdx.x*128 + k] = acc;
}

// ---------------- time embedding hidden: hid = silu(four @ tW1 + tb1) -> bf16 ----------------
__global__ __launch_bounds__(256) void temb_hidden(const float* __restrict__ timesteps,
                                                   const float* __restrict__ fw,
                                                   const float* __restrict__ tW1,
                                                   const float* __restrict__ tb1,
                                                   unsigned short* __restrict__ hid){
  __shared__ float sfour[32][17];
  __shared__ float sW[17][128];
  int tid = threadIdx.x;
  int row0 = blockIdx.x * 32;
  if (tid < 32){
    int gr = row0 + tid;
    float t = (gr < N_NODES) ? timesteps[gr] : 0.f;
    sfour[tid][0] = t;
    #pragma unroll
    for (int q = 0; q < 8; q++){
      float f = t * fw[q] * 6.2831853071795864769f;
      float sv, cv;
      sincosf(f, &sv, &cv);
      sfour[tid][1+q] = sv;
      sfour[tid][9+q] = cv;
    }
  }
  for (int i = tid; i < 17*128; i += 256) sW[i>>7][i&127] = tW1[i];
  __syncthreads();
  int j = tid & 127, rg = tid >> 7;
  float b = tb1[j];
  #pragma unroll
  for (int r = 0; r < 16; r++){
    int row = rg*16 + r;
    float acc = b;
    #pragma unroll
    for (int k = 0; k < 17; k++) acc += sfour[row][k]*sW[k][j];
    int gr = row0 + row;
    if (gr < N_NODES) hid[gr*128 + j] = f2bf(silu(acc));
  }
}

// ---------------- MFMA GEMM ----------------
// A-frag: row=lane&15, k=(lane>>4)*8+i (contiguous). B-frag: same from B^T row col=lane&15.
// D: col=lane&15, row=(lane>>4)*4+reg (m89-verified).
template<int KD, int EPI>
__global__ __launch_bounds__(256) void mfma_gemm(const unsigned short* __restrict__ A0,
                                                 const unsigned short* __restrict__ A1,
                                                 const unsigned short* __restrict__ Bt,
                                                 const float* __restrict__ bias0,
                                                 const float* __restrict__ bias1,
                                                 const float* __restrict__ cproj,
                                                 unsigned short* __restrict__ O0,
                                                 unsigned short* __restrict__ O1){
  constexpr int CHR  = KD / 8;    // 16B chunks per LDS row
  constexpr int ROWB = KD * 2;    // bytes per LDS row
  constexpr int KS   = KD / 32;   // mfma k-steps
  __shared__ alignas(16) char sA[64 * ROWB];
  const int tid  = threadIdx.x;
  const int m0   = blockIdx.x * 64;
  const int nb   = blockIdx.y;
  const int lane = tid & 63, w = tid >> 6;
  const int lr   = lane & 15, lk = lane >> 4;

  // B fragments, registers for the whole block
  bf16x8 bfr[4][KS];
  #pragma unroll
  for (int nt = 0; nt < 4; nt++){
    int c = nb*64 + nt*16 + lr;
    #pragma unroll
    for (int ks = 0; ks < KS; ks++)
      bfr[nt][ks] = *(const bf16x8*)&Bt[(size_t)c*KD + ks*32 + lk*8];
  }

  // stage A tile (64 rows x KD bf16), XOR swizzle byte ^= (row&7)<<4 (G4)
  for (int i = tid; i < 64*CHR; i += 256){
    int r = i / CHR, ch = i % CHR;
    int grow = m0 + r;
    u16x8 v;
    #pragma unroll
    for (int q = 0; q < 8; q++) v[q] = 0;
    if (grow < N_NODES){
      if constexpr (KD == 128){
        v = *(const u16x8*)&A0[(size_t)grow*128 + ch*8];
      } else {
        if (ch < 16) v = *(const u16x8*)&A0[(size_t)grow*128 + ch*8];
        else         v = *(const u16x8*)&A1[(size_t)grow*64 + (ch-16)*8];
      }
    }
    *(u16x8*)&sA[r*ROWB + ((ch*16) ^ ((r & 7) << 4))] = v;
  }
  __syncthreads();

  f32x4 acc[4];
  #pragma unroll
  for (int nt = 0; nt < 4; nt++)
    #pragma unroll
    for (int q = 0; q < 4; q++) acc[nt][q] = 0.f;

  const int arow = w*16 + lr;
  #pragma unroll
  for (int ks = 0; ks < KS; ks++){
    bf16x8 a = *(const bf16x8*)&sA[arow*ROWB + ((ks*64 + lk*16) ^ ((arow & 7) << 4))];
    #pragma unroll
    for (int nt = 0; nt < 4; nt++)
      acc[nt] = __builtin_amdgcn_mfma_f32_16x16x32_bf16(a, bfr[nt][ks], acc[nt], 0, 0, 0);
  }

  const int rbase = m0 + w*16 + lk*4;
  #pragma unroll
  for (int nt = 0; nt < 4; nt++){
    int c = nb*64 + nt*16 + lr;
    #pragma unroll
    for (int rg = 0; rg < 4; rg++){
      int row = rbase + rg;
      if (row >= N_NODES) continue;
      float v = acc[nt][rg];
      if constexpr (EPI == 0){
        if (c < 128) O0[(size_t)row*128 + c]       = f2bf(v);
        else         O1[(size_t)row*128 + (c-128)] = f2bf(v);
      } else if constexpr (EPI == 1){
        v += bias0[c] + bias1[c] + cproj[(row/NPB)*128 + c];
        O0[(size_t)row*128 + c] = f2bf(v);
      } else {
        v = gelu_exact(v + bias0[c]);
        O0[(size_t)row*128 + c] = f2bf(v);
      }
    }
  }
}

// ---------------- a_src/a_dst = h . u / h . v ----------------
__global__ __launch_bounds__(256) void dotpair(const unsigned short* __restrict__ h,
                                               const float* __restrict__ uv_l,
                                               float* __restrict__ a_src,
                                               float* __restrict__ a_dst){
  int lane = threadIdx.x & 63, wid = threadIdx.x >> 6;
  int i = blockIdx.x*4 + wid;
  if (i >= N_NODES) return;
  ushort2 hv = *(const ushort2*)&h[(size_t)i*128 + lane*2];
  float h0 = bf2f(hv.x), h1 = bf2f(hv.y);
  float u0 = uv_l[lane*2], u1 = uv_l[lane*2+1];
  float v0 = uv_l[128 + lane*2], v1 = uv_l[128 + lane*2+1];
  float ps = h0*u0 + h1*u1;
  float pd = h0*v0 + h1*v1;
  #pragma unroll
  for (int off = 32; off; off >>= 1){
    ps += __shfl_xor(ps, off, 64);
    pd += __shfl_xor(pd, off, 64);
  }
  if (lane == 0){ a_src[i] = ps; a_dst[i] = pd; }
}

// ---------------- GAT aggregation + residual + gelu ----------------
__global__ __launch_bounds__(256) void aggregate(const unsigned short* __restrict__ xl,
                                                 const float* __restrict__ a_src,
                                                 const float* __restrict__ a_dst,
                                                 const unsigned short* __restrict__ hres,
                                                 const float* __restrict__ gbias_l,
                                                 const int* __restrict__ offsets,
                                                 const int* __restrict__ srt_src,
                                                 unsigned short* __restrict__ h_out){
  int lane = threadIdx.x & 63, wid = threadIdx.x >> 6;
  int i = blockIdx.x*4 + wid;
  if (i >= N_NODES) return;
  int beg = offsets[i], end = offsets[i+1];
  float adst = a_dst[i];
  float m = -INFINITY, den = 0.f;
  for (int e = beg; e < end; e += 64){
    int idx = e + lane;
    float ev = -INFINITY;
    if (idx < end){
      int s = srt_src[idx];
      float t = a_src[s] + adst;
      ev = (t > 0.f) ? t : 0.2f*t;
    }
    float cm = ev;
    #pragma unroll
    for (int off = 32; off; off >>= 1) cm = fmaxf(cm, __shfl_xor(cm, off, 64));
    if (cm > m){ den *= __expf(m - cm); m = cm; }
    float w = (idx < end) ? __expf(ev - m) : 0.f;
    #pragma unroll
    for (int off = 32; off; off >>= 1) w += __shfl_xor(w, off, 64);
    den += w;
  }
  float acc0 = 0.f, acc1 = 0.f;
  for (int e = beg; e < end; e++){
    int s = srt_src[e];
    float t = a_src[s] + adst;
    float ev = (t > 0.f) ? t : 0.2f*t;
    float wgt = __expf(ev - m);
    ushort2 xv = *(const ushort2*)&xl[(size_t)s*128 + lane*2];
    acc0 += wgt * bf2f(xv.x);
    acc1 += wgt * bf2f(xv.y);
  }
  float inv = 1.f / den;
  ushort2 hr = *(const ushort2*)&hres[(size_t)i*128 + lane*2];
  float r0 = acc0*inv + gbias_l[lane*2]   + bf2f(hr.x);
  float r1 = acc1*inv + gbias_l[lane*2+1] + bf2f(hr.y);
  ushort2 o;
  o.x = f2bf(gelu_exact(r0));
  o.y = f2bf(gelu_exact(r1));
  *(ushort2*)&h_out[(size_t)i*128 + lane*2] = o;
}

// ---------------- out = g@dW2 + db2 ----------------
__global__ __launch_bounds__(256) void head2(const unsigned short* __restrict__ g,
                                             const float* __restrict__ dW2,
                                             const float* __restrict__ db2,
                                             float* __restrict__ out){
  int lane = threadIdx.x & 63, wid = threadIdx.x >> 6;
  int i = blockIdx.x*4 + wid;
  if (i >= N_NODES) return;
  ushort2 gv = *(const ushort2*)&g[(size_t)i*128 + lane*2];
  float g0 = bf2f(gv.x), g1 = bf2f(gv.y);
  const float4 wv = *(const float4*)&dW2[lane*4];
  float p0 = g0*wv.x + g1*wv.z;
  float p1 = g0*wv.y + g1*wv.w;
  #pragma unroll
  for (int off = 32; off; off >>= 1){
    p0 += __shfl_xor(p0, off, 64);
    p1 += __shfl_xor(p1, off, 64);
  }
  if (lane == 0){
    out[i*2]   = p0 + db2[0];
    out[i*2+1] = p1 + db2[1];
  }
}

extern "C" void kernel_launch(void* const* d_in, const int* in_sizes, int n_in,
                              void* d_out, int out_size, void* d_ws, size_t ws_size,
                              hipStream_t stream) {
  const float* x   = (const float*)d_in[0];
  const int*   adj = (const int*)  d_in[1];
  const float* timesteps = (const float*)d_in[3];
  const float* cond = (const float*)d_in[4];
  const float* fw   = (const float*)d_in[5];
  const float* tW1  = (const float*)d_in[6];
  const float* tb1  = (const float*)d_in[7];
  const float* tW2  = (const float*)d_in[8];
  const float* tb2  = (const float*)d_in[9];
  const float* pxW  = (const float*)d_in[10];
  const float* pxb  = (const float*)d_in[11];
  const float* pcW  = (const float*)d_in[12];
  const float* pcb  = (const float*)d_in[13];
  const float* linW = (const float*)d_in[14];
  const float* attS = (const float*)d_in[15];
  const float* attD = (const float*)d_in[16];
  const float* gbias= (const float*)d_in[17];
  const float* resW = (const float*)d_in[18];
  const float* dW1  = (const float*)d_in[19];
  const float* db1  = (const float*)d_in[20];
  const float* dW2  = (const float*)d_in[21];
  const float* db2  = (const float*)d_in[22];
  float* out = (float*)d_out;

  char* w = (char*)d_ws;
  size_t off = 0;
  auto carve = [&](size_t bytes) -> void* {
    void* p = w + off;
    off = (off + bytes + 255) & ~(size_t)255;
    return p;
  };
  unsigned short* h_bf    = (unsigned short*)carve((size_t)N_NODES*128*2);
  unsigned short* xl_bf   = (unsigned short*)carve((size_t)N_NODES*128*2); // also hid_bf, also g_bf
  unsigned short* hres_bf = (unsigned short*)carve((size_t)N_NODES*128*2);
  unsigned short* x_bf    = (unsigned short*)carve((size_t)N_NODES*64*2);
  float* a_src = (float*)carve((size_t)N_NODES*4);
  float* a_dst = (float*)carve((size_t)N_NODES*4);
  float* cproj = (float*)carve(50*128*4);
  float* uv    = (float*)carve(6*128*4);
  int* counts  = (int*)carve((size_t)N_NODES*4);
  int* cursor  = (int*)carve((size_t)N_NODES*4);
  int* offsets = (int*)carve((size_t)(N_NODES+1)*4);
  int* srt_src = (int*)carve((size_t)TOT_EDGES*4);
  unsigned short* Bt2     = (unsigned short*)carve((size_t)3*256*128*2);
  unsigned short* Bt_init = (unsigned short*)carve((size_t)128*192*2);
  unsigned short* Bt_d1   = (unsigned short*)carve((size_t)128*128*2);
  (void)ws_size; (void)in_sizes; (void)n_in; (void)out_size;

  const int edge_blocks = (TOT_EDGES + 255)/256;
  const int tile_blocks = (N_NODES + 31)/32;
  const int gemm_gx     = (N_NODES + 63)/64;
  const int node_blocks = (N_NODES + 3)/4;

  // CSR build
  hipMemsetAsync(counts, 0, (size_t)N_NODES*4, stream);
  count_deg<<<edge_blocks, 256, 0, stream>>>(adj, counts);
  scan_kernel<<<1, 1024, 0, stream>>>(counts, offsets, cursor);
  scatter_edges<<<edge_blocks, 256, 0, stream>>>(adj, cursor, srt_src);

  // weight prep + small precomputes
  prep_weights<<<(139264+255)/256, 256, 0, stream>>>(linW, resW, tW2, pxW, dW1, Bt2, Bt_init, Bt_d1);
  cvt_x<<<(N_NODES*64/4+255)/256, 256, 0, stream>>>(x, x_bf);
  cond_proj_k<<<50, 128, 0, stream>>>(cond, pcW, pcb, cproj);
  attvec_k<<<6, 128, 0, stream>>>(linW, attS, attD, uv);

  // initial h = [hid | x] @ [tW2 ; pxW] + biases + cproj
  temb_hidden<<<tile_blocks, 256, 0, stream>>>(timesteps, fw, tW1, tb1, xl_bf /*hid*/);
  mfma_gemm<192,1><<<dim3(gemm_gx,2), 256, 0, stream>>>(xl_bf /*hid*/, x_bf, Bt_init, tb2, pxb, cproj, h_bf, nullptr);

  // GAT layers
  for (int l = 0; l < 3; l++){
    dotpair<<<node_blocks, 256, 0, stream>>>(h_bf, uv + l*256, a_src, a_dst);
    mfma_gemm<128,0><<<dim3(gemm_gx,4), 256, 0, stream>>>(h_bf, nullptr, Bt2 + (size_t)l*32768, nullptr, nullptr, nullptr, xl_bf, hres_bf);
    aggregate<<<node_blocks, 256, 0, stream>>>(xl_bf, a_src, a_dst, hres_bf, gbias + l*128, offsets, srt_src, h_bf);
  }

  // head
  mfma_gemm<128,2><<<dim3(gemm_gx,2), 256, 0, stream>>>(h_bf, nullptr, Bt_d1, db1, nullptr, nullptr, xl_bf /*g*/, nullptr);
  head2<<<node_blocks, 256, 0, stream>>>(xl_bf /*g*/, dW2, db2, out);
}

// Round 4
// 512.578 us; speedup vs baseline: 2.9306x; 1.3205x over previous
//
#include <hip/hip_runtime.h>
#include <hip/hip_bf16.h>

#define N_NODES 50000
#define N_EDGES 600000
#define TOT_EDGES (N_EDGES + N_NODES)
#define NPB 1000   // nodes per cond row (N/B)
#define SCAN_BLK 49  // ceil(N_NODES/1024)

typedef __bf16 bf16x8 __attribute__((ext_vector_type(8)));
typedef float f32x4 __attribute__((ext_vector_type(4)));
typedef unsigned short u16x8 __attribute__((ext_vector_type(8)));

__device__ __forceinline__ float gelu_exact(float v){
  return 0.5f * v * (1.f + erff(v * 0.70710678118654752f));
}
__device__ __forceinline__ float silu(float v){
  return v / (1.f + expf(-v));
}
__device__ __forceinline__ unsigned short f2bf(float f){
  unsigned u = __builtin_bit_cast(unsigned, f);
  unsigned r = (u + 0x7FFFu + ((u >> 16) & 1u)) >> 16;
  return (unsigned short)r;
}
__device__ __forceinline__ float bf2f(unsigned short u){
  return __builtin_bit_cast(float, ((unsigned)u) << 16);
}

// ---------------- CSR build ----------------
__global__ __launch_bounds__(256) void count_deg(const int* __restrict__ adj, int* __restrict__ counts){
  int j = blockIdx.x*256 + threadIdx.x;
  if (j >= TOT_EDGES) return;
  int d = (j < N_EDGES) ? adj[N_EDGES + j] : (j - N_EDGES);
  atomicAdd(&counts[d], 1);
}

// parallel scan: per-block sums -> base scan -> final scan
__global__ __launch_bounds__(256) void scan_part(const int* __restrict__ counts, int* __restrict__ blksum){
  int tid = threadIdx.x;
  int base = blockIdx.x*1024 + tid*4;
  int s = 0;
  #pragma unroll
  for (int k = 0; k < 4; k++){ int idx = base+k; if (idx < N_NODES) s += counts[idx]; }
  #pragma unroll
  for (int off = 1; off < 64; off <<= 1) s += __shfl_xor(s, off, 64);
  __shared__ int ws[4];
  int lane = tid & 63, wid = tid >> 6;
  if (lane == 0) ws[wid] = s;
  __syncthreads();
  if (tid == 0) blksum[blockIdx.x] = ws[0]+ws[1]+ws[2]+ws[3];
}

__global__ __launch_bounds__(64) void scan_base(const int* __restrict__ blksum,
                                                int* __restrict__ blkbase,
                                                int* __restrict__ offsets){
  int lane = threadIdx.x;
  int v = (lane < SCAN_BLK) ? blksum[lane] : 0;
  int x = v;
  #pragma unroll
  for (int off = 1; off < 64; off <<= 1){
    int y = __shfl_up(x, off, 64);
    if (lane >= off) x += y;
  }
  if (lane < SCAN_BLK) blkbase[lane] = x - v;
  if (lane == 63) offsets[N_NODES] = x;
}

__global__ __launch_bounds__(256) void scan_final(const int* __restrict__ counts,
                                                  const int* __restrict__ blkbase,
                                                  int* __restrict__ offsets,
                                                  int* __restrict__ cursor){
  int tid = threadIdx.x; int lane = tid & 63, wid = tid >> 6;
  int base = blockIdx.x*1024 + tid*4;
  int v[4]; int s = 0;
  #pragma unroll
  for (int k = 0; k < 4; k++){ int idx = base+k; v[k] = (idx < N_NODES) ? counts[idx] : 0; s += v[k]; }
  int x = s;
  #pragma unroll
  for (int off = 1; off < 64; off <<= 1){
    int y = __shfl_up(x, off, 64);
    if (lane >= off) x += y;
  }
  __shared__ int ws[4];
  if (lane == 63) ws[wid] = x;
  __syncthreads();
  int run = blkbase[blockIdx.x];
  for (int q = 0; q < wid; q++) run += ws[q];
  run += x - s;   // exclusive within wave
  #pragma unroll
  for (int k = 0; k < 4; k++){
    int idx = base+k;
    if (idx < N_NODES){ offsets[idx] = run; cursor[idx] = run; }
    run += v[k];
  }
}

__global__ __launch_bounds__(256) void scatter_edges(const int* __restrict__ adj,
                                                     int* __restrict__ cursor,
                                                     int* __restrict__ srt_src){
  int j = blockIdx.x*256 + threadIdx.x;
  if (j >= TOT_EDGES) return;
  int s, d;
  if (j < N_EDGES){ s = adj[j]; d = adj[N_EDGES + j]; }
  else { s = j - N_EDGES; d = s; }
  int pos = atomicAdd(&cursor[d], 1);
  srt_src[pos] = s;
}

// ---------------- weight prep: transpose + cvt to bf16 ----------------
__global__ __launch_bounds__(256) void prep_weights(const float* __restrict__ linW,
                                                    const float* __restrict__ resW,
                                                    const float* __restrict__ tW2,
                                                    const float* __restrict__ pxW,
                                                    const float* __restrict__ dW1,
                                                    unsigned short* __restrict__ Bt2,
                                                    unsigned short* __restrict__ Bt_init,
                                                    unsigned short* __restrict__ Bt_d1){
  int idx = blockIdx.x*256 + threadIdx.x;
  if (idx < 98304){
    int j = idx >> 14, e = idx & 16383;
    int l = j >> 1, isres = j & 1;
    int k = e >> 7, c = e & 127;
    const float* src = (isres ? resW : linW) + l*16384;
    Bt2[(size_t)l*32768 + (size_t)(isres*128 + c)*128 + k] = f2bf(src[k*128 + c]);
  } else if (idx < 114688){
    int e = idx - 98304; int k = e >> 7, c = e & 127;
    Bt_init[c*192 + k] = f2bf(tW2[k*128 + c]);
  } else if (idx < 122880){
    int e = idx - 114688; int k = e >> 7, c = e & 127;
    Bt_init[c*192 + 128 + k] = f2bf(pxW[k*128 + c]);
  } else if (idx < 139264){
    int e = idx - 122880; int k = e >> 7, c = e & 127;
    Bt_d1[c*128 + k] = f2bf(dW1[k*128 + c]);
  }
}

__global__ __launch_bounds__(256) void cvt_x(const float* __restrict__ x, unsigned short* __restrict__ xbf){
  int i = blockIdx.x*256 + threadIdx.x;
  float4 v = ((const float4*)x)[i];
  ushort4 o;
  o.x = f2bf(v.x); o.y = f2bf(v.y); o.z = f2bf(v.z); o.w = f2bf(v.w);
  *(ushort4*)&xbf[(size_t)i*4] = o;
}

// ---------------- small precomputes ----------------
__global__ __launch_bounds__(128) void cond_proj_k(const float* __restrict__ cond,
                                                   const float* __restrict__ pcW,
                                                   const float* __restrict__ pcb,
                                                   float* __restrict__ cproj){
  int b = blockIdx.x, j = threadIdx.x;
  float acc = pcb[j];
  for (int k = 0; k < 32; k++) acc += cond[b*32+k]*pcW[k*128+j];
  cproj[b*128+j] = acc;
}

__global__ __launch_bounds__(128) void attvec_k(const float* __restrict__ linW,
                                                const float* __restrict__ attS,
                                                const float* __restrict__ attD,
                                                float* __restrict__ uv){
  int l = blockIdx.x >> 1, s = blockIdx.x & 1;
  const float* att = s ? (attD + l*128) : (attS + l*128);
  int k = threadIdx.x;
  const float* row = linW + (l*128 + k)*128;
  float acc = 0.f;
  for (int j = 0; j < 128; j++) acc += row[j]*att[j];
  uv[blockIdx.x*128 + k] = acc;
}

// ---------------- time embedding hidden ----------------
__global__ __launch_bounds__(256) void temb_hidden(const float* __restrict__ timesteps,
                                                   const float* __restrict__ fw,
                                                   const float* __restrict__ tW1,
                                                   const float* __restrict__ tb1,
                                                   unsigned short* __restrict__ hid){
  __shared__ float sfour[32][17];
  __shared__ float sW[17][128];
  int tid = threadIdx.x;
  int row0 = blockIdx.x * 32;
  if (tid < 32){
    int gr = row0 + tid;
    float t = (gr < N_NODES) ? timesteps[gr] : 0.f;
    sfour[tid][0] = t;
    #pragma unroll
    for (int q = 0; q < 8; q++){
      float f = t * fw[q] * 6.2831853071795864769f;
      float sv, cv;
      sincosf(f, &sv, &cv);
      sfour[tid][1+q] = sv;
      sfour[tid][9+q] = cv;
    }
  }
  for (int i = tid; i < 17*128; i += 256) sW[i>>7][i&127] = tW1[i];
  __syncthreads();
  int j = tid & 127, rg = tid >> 7;
  float b = tb1[j];
  #pragma unroll
  for (int r = 0; r < 16; r++){
    int row = rg*16 + r;
    float acc = b;
    #pragma unroll
    for (int k = 0; k < 17; k++) acc += sfour[row][k]*sW[k][j];
    int gr = row0 + row;
    if (gr < N_NODES) hid[gr*128 + j] = f2bf(silu(acc));
  }
}

// ---------------- MFMA GEMM ----------------
template<int KD, int EPI>
__global__ __launch_bounds__(256) void mfma_gemm(const unsigned short* __restrict__ A0,
                                                 const unsigned short* __restrict__ A1,
                                                 const unsigned short* __restrict__ Bt,
                                                 const float* __restrict__ bias0,
                                                 const float* __restrict__ bias1,
                                                 const float* __restrict__ cproj,
                                                 unsigned short* __restrict__ O0,
                                                 unsigned short* __restrict__ O1){
  constexpr int CHR  = KD / 8;
  constexpr int ROWB = KD * 2;
  constexpr int KS   = KD / 32;
  __shared__ alignas(16) char sA[64 * ROWB];
  const int tid  = threadIdx.x;
  const int m0   = blockIdx.x * 64;
  const int nb   = blockIdx.y;
  const int lane = tid & 63, w = tid >> 6;
  const int lr   = lane & 15, lk = lane >> 4;

  bf16x8 bfr[4][KS];
  #pragma unroll
  for (int nt = 0; nt < 4; nt++){
    int c = nb*64 + nt*16 + lr;
    #pragma unroll
    for (int ks = 0; ks < KS; ks++)
      bfr[nt][ks] = *(const bf16x8*)&Bt[(size_t)c*KD + ks*32 + lk*8];
  }

  for (int i = tid; i < 64*CHR; i += 256){
    int r = i / CHR, ch = i % CHR;
    int grow = m0 + r;
    u16x8 v;
    #pragma unroll
    for (int q = 0; q < 8; q++) v[q] = 0;
    if (grow < N_NODES){
      if constexpr (KD == 128){
        v = *(const u16x8*)&A0[(size_t)grow*128 + ch*8];
      } else {
        if (ch < 16) v = *(const u16x8*)&A0[(size_t)grow*128 + ch*8];
        else         v = *(const u16x8*)&A1[(size_t)grow*64 + (ch-16)*8];
      }
    }
    *(u16x8*)&sA[r*ROWB + ((ch*16) ^ ((r & 7) << 4))] = v;
  }
  __syncthreads();

  f32x4 acc[4];
  #pragma unroll
  for (int nt = 0; nt < 4; nt++)
    #pragma unroll
    for (int q = 0; q < 4; q++) acc[nt][q] = 0.f;

  const int arow = w*16 + lr;
  #pragma unroll
  for (int ks = 0; ks < KS; ks++){
    bf16x8 a = *(const bf16x8*)&sA[arow*ROWB + ((ks*64 + lk*16) ^ ((arow & 7) << 4))];
    #pragma unroll
    for (int nt = 0; nt < 4; nt++)
      acc[nt] = __builtin_amdgcn_mfma_f32_16x16x32_bf16(a, bfr[nt][ks], acc[nt], 0, 0, 0);
  }

  const int rbase = m0 + w*16 + lk*4;
  #pragma unroll
  for (int nt = 0; nt < 4; nt++){
    int c = nb*64 + nt*16 + lr;
    #pragma unroll
    for (int rg = 0; rg < 4; rg++){
      int row = rbase + rg;
      if (row >= N_NODES) continue;
      float v = acc[nt][rg];
      if constexpr (EPI == 0){
        if (c < 128) O0[(size_t)row*128 + c]       = f2bf(v);
        else         O1[(size_t)row*128 + (c-128)] = f2bf(v);
      } else if constexpr (EPI == 1){
        v += bias0[c] + bias1[c] + cproj[(row/NPB)*128 + c];
        O0[(size_t)row*128 + c] = f2bf(v);
      } else {
        v = gelu_exact(v + bias0[c]);
        O0[(size_t)row*128 + c] = f2bf(v);
      }
    }
  }
}

// ---------------- a_src/a_dst = h . u / h . v ----------------
__global__ __launch_bounds__(256) void dotpair(const unsigned short* __restrict__ h,
                                               const float* __restrict__ uv_l,
                                               float* __restrict__ a_src,
                                               float* __restrict__ a_dst){
  int lane = threadIdx.x & 63, wid = threadIdx.x >> 6;
  int i = blockIdx.x*4 + wid;
  if (i >= N_NODES) return;
  ushort2 hv = *(const ushort2*)&h[(size_t)i*128 + lane*2];
  float h0 = bf2f(hv.x), h1 = bf2f(hv.y);
  float u0 = uv_l[lane*2], u1 = uv_l[lane*2+1];
  float v0 = uv_l[128 + lane*2], v1 = uv_l[128 + lane*2+1];
  float ps = h0*u0 + h1*u1;
  float pd = h0*v0 + h1*v1;
  #pragma unroll
  for (int off = 32; off; off >>= 1){
    ps += __shfl_xor(ps, off, 64);
    pd += __shfl_xor(pd, off, 64);
  }
  if (lane == 0){ a_src[i] = ps; a_dst[i] = pd; }
}

// ---------------- GAT aggregation: 16-lane groups, 4 nodes/wave ----------------
__global__ __launch_bounds__(256) void aggregate(const unsigned short* __restrict__ xl,
                                                 const float* __restrict__ a_src,
                                                 const float* __restrict__ a_dst,
                                                 const unsigned short* __restrict__ hres,
                                                 const float* __restrict__ gbias_l,
                                                 const int* __restrict__ offsets,
                                                 const int* __restrict__ srt_src,
                                                 unsigned short* __restrict__ h_out){
  const int tid  = threadIdx.x;
  const int lane = tid & 63;
  const int l16  = lane & 15;
  const int i    = blockIdx.x*16 + (tid >> 4);   // grid exactly N/16
  const int beg  = offsets[i];
  const int deg  = offsets[i+1] - beg;
  const float adst = a_dst[i];

  // ---- phase 1: online softmax stats over 16-edge chunks
  int   s0  = 0;
  float ev0 = -INFINITY;
  if (l16 < deg){
    s0 = srt_src[beg + l16];
    float t = a_src[s0] + adst;
    ev0 = (t > 0.f) ? t : 0.2f*t;
  }
  float m = ev0;
  #pragma unroll
  for (int off = 1; off < 16; off <<= 1) m = fmaxf(m, __shfl_xor(m, off, 64));
  float den = (l16 < deg) ? __expf(ev0 - m) : 0.f;
  #pragma unroll
  for (int off = 1; off < 16; off <<= 1) den += __shfl_xor(den, off, 64);
  for (int c0 = 16; c0 < deg; c0 += 16){
    float ev = -INFINITY;
    if (c0 + l16 < deg){
      int s = srt_src[beg + c0 + l16];
      float t = a_src[s] + adst;
      ev = (t > 0.f) ? t : 0.2f*t;
    }
    float cm = ev;
    #pragma unroll
    for (int off = 1; off < 16; off <<= 1) cm = fmaxf(cm, __shfl_xor(cm, off, 64));
    if (cm > m){ den *= __expf(m - cm); m = cm; }
    float wv = (c0 + l16 < deg) ? __expf(ev - m) : 0.f;
    #pragma unroll
    for (int off = 1; off < 16; off <<= 1) wv += __shfl_xor(wv, off, 64);
    den += wv;
  }
  const float inv = 1.f / den;
  float w0 = (l16 < deg) ? __expf(ev0 - m) * inv : 0.f;

  // ---- phase 2: weighted gather (alpha pre-folded into w)
  float acc[8];
  #pragma unroll
  for (int k = 0; k < 8; k++) acc[k] = 0.f;
  const int gbb = (lane & 48) << 2;   // group-base byte addr for bpermute

  int lim0 = deg < 16 ? deg : 16;
  for (int q = 0; q < lim0; q++){
    int addr = gbb + q*4;
    int s    = __builtin_amdgcn_ds_bpermute(addr, s0);
    float wq = __builtin_bit_cast(float, __builtin_amdgcn_ds_bpermute(addr, __builtin_bit_cast(int, w0)));
    const int4 xv = *(const int4*)&xl[((size_t)s << 7) + (l16 << 3)];
    const int xd[4] = {xv.x, xv.y, xv.z, xv.w};
    #pragma unroll
    for (int k = 0; k < 4; k++){
      acc[2*k]   += wq * __builtin_bit_cast(float, xd[k] << 16);
      acc[2*k+1] += wq * __builtin_bit_cast(float, xd[k] & 0xffff0000);
    }
  }
  for (int c0 = 16; c0 < deg; c0 += 16){
    int s1 = 0; float w1 = 0.f;
    if (c0 + l16 < deg){
      s1 = srt_src[beg + c0 + l16];
      float t = a_src[s1] + adst;
      float ev = (t > 0.f) ? t : 0.2f*t;
      w1 = __expf(ev - m) * inv;
    }
    int lim = deg - c0; if (lim > 16) lim = 16;
    for (int q = 0; q < lim; q++){
      int addr = gbb + q*4;
      int s    = __builtin_amdgcn_ds_bpermute(addr, s1);
      float wq = __builtin_bit_cast(float, __builtin_amdgcn_ds_bpermute(addr, __builtin_bit_cast(int, w1)));
      const int4 xv = *(const int4*)&xl[((size_t)s << 7) + (l16 << 3)];
      const int xd[4] = {xv.x, xv.y, xv.z, xv.w};
      #pragma unroll
      for (int k = 0; k < 4; k++){
        acc[2*k]   += wq * __builtin_bit_cast(float, xd[k] << 16);
        acc[2*k+1] += wq * __builtin_bit_cast(float, xd[k] & 0xffff0000);
      }
    }
  }

  // ---- epilogue: + gbias + hres, gelu, bf16 store (16B/lane)
  const int4 hr = *(const int4*)&hres[((size_t)i << 7) + (l16 << 3)];
  const int hd[4] = {hr.x, hr.y, hr.z, hr.w};
  const float4 gb0 = *(const float4*)&gbias_l[l16*8];
  const float4 gb1 = *(const float4*)&gbias_l[l16*8 + 4];
  const float gbv[8] = {gb0.x, gb0.y, gb0.z, gb0.w, gb1.x, gb1.y, gb1.z, gb1.w};
  int od[4];
  #pragma unroll
  for (int k = 0; k < 4; k++){
    float r0 = acc[2*k]   + gbv[2*k]   + __builtin_bit_cast(float, hd[k] << 16);
    float r1 = acc[2*k+1] + gbv[2*k+1] + __builtin_bit_cast(float, hd[k] & 0xffff0000);
    unsigned lo = f2bf(gelu_exact(r0));
    unsigned hi = f2bf(gelu_exact(r1));
    od[k] = (int)(lo | (hi << 16));
  }
  *(int4*)&h_out[((size_t)i << 7) + (l16 << 3)] = make_int4(od[0], od[1], od[2], od[3]);
}

// ---------------- out = g@dW2 + db2 ----------------
__global__ __launch_bounds__(256) void head2(const unsigned short* __restrict__ g,
                                             const float* __restrict__ dW2,
                                             const float* __restrict__ db2,
                                             float* __restrict__ out){
  int lane = threadIdx.x & 63, wid = threadIdx.x >> 6;
  int i = blockIdx.x*4 + wid;
  if (i >= N_NODES) return;
  ushort2 gv = *(const ushort2*)&g[(size_t)i*128 + lane*2];
  float g0 = bf2f(gv.x), g1 = bf2f(gv.y);
  const float4 wv = *(const float4*)&dW2[lane*4];
  float p0 = g0*wv.x + g1*wv.z;
  float p1 = g0*wv.y + g1*wv.w;
  #pragma unroll
  for (int off = 32; off; off >>= 1){
    p0 += __shfl_xor(p0, off, 64);
    p1 += __shfl_xor(p1, off, 64);
  }
  if (lane == 0){
    out[i*2]   = p0 + db2[0];
    out[i*2+1] = p1 + db2[1];
  }
}

extern "C" void kernel_launch(void* const* d_in, const int* in_sizes, int n_in,
                              void* d_out, int out_size, void* d_ws, size_t ws_size,
                              hipStream_t stream) {
  const float* x   = (const float*)d_in[0];
  const int*   adj = (const int*)  d_in[1];
  const float* timesteps = (const float*)d_in[3];
  const float* cond = (const float*)d_in[4];
  const float* fw   = (const float*)d_in[5];
  const float* tW1  = (const float*)d_in[6];
  const float* tb1  = (const float*)d_in[7];
  const float* tW2  = (const float*)d_in[8];
  const float* tb2  = (const float*)d_in[9];
  const float* pxW  = (const float*)d_in[10];
  const float* pxb  = (const float*)d_in[11];
  const float* pcW  = (const float*)d_in[12];
  const float* pcb  = (const float*)d_in[13];
  const float* linW = (const float*)d_in[14];
  const float* attS = (const float*)d_in[15];
  const float* attD = (const float*)d_in[16];
  const float* gbias= (const float*)d_in[17];
  const float* resW = (const float*)d_in[18];
  const float* dW1  = (const float*)d_in[19];
  const float* db1  = (const float*)d_in[20];
  const float* dW2  = (const float*)d_in[21];
  const float* db2  = (const float*)d_in[22];
  float* out = (float*)d_out;

  char* w = (char*)d_ws;
  size_t off = 0;
  auto carve = [&](size_t bytes) -> void* {
    void* p = w + off;
    off = (off + bytes + 255) & ~(size_t)255;
    return p;
  };
  unsigned short* h_bf    = (unsigned short*)carve((size_t)N_NODES*128*2);
  unsigned short* xl_bf   = (unsigned short*)carve((size_t)N_NODES*128*2); // also hid_bf, also g_bf
  unsigned short* hres_bf = (unsigned short*)carve((size_t)N_NODES*128*2);
  unsigned short* x_bf    = (unsigned short*)carve((size_t)N_NODES*64*2);
  float* a_src = (float*)carve((size_t)N_NODES*4);
  float* a_dst = (float*)carve((size_t)N_NODES*4);
  float* cproj = (float*)carve(50*128*4);
  float* uv    = (float*)carve(6*128*4);
  int* counts  = (int*)carve((size_t)N_NODES*4);
  int* cursor  = (int*)carve((size_t)N_NODES*4);
  int* offsets = (int*)carve((size_t)(N_NODES+1)*4);
  int* srt_src = (int*)carve((size_t)TOT_EDGES*4);
  int* blksum  = (int*)carve(SCAN_BLK*4);
  int* blkbase = (int*)carve(SCAN_BLK*4);
  unsigned short* Bt2     = (unsigned short*)carve((size_t)3*256*128*2);
  unsigned short* Bt_init = (unsigned short*)carve((size_t)128*192*2);
  unsigned short* Bt_d1   = (unsigned short*)carve((size_t)128*128*2);
  (void)ws_size; (void)in_sizes; (void)n_in; (void)out_size;

  const int edge_blocks = (TOT_EDGES + 255)/256;
  const int tile_blocks = (N_NODES + 31)/32;
  const int gemm_gx     = (N_NODES + 63)/64;
  const int node_blocks = (N_NODES + 3)/4;
  const int agg_blocks  = N_NODES/16;   // exact: 3125

  // CSR build
  hipMemsetAsync(counts, 0, (size_t)N_NODES*4, stream);
  count_deg<<<edge_blocks, 256, 0, stream>>>(adj, counts);
  scan_part<<<SCAN_BLK, 256, 0, stream>>>(counts, blksum);
  scan_base<<<1, 64, 0, stream>>>(blksum, blkbase, offsets);
  scan_final<<<SCAN_BLK, 256, 0, stream>>>(counts, blkbase, offsets, cursor);
  scatter_edges<<<edge_blocks, 256, 0, stream>>>(adj, cursor, srt_src);

  // weight prep + small precomputes
  prep_weights<<<(139264+255)/256, 256, 0, stream>>>(linW, resW, tW2, pxW, dW1, Bt2, Bt_init, Bt_d1);
  cvt_x<<<(N_NODES*64/4+255)/256, 256, 0, stream>>>(x, x_bf);
  cond_proj_k<<<50, 128, 0, stream>>>(cond, pcW, pcb, cproj);
  attvec_k<<<6, 128, 0, stream>>>(linW, attS, attD, uv);

  // initial h = [hid | x] @ [tW2 ; pxW] + biases + cproj
  temb_hidden<<<tile_blocks, 256, 0, stream>>>(timesteps, fw, tW1, tb1, xl_bf /*hid*/);
  mfma_gemm<192,1><<<dim3(gemm_gx,2), 256, 0, stream>>>(xl_bf /*hid*/, x_bf, Bt_init, tb2, pxb, cproj, h_bf, nullptr);

  // GAT layers
  for (int l = 0; l < 3; l++){
    dotpair<<<node_blocks, 256, 0, stream>>>(h_bf, uv + l*256, a_src, a_dst);
    mfma_gemm<128,0><<<dim3(gemm_gx,4), 256, 0, stream>>>(h_bf, nullptr, Bt2 + (size_t)l*32768, nullptr, nullptr, nullptr, xl_bf, hres_bf);
    aggregate<<<agg_blocks, 256, 0, stream>>>(xl_bf, a_src, a_dst, hres_bf, gbias + l*128, offsets, srt_src, h_bf);
  }

  // head
  mfma_gemm<128,2><<<dim3(gemm_gx,2), 256, 0, stream>>>(h_bf, nullptr, Bt_d1, db1, nullptr, nullptr, xl_bf /*g*/, nullptr);
  head2<<<node_blocks, 256, 0, stream>>>(xl_bf /*g*/, dW2, db2, out);
}

// Round 6
// 471.253 us; speedup vs baseline: 3.1876x; 1.0877x over previous
//
#include <hip/hip_runtime.h>
#include <hip/hip_bf16.h>

#define N_NODES 50000
#define N_EDGES 600000
#define TOT_EDGES (N_EDGES + N_NODES)
#define NPB 1000     // nodes per cond row (N/B)
#define SCAN_BLK 49  // ceil(N_NODES/1024)

// prep_all block ranges
#define PREP_T0 1563                 // temb: (N+31)/32
#define PREP_T1 (PREP_T0 + 544)     // prep_weights: 139264/256
#define PREP_T2 (PREP_T1 + 3125)    // cvt_x: N*64/4/256
#define PREP_T3 (PREP_T2 + 25)      // cond_proj: 50*128/256
#define PREP_T4 (PREP_T3 + 3)       // attvec: 768/256

typedef __bf16 bf16x8 __attribute__((ext_vector_type(8)));
typedef float f32x4 __attribute__((ext_vector_type(4)));
typedef unsigned short u16x8 __attribute__((ext_vector_type(8)));

__device__ __forceinline__ float gelu_exact(float v){
  return 0.5f * v * (1.f + erff(v * 0.70710678118654752f));
}
__device__ __forceinline__ float silu(float v){
  return v / (1.f + expf(-v));
}
__device__ __forceinline__ unsigned short f2bf(float f){
  unsigned u = __builtin_bit_cast(unsigned, f);
  unsigned r = (u + 0x7FFFu + ((u >> 16) & 1u)) >> 16;
  return (unsigned short)r;
}
__device__ __forceinline__ float bf2f(unsigned short u){
  return __builtin_bit_cast(float, ((unsigned)u) << 16);
}

// ---------------- CSR build (4 edges/thread) ----------------
__global__ __launch_bounds__(256) void count_deg(const int* __restrict__ adj, int* __restrict__ counts){
  int t = blockIdx.x*256 + threadIdx.x;
  if (t >= TOT_EDGES/4) return;
  int j4 = t*4;
  if (j4 < N_EDGES){
    const int4 d4 = *(const int4*)&adj[N_EDGES + j4];
    atomicAdd(&counts[d4.x], 1);
    atomicAdd(&counts[d4.y], 1);
    atomicAdd(&counts[d4.z], 1);
    atomicAdd(&counts[d4.w], 1);
  } else {
    int base = j4 - N_EDGES;
    #pragma unroll
    for (int k = 0; k < 4; k++) atomicAdd(&counts[base+k], 1);
  }
}

__global__ __launch_bounds__(256) void scan_part(const int* __restrict__ counts, int* __restrict__ blksum){
  int tid = threadIdx.x;
  int base = blockIdx.x*1024 + tid*4;
  int s = 0;
  #pragma unroll
  for (int k = 0; k < 4; k++){ int idx = base+k; if (idx < N_NODES) s += counts[idx]; }
  #pragma unroll
  for (int off = 1; off < 64; off <<= 1) s += __shfl_xor(s, off, 64);
  __shared__ int ws[4];
  int lane = tid & 63, wid = tid >> 6;
  if (lane == 0) ws[wid] = s;
  __syncthreads();
  if (tid == 0) blksum[blockIdx.x] = ws[0]+ws[1]+ws[2]+ws[3];
}

// folds the old scan_base: each block re-scans the 49 partials in wave 0
__global__ __launch_bounds__(256) void scan_final(const int* __restrict__ counts,
                                                  const int* __restrict__ blksum,
                                                  int* __restrict__ offsets,
                                                  int* __restrict__ cursor){
  int tid = threadIdx.x; int lane = tid & 63, wid = tid >> 6;
  __shared__ int ws[4];
  __shared__ int sbase;
  // per-thread 4-element chunk + wave scan
  int base = blockIdx.x*1024 + tid*4;
  int v[4]; int s = 0;
  #pragma unroll
  for (int k = 0; k < 4; k++){ int idx = base+k; v[k] = (idx < N_NODES) ? counts[idx] : 0; s += v[k]; }
  int x = s;
  #pragma unroll
  for (int off = 1; off < 64; off <<= 1){
    int y = __shfl_up(x, off, 64);
    if (lane >= off) x += y;
  }
  if (lane == 63) ws[wid] = x;
  // wave 0: block base from blksum scan
  if (tid < 64){
    int bv = (tid < SCAN_BLK) ? blksum[tid] : 0;
    int bx = bv;
    #pragma unroll
    for (int off = 1; off < 64; off <<= 1){
      int y = __shfl_up(bx, off, 64);
      if (tid >= off) bx += y;
    }
    int basev = (blockIdx.x == 0) ? 0 : __shfl(bx, blockIdx.x - 1, 64);
    int total = __shfl(bx, SCAN_BLK - 1, 64);
    if (tid == 0){
      sbase = basev;
      if (blockIdx.x == SCAN_BLK-1) offsets[N_NODES] = total;
    }
  }
  __syncthreads();
  int run = sbase;
  for (int q = 0; q < wid; q++) run += ws[q];
  run += x - s;   // exclusive within wave
  #pragma unroll
  for (int k = 0; k < 4; k++){
    int idx = base+k;
    if (idx < N_NODES){ offsets[idx] = run; cursor[idx] = run; }
    run += v[k];
  }
}

__global__ __launch_bounds__(256) void scatter_edges(const int* __restrict__ adj,
                                                     int* __restrict__ cursor,
                                                     int* __restrict__ srt_src){
  int t = blockIdx.x*256 + threadIdx.x;
  if (t >= TOT_EDGES/4) return;
  int j4 = t*4;
  if (j4 < N_EDGES){
    const int4 s4 = *(const int4*)&adj[j4];
    const int4 d4 = *(const int4*)&adj[N_EDGES + j4];
    int p0 = atomicAdd(&cursor[d4.x], 1); srt_src[p0] = s4.x;
    int p1 = atomicAdd(&cursor[d4.y], 1); srt_src[p1] = s4.y;
    int p2 = atomicAdd(&cursor[d4.z], 1); srt_src[p2] = s4.z;
    int p3 = atomicAdd(&cursor[d4.w], 1); srt_src[p3] = s4.w;
  } else {
    int base = j4 - N_EDGES;
    #pragma unroll
    for (int k = 0; k < 4; k++){
      int d = base + k;
      int pos = atomicAdd(&cursor[d], 1);
      srt_src[pos] = d;
    }
  }
}

// ---------------- merged prep: temb + weight-prep + cvt_x + cond_proj + attvec ----------------
__global__ __launch_bounds__(256) void prep_all(const float* __restrict__ timesteps,
                                                const float* __restrict__ fw,
                                                const float* __restrict__ tW1,
                                                const float* __restrict__ tb1,
                                                unsigned short* __restrict__ hid,
                                                const float* __restrict__ linW,
                                                const float* __restrict__ resW,
                                                const float* __restrict__ tW2,
                                                const float* __restrict__ pxW,
                                                const float* __restrict__ dW1,
                                                unsigned short* __restrict__ Bt2,
                                                unsigned short* __restrict__ Bt_init,
                                                unsigned short* __restrict__ Bt_d1,
                                                const float* __restrict__ x,
                                                unsigned short* __restrict__ xbf,
                                                const float* __restrict__ cond,
                                                const float* __restrict__ pcW,
                                                const float* __restrict__ pcb,
                                                float* __restrict__ cproj,
                                                const float* __restrict__ attS,
                                                const float* __restrict__ attD,
                                                float* __restrict__ uv){
  __shared__ float sfour[32][17];
  __shared__ float sW[17][128];
  const int bid = blockIdx.x, tid = threadIdx.x;

  if (bid < PREP_T0){
    // ---- temb_hidden
    int row0 = bid * 32;
    if (tid < 32){
      int gr = row0 + tid;
      float t = (gr < N_NODES) ? timesteps[gr] : 0.f;
      sfour[tid][0] = t;
      #pragma unroll
      for (int q = 0; q < 8; q++){
        float f = t * fw[q] * 6.2831853071795864769f;
        float sv, cv;
        sincosf(f, &sv, &cv);
        sfour[tid][1+q] = sv;
        sfour[tid][9+q] = cv;
      }
    }
    for (int i = tid; i < 17*128; i += 256) sW[i>>7][i&127] = tW1[i];
    __syncthreads();
    int j = tid & 127, rg = tid >> 7;
    float b = tb1[j];
    #pragma unroll
    for (int r = 0; r < 16; r++){
      int row = rg*16 + r;
      float acc = b;
      #pragma unroll
      for (int k = 0; k < 17; k++) acc += sfour[row][k]*sW[k][j];
      int gr = row0 + row;
      if (gr < N_NODES) hid[gr*128 + j] = f2bf(silu(acc));
    }
  } else if (bid < PREP_T1){
    // ---- prep_weights
    int idx = (bid - PREP_T0)*256 + tid;
    if (idx < 98304){
      int j = idx >> 14, e = idx & 16383;
      int l = j >> 1, isres = j & 1;
      int k = e >> 7, c = e & 127;
      const float* src = (isres ? resW : linW) + l*16384;
      Bt2[(size_t)l*32768 + (size_t)(isres*128 + c)*128 + k] = f2bf(src[k*128 + c]);
    } else if (idx < 114688){
      int e = idx - 98304; int k = e >> 7, c = e & 127;
      Bt_init[c*192 + k] = f2bf(tW2[k*128 + c]);
    } else if (idx < 122880){
      int e = idx - 114688; int k = e >> 7, c = e & 127;
      Bt_init[c*192 + 128 + k] = f2bf(pxW[k*128 + c]);
    } else if (idx < 139264){
      int e = idx - 122880; int k = e >> 7, c = e & 127;
      Bt_d1[c*128 + k] = f2bf(dW1[k*128 + c]);
    }
  } else if (bid < PREP_T2){
    // ---- cvt_x (float4 -> 4 bf16)
    int i = (bid - PREP_T1)*256 + tid;   // < 800000 exactly
    float4 v = ((const float4*)x)[i];
    ushort4 o;
    o.x = f2bf(v.x); o.y = f2bf(v.y); o.z = f2bf(v.z); o.w = f2bf(v.w);
    *(ushort4*)&xbf[(size_t)i*4] = o;
  } else if (bid < PREP_T3){
    // ---- cond_proj
    int g = (bid - PREP_T2)*256 + tid;   // < 6400
    int b = g >> 7, j = g & 127;
    float acc = pcb[j];
    for (int k = 0; k < 32; k++) acc += cond[b*32+k]*pcW[k*128+j];
    cproj[b*128+j] = acc;
  } else {
    // ---- attvec
    int g = (bid - PREP_T3)*256 + tid;   // < 768
    if (g < 768){
      int l = g >> 8, s = (g >> 7) & 1, k = g & 127;
      const float* att = s ? (attD + l*128) : (attS + l*128);
      const float* row = linW + (l*128 + k)*128;
      float acc = 0.f;
      for (int j = 0; j < 128; j++) acc += row[j]*att[j];
      uv[(l*2 + s)*128 + k] = acc;
    }
  }
}

// ---------------- MFMA GEMM ----------------
// A-frag: row=lane&15, k=(lane>>4)*8+i. B-frag same from B^T. D: col=lane&15, row=(lane>>4)*4+reg.
// SWZ: flat grid, XCD-grouped so the 4 col-blocks of one row-tile share an XCD L2.
template<int KD, int EPI, bool SWZ>
__global__ __launch_bounds__(256) void mfma_gemm(const unsigned short* __restrict__ A0,
                                                 const unsigned short* __restrict__ A1,
                                                 const unsigned short* __restrict__ Bt,
                                                 const float* __restrict__ bias0,
                                                 const float* __restrict__ bias1,
                                                 const float* __restrict__ cproj,
                                                 unsigned short* __restrict__ O0,
                                                 unsigned short* __restrict__ O1){
  constexpr int CHR  = KD / 8;
  constexpr int ROWB = KD * 2;
  constexpr int KS   = KD / 32;
  __shared__ alignas(16) char sA[64 * ROWB];
  const int tid  = threadIdx.x;
  int bx, nb;
  if constexpr (SWZ){
    int id = blockIdx.x;
    int nper = gridDim.x >> 3;          // gridDim.x % 8 == 0
    int lin = (id & 7) * nper + (id >> 3);
    bx = lin >> 2; nb = lin & 3;
  } else {
    bx = blockIdx.x; nb = blockIdx.y;
  }
  const int m0   = bx * 64;
  const int lane = tid & 63, w = tid >> 6;
  const int lr   = lane & 15, lk = lane >> 4;

  bf16x8 bfr[4][KS];
  #pragma unroll
  for (int nt = 0; nt < 4; nt++){
    int c = nb*64 + nt*16 + lr;
    #pragma unroll
    for (int ks = 0; ks < KS; ks++)
      bfr[nt][ks] = *(const bf16x8*)&Bt[(size_t)c*KD + ks*32 + lk*8];
  }

  for (int i = tid; i < 64*CHR; i += 256){
    int r = i / CHR, ch = i % CHR;
    int grow = m0 + r;
    u16x8 v;
    #pragma unroll
    for (int q = 0; q < 8; q++) v[q] = 0;
    if (grow < N_NODES){
      if constexpr (KD == 128){
        v = *(const u16x8*)&A0[(size_t)grow*128 + ch*8];
      } else {
        if (ch < 16) v = *(const u16x8*)&A0[(size_t)grow*128 + ch*8];
        else         v = *(const u16x8*)&A1[(size_t)grow*64 + (ch-16)*8];
      }
    }
    *(u16x8*)&sA[r*ROWB + ((ch*16) ^ ((r & 7) << 4))] = v;
  }
  __syncthreads();

  f32x4 acc[4];
  #pragma unroll
  for (int nt = 0; nt < 4; nt++)
    #pragma unroll
    for (int q = 0; q < 4; q++) acc[nt][q] = 0.f;

  const int arow = w*16 + lr;
  #pragma unroll
  for (int ks = 0; ks < KS; ks++){
    bf16x8 a = *(const bf16x8*)&sA[arow*ROWB + ((ks*64 + lk*16) ^ ((arow & 7) << 4))];
    #pragma unroll
    for (int nt = 0; nt < 4; nt++)
      acc[nt] = __builtin_amdgcn_mfma_f32_16x16x32_bf16(a, bfr[nt][ks], acc[nt], 0, 0, 0);
  }

  const int rbase = m0 + w*16 + lk*4;
  #pragma unroll
  for (int nt = 0; nt < 4; nt++){
    int c = nb*64 + nt*16 + lr;
    #pragma unroll
    for (int rg = 0; rg < 4; rg++){
      int row = rbase + rg;
      if (row >= N_NODES) continue;
      float v = acc[nt][rg];
      if constexpr (EPI == 0){
        if (c < 128) O0[(size_t)row*128 + c]       = f2bf(v);
        else         O1[(size_t)row*128 + (c-128)] = f2bf(v);
      } else if constexpr (EPI == 1){
        v += bias0[c] + bias1[c] + cproj[(row/NPB)*128 + c];
        O0[(size_t)row*128 + c] = f2bf(v);
      } else {
        v = gelu_exact(v + bias0[c]);
        O0[(size_t)row*128 + c] = f2bf(v);
      }
    }
  }
}

// ---------------- a_src/a_dst = h . u / h . v (layer 0 only) ----------------
__global__ __launch_bounds__(256) void dotpair(const unsigned short* __restrict__ h,
                                               const float* __restrict__ uv_l,
                                               float* __restrict__ a_src,
                                               float* __restrict__ a_dst){
  int lane = threadIdx.x & 63, wid = threadIdx.x >> 6;
  int i = blockIdx.x*4 + wid;
  if (i >= N_NODES) return;
  ushort2 hv = *(const ushort2*)&h[(size_t)i*128 + lane*2];
  float h0 = bf2f(hv.x), h1 = bf2f(hv.y);
  float u0 = uv_l[lane*2], u1 = uv_l[lane*2+1];
  float v0 = uv_l[128 + lane*2], v1 = uv_l[128 + lane*2+1];
  float ps = h0*u0 + h1*u1;
  float pd = h0*v0 + h1*v1;
  #pragma unroll
  for (int off = 32; off; off >>= 1){
    ps += __shfl_xor(ps, off, 64);
    pd += __shfl_xor(pd, off, 64);
  }
  if (lane == 0){ a_src[i] = ps; a_dst[i] = pd; }
}

// ---------------- GAT aggregation: 16-lane groups; optionally fuse next-layer dots ----------------
// NOTE: a_src_o/a_dst_o MUST NOT alias a_src/a_dst (cross-block race) — double-buffered by caller.
template<bool FUSE>
__global__ __launch_bounds__(256) void aggregate(const unsigned short* __restrict__ xl,
                                                 const float* __restrict__ a_src,
                                                 const float* __restrict__ a_dst,
                                                 const unsigned short* __restrict__ hres,
                                                 const float* __restrict__ gbias_l,
                                                 const int* __restrict__ offsets,
                                                 const int* __restrict__ srt_src,
                                                 unsigned short* __restrict__ h_out,
                                                 const float* __restrict__ uv_next,
                                                 float* __restrict__ a_src_o,
                                                 float* __restrict__ a_dst_o){
  const int tid  = threadIdx.x;
  const int lane = tid & 63;
  const int l16  = lane & 15;
  const int i    = blockIdx.x*16 + (tid >> 4);   // grid exactly N/16
  const int beg  = offsets[i];
  const int deg  = offsets[i+1] - beg;
  const float adst = a_dst[i];

  // ---- phase 1: online softmax stats over 16-edge chunks
  int   s0  = 0;
  float ev0 = -INFINITY;
  if (l16 < deg){
    s0 = srt_src[beg + l16];
    float t = a_src[s0] + adst;
    ev0 = (t > 0.f) ? t : 0.2f*t;
  }
  float m = ev0;
  #pragma unroll
  for (int off = 1; off < 16; off <<= 1) m = fmaxf(m, __shfl_xor(m, off, 64));
  float den = (l16 < deg) ? __expf(ev0 - m) : 0.f;
  #pragma unroll
  for (int off = 1; off < 16; off <<= 1) den += __shfl_xor(den, off, 64);
  for (int c0 = 16; c0 < deg; c0 += 16){
    float ev = -INFINITY;
    if (c0 + l16 < deg){
      int s = srt_src[beg + c0 + l16];
      float t = a_src[s] + adst;
      ev = (t > 0.f) ? t : 0.2f*t;
    }
    float cm = ev;
    #pragma unroll
    for (int off = 1; off < 16; off <<= 1) cm = fmaxf(cm, __shfl_xor(cm, off, 64));
    if (cm > m){ den *= __expf(m - cm); m = cm; }
    float wv = (c0 + l16 < deg) ? __expf(ev - m) : 0.f;
    #pragma unroll
    for (int off = 1; off < 16; off <<= 1) wv += __shfl_xor(wv, off, 64);
    den += wv;
  }
  const float inv = 1.f / den;
  float w0 = (l16 < deg) ? __expf(ev0 - m) * inv : 0.f;

  // ---- phase 2: weighted gather (alpha pre-folded into w)
  float acc[8];
  #pragma unroll
  for (int k = 0; k < 8; k++) acc[k] = 0.f;
  const int gbb = (lane & 48) << 2;   // group-base byte addr for bpermute

  int lim0 = deg < 16 ? deg : 16;
  for (int q = 0; q < lim0; q++){
    int addr = gbb + q*4;
    int s    = __builtin_amdgcn_ds_bpermute(addr, s0);
    float wq = __builtin_bit_cast(float, __builtin_amdgcn_ds_bpermute(addr, __builtin_bit_cast(int, w0)));
    const int4 xv = *(const int4*)&xl[((size_t)s << 7) + (l16 << 3)];
    const int xd[4] = {xv.x, xv.y, xv.z, xv.w};
    #pragma unroll
    for (int k = 0; k < 4; k++){
      acc[2*k]   += wq * __builtin_bit_cast(float, xd[k] << 16);
      acc[2*k+1] += wq * __builtin_bit_cast(float, xd[k] & 0xffff0000);
    }
  }
  for (int c0 = 16; c0 < deg; c0 += 16){
    int s1 = 0; float w1 = 0.f;
    if (c0 + l16 < deg){
      s1 = srt_src[beg + c0 + l16];
      float t = a_src[s1] + adst;
      float ev = (t > 0.f) ? t : 0.2f*t;
      w1 = __expf(ev - m) * inv;
    }
    int lim = deg - c0; if (lim > 16) lim = 16;
    for (int q = 0; q < lim; q++){
      int addr = gbb + q*4;
      int s    = __builtin_amdgcn_ds_bpermute(addr, s1);
      float wq = __builtin_bit_cast(float, __builtin_amdgcn_ds_bpermute(addr, __builtin_bit_cast(int, w1)));
      const int4 xv = *(const int4*)&xl[((size_t)s << 7) + (l16 << 3)];
      const int xd[4] = {xv.x, xv.y, xv.z, xv.w};
      #pragma unroll
      for (int k = 0; k < 4; k++){
        acc[2*k]   += wq * __builtin_bit_cast(float, xd[k] << 16);
        acc[2*k+1] += wq * __builtin_bit_cast(float, xd[k] & 0xffff0000);
      }
    }
  }

  // ---- epilogue: + gbias + hres, gelu, bf16 store; optionally next-layer dots
  const int4 hr = *(const int4*)&hres[((size_t)i << 7) + (l16 << 3)];
  const int hd[4] = {hr.x, hr.y, hr.z, hr.w};
  const float4 gb0 = *(const float4*)&gbias_l[l16*8];
  const float4 gb1 = *(const float4*)&gbias_l[l16*8 + 4];
  const float gbv[8] = {gb0.x, gb0.y, gb0.z, gb0.w, gb1.x, gb1.y, gb1.z, gb1.w};
  float uu[8], vv[8];
  if constexpr (FUSE){
    const float4 a0 = *(const float4*)&uv_next[l16*8];
    const float4 a1 = *(const float4*)&uv_next[l16*8 + 4];
    const float4 b0 = *(const float4*)&uv_next[128 + l16*8];
    const float4 b1 = *(const float4*)&uv_next[128 + l16*8 + 4];
    uu[0]=a0.x; uu[1]=a0.y; uu[2]=a0.z; uu[3]=a0.w; uu[4]=a1.x; uu[5]=a1.y; uu[6]=a1.z; uu[7]=a1.w;
    vv[0]=b0.x; vv[1]=b0.y; vv[2]=b0.z; vv[3]=b0.w; vv[4]=b1.x; vv[5]=b1.y; vv[6]=b1.z; vv[7]=b1.w;
  }
  float ps = 0.f, pd = 0.f;
  int od[4];
  #pragma unroll
  for (int k = 0; k < 4; k++){
    float r0 = acc[2*k]   + gbv[2*k]   + __builtin_bit_cast(float, hd[k] << 16);
    float r1 = acc[2*k+1] + gbv[2*k+1] + __builtin_bit_cast(float, hd[k] & 0xffff0000);
    float g0 = gelu_exact(r0);
    float g1 = gelu_exact(r1);
    if constexpr (FUSE){
      ps += g0*uu[2*k] + g1*uu[2*k+1];
      pd += g0*vv[2*k] + g1*vv[2*k+1];
    }
    unsigned lo = f2bf(g0);
    unsigned hi = f2bf(g1);
    od[k] = (int)(lo | (hi << 16));
  }
  *(int4*)&h_out[((size_t)i << 7) + (l16 << 3)] = make_int4(od[0], od[1], od[2], od[3]);
  if constexpr (FUSE){
    #pragma unroll
    for (int off = 1; off < 16; off <<= 1){
      ps += __shfl_xor(ps, off, 64);
      pd += __shfl_xor(pd, off, 64);
    }
    if (l16 == 0){ a_src_o[i] = ps; a_dst_o[i] = pd; }
  }
}

// ---------------- out = g@dW2 + db2 (16-lane groups) ----------------
__global__ __launch_bounds__(256) void head2(const unsigned short* __restrict__ g,
                                             const float* __restrict__ dW2,
                                             const float* __restrict__ db2,
                                             float* __restrict__ out){
  const int tid = threadIdx.x;
  const int l16 = tid & 15;
  const int i   = blockIdx.x*16 + (tid >> 4);
  const int4 gv = *(const int4*)&g[((size_t)i << 7) + (l16 << 3)];
  const int gd[4] = {gv.x, gv.y, gv.z, gv.w};
  float wk[16];
  #pragma unroll
  for (int q = 0; q < 4; q++){
    const float4 wq = *(const float4*)&dW2[l16*16 + q*4];
    wk[q*4+0]=wq.x; wk[q*4+1]=wq.y; wk[q*4+2]=wq.z; wk[q*4+3]=wq.w;
  }
  float p0 = 0.f, p1 = 0.f;
  #pragma unroll
  for (int k = 0; k < 4; k++){
    float lo = __builtin_bit_cast(float, gd[k] << 16);
    float hi = __builtin_bit_cast(float, gd[k] & 0xffff0000);
    p0 += lo*wk[4*k+0] + hi*wk[4*k+2];
    p1 += lo*wk[4*k+1] + hi*wk[4*k+3];
  }
  #pragma unroll
  for (int off = 1; off < 16; off <<= 1){
    p0 += __shfl_xor(p0, off, 64);
    p1 += __shfl_xor(p1, off, 64);
  }
  if (l16 == 0){
    float2 o; o.x = p0 + db2[0]; o.y = p1 + db2[1];
    *(float2*)&out[i*2] = o;
  }
}

extern "C" void kernel_launch(void* const* d_in, const int* in_sizes, int n_in,
                              void* d_out, int out_size, void* d_ws, size_t ws_size,
                              hipStream_t stream) {
  const float* x   = (const float*)d_in[0];
  const int*   adj = (const int*)  d_in[1];
  const float* timesteps = (const float*)d_in[3];
  const float* cond = (const float*)d_in[4];
  const float* fw   = (const float*)d_in[5];
  const float* tW1  = (const float*)d_in[6];
  const float* tb1  = (const float*)d_in[7];
  const float* tW2  = (const float*)d_in[8];
  const float* tb2  = (const float*)d_in[9];
  const float* pxW  = (const float*)d_in[10];
  const float* pxb  = (const float*)d_in[11];
  const float* pcW  = (const float*)d_in[12];
  const float* pcb  = (const float*)d_in[13];
  const float* linW = (const float*)d_in[14];
  const float* attS = (const float*)d_in[15];
  const float* attD = (const float*)d_in[16];
  const float* gbias= (const float*)d_in[17];
  const float* resW = (const float*)d_in[18];
  const float* dW1  = (const float*)d_in[19];
  const float* db1  = (const float*)d_in[20];
  const float* dW2  = (const float*)d_in[21];
  const float* db2  = (const float*)d_in[22];
  float* out = (float*)d_out;

  char* w = (char*)d_ws;
  size_t off = 0;
  auto carve = [&](size_t bytes) -> void* {
    void* p = w + off;
    off = (off + bytes + 255) & ~(size_t)255;
    return p;
  };
  unsigned short* h_bf    = (unsigned short*)carve((size_t)N_NODES*128*2);
  unsigned short* xl_bf   = (unsigned short*)carve((size_t)N_NODES*128*2); // also hid_bf, also g_bf
  unsigned short* hres_bf = (unsigned short*)carve((size_t)N_NODES*128*2);
  unsigned short* x_bf    = (unsigned short*)carve((size_t)N_NODES*64*2);
  float* a_src0 = (float*)carve((size_t)N_NODES*4);
  float* a_dst0 = (float*)carve((size_t)N_NODES*4);
  float* a_src1 = (float*)carve((size_t)N_NODES*4);
  float* a_dst1 = (float*)carve((size_t)N_NODES*4);
  float* cproj = (float*)carve(50*128*4);
  float* uv    = (float*)carve(6*128*4);
  int* counts  = (int*)carve((size_t)N_NODES*4);
  int* cursor  = (int*)carve((size_t)N_NODES*4);
  int* offsets = (int*)carve((size_t)(N_NODES+1)*4);
  int* srt_src = (int*)carve((size_t)TOT_EDGES*4);
  int* blksum  = (int*)carve(SCAN_BLK*4);
  unsigned short* Bt2     = (unsigned short*)carve((size_t)3*256*128*2);
  unsigned short* Bt_init = (unsigned short*)carve((size_t)128*192*2);
  unsigned short* Bt_d1   = (unsigned short*)carve((size_t)128*128*2);
  (void)ws_size; (void)in_sizes; (void)n_in; (void)out_size;

  const int quad_blocks = (TOT_EDGES/4 + 255)/256;   // 635
  const int gemm_gx     = (N_NODES + 63)/64;          // 782
  const int node_blocks = (N_NODES + 3)/4;            // 12500
  const int grp_blocks  = N_NODES/16;                 // 3125

  // CSR build
  hipMemsetAsync(counts, 0, (size_t)N_NODES*4, stream);
  count_deg<<<quad_blocks, 256, 0, stream>>>(adj, counts);
  scan_part<<<SCAN_BLK, 256, 0, stream>>>(counts, blksum);
  scan_final<<<SCAN_BLK, 256, 0, stream>>>(counts, blksum, offsets, cursor);
  scatter_edges<<<quad_blocks, 256, 0, stream>>>(adj, cursor, srt_src);

  // merged prep (temb + weights + cvt_x + cond_proj + attvec)
  prep_all<<<PREP_T4, 256, 0, stream>>>(timesteps, fw, tW1, tb1, xl_bf /*hid*/,
                                        linW, resW, tW2, pxW, dW1, Bt2, Bt_init, Bt_d1,
                                        x, x_bf, cond, pcW, pcb, cproj, attS, attD, uv);

  // initial h = [hid | x] @ [tW2 ; pxW] + biases + cproj
  mfma_gemm<192,1,false><<<dim3(gemm_gx,2), 256, 0, stream>>>(xl_bf /*hid*/, x_bf, Bt_init, tb2, pxb, cproj, h_bf, nullptr);

  // layer-0 attention dots -> buffer 0
  dotpair<<<node_blocks, 256, 0, stream>>>(h_bf, uv, a_src0, a_dst0);

  // GAT layers (aggregate fuses next layer's dots; logits double-buffered to avoid
  // cross-block read/write races on a_src/a_dst)
  float* asrc_in = a_src0; float* adst_in = a_dst0;
  float* asrc_out = a_src1; float* adst_out = a_dst1;
  for (int l = 0; l < 3; l++){
    mfma_gemm<128,0,true><<<gemm_gx*4, 256, 0, stream>>>(h_bf, nullptr, Bt2 + (size_t)l*32768, nullptr, nullptr, nullptr, xl_bf, hres_bf);
    if (l < 2){
      aggregate<true><<<grp_blocks, 256, 0, stream>>>(xl_bf, asrc_in, adst_in, hres_bf, gbias + l*128,
                                                      offsets, srt_src, h_bf, uv + (l+1)*256, asrc_out, adst_out);
      float* t0 = asrc_in; asrc_in = asrc_out; asrc_out = t0;
      float* t1 = adst_in; adst_in = adst_out; adst_out = t1;
    } else {
      aggregate<false><<<grp_blocks, 256, 0, stream>>>(xl_bf, asrc_in, adst_in, hres_bf, gbias + l*128,
                                                       offsets, srt_src, h_bf, nullptr, nullptr, nullptr);
    }
  }

  // head
  mfma_gemm<128,2,false><<<dim3(gemm_gx,2), 256, 0, stream>>>(h_bf, nullptr, Bt_d1, db1, nullptr, nullptr, xl_bf /*g*/, nullptr);
  head2<<<grp_blocks, 256, 0, stream>>>(xl_bf /*g*/, dW2, db2, out);
}

// Round 8
// 462.888 us; speedup vs baseline: 3.2452x; 1.0181x over previous
//
#include <hip/hip_runtime.h>
#include <hip/hip_bf16.h>

#define N_NODES 50000
#define N_EDGES 600000
#define TOT_EDGES (N_EDGES + N_NODES)
#define NPB 1000     // nodes per cond row (N/B)
#define SCAN_BLK 49  // ceil(N_NODES/1024)

// prep_all block ranges
#define PREP_T0 1563                 // temb: (N+31)/32
#define PREP_T1 (PREP_T0 + 544)     // prep_weights: 139264/256
#define PREP_T2 (PREP_T1 + 3125)    // cvt_x: N*64/4/256
#define PREP_T3 (PREP_T2 + 25)      // cond_proj: 50*128/256
#define PREP_T4 (PREP_T3 + 3)       // attvec: 768/256

typedef __bf16 bf16x8 __attribute__((ext_vector_type(8)));
typedef float f32x4 __attribute__((ext_vector_type(4)));
typedef unsigned short u16x8 __attribute__((ext_vector_type(8)));

__device__ __forceinline__ float gelu_exact(float v){
  return 0.5f * v * (1.f + erff(v * 0.70710678118654752f));
}
__device__ __forceinline__ float silu(float v){
  return v / (1.f + expf(-v));
}
__device__ __forceinline__ unsigned short f2bf(float f){
  unsigned u = __builtin_bit_cast(unsigned, f);
  unsigned r = (u + 0x7FFFu + ((u >> 16) & 1u)) >> 16;
  return (unsigned short)r;
}
__device__ __forceinline__ float bf2f(unsigned short u){
  return __builtin_bit_cast(float, ((unsigned)u) << 16);
}

// ---------------- CSR build ----------------
// Pass A: count edge in-degree AND record each edge's arrival rank (atomic return).
__global__ __launch_bounds__(256) void count_deg(const int* __restrict__ adj,
                                                 int* __restrict__ counts,
                                                 int* __restrict__ rank){
  int t = blockIdx.x*256 + threadIdx.x;
  if (t >= N_EDGES/4) return;
  int j4 = t*4;
  const int4 d4 = *(const int4*)&adj[N_EDGES + j4];
  int4 r4;
  r4.x = atomicAdd(&counts[d4.x], 1);
  r4.y = atomicAdd(&counts[d4.y], 1);
  r4.z = atomicAdd(&counts[d4.z], 1);
  r4.w = atomicAdd(&counts[d4.w], 1);
  *(int4*)&rank[j4] = r4;
}

// Per-node slot count = counts[i] + 1 (self loop).
__global__ __launch_bounds__(256) void scan_part(const int* __restrict__ counts, int* __restrict__ blksum){
  int tid = threadIdx.x;
  int base = blockIdx.x*1024 + tid*4;
  int s = 0;
  #pragma unroll
  for (int k = 0; k < 4; k++){ int idx = base+k; if (idx < N_NODES) s += counts[idx] + 1; }
  #pragma unroll
  for (int off = 1; off < 64; off <<= 1) s += __shfl_xor(s, off, 64);
  __shared__ int ws[4];
  int lane = tid & 63, wid = tid >> 6;
  if (lane == 0) ws[wid] = s;
  __syncthreads();
  if (tid == 0) blksum[blockIdx.x] = ws[0]+ws[1]+ws[2]+ws[3];
}

// Computes offsets AND writes the self-loop entry srt_src[offsets[i]] = i.
__global__ __launch_bounds__(256) void scan_final(const int* __restrict__ counts,
                                                  const int* __restrict__ blksum,
                                                  int* __restrict__ offsets,
                                                  int* __restrict__ srt_src){
  int tid = threadIdx.x; int lane = tid & 63, wid = tid >> 6;
  __shared__ int ws[4];
  __shared__ int sbase;
  int base = blockIdx.x*1024 + tid*4;
  int v[4]; int s = 0;
  #pragma unroll
  for (int k = 0; k < 4; k++){ int idx = base+k; v[k] = (idx < N_NODES) ? (counts[idx] + 1) : 0; s += v[k]; }
  int x = s;
  #pragma unroll
  for (int off = 1; off < 64; off <<= 1){
    int y = __shfl_up(x, off, 64);
    if (lane >= off) x += y;
  }
  if (lane == 63) ws[wid] = x;
  if (tid < 64){
    int bv = (tid < SCAN_BLK) ? blksum[tid] : 0;
    int bx = bv;
    #pragma unroll
    for (int off = 1; off < 64; off <<= 1){
      int y = __shfl_up(bx, off, 64);
      if (tid >= off) bx += y;
    }
    int basev = (blockIdx.x == 0) ? 0 : __shfl(bx, blockIdx.x - 1, 64);
    int total = __shfl(bx, SCAN_BLK - 1, 64);
    if (tid == 0){
      sbase = basev;
      if (blockIdx.x == SCAN_BLK-1) offsets[N_NODES] = total;
    }
  }
  __syncthreads();
  int run = sbase;
  for (int q = 0; q < wid; q++) run += ws[q];
  run += x - s;   // exclusive within wave
  #pragma unroll
  for (int k = 0; k < 4; k++){
    int idx = base+k;
    if (idx < N_NODES){
      offsets[idx] = run;
      srt_src[run] = idx;   // self-loop in slot 0 of the segment
    }
    run += v[k];
  }
}

// Pass B: atomic-free scatter using precomputed rank.
__global__ __launch_bounds__(256) void scatter_edges(const int* __restrict__ adj,
                                                     const int* __restrict__ rank,
                                                     const int* __restrict__ offsets,
                                                     int* __restrict__ srt_src){
  int t = blockIdx.x*256 + threadIdx.x;
  if (t >= N_EDGES/4) return;
  int j4 = t*4;
  const int4 s4 = *(const int4*)&adj[j4];
  const int4 d4 = *(const int4*)&adj[N_EDGES + j4];
  const int4 r4 = *(const int4*)&rank[j4];
  srt_src[offsets[d4.x] + 1 + r4.x] = s4.x;
  srt_src[offsets[d4.y] + 1 + r4.y] = s4.y;
  srt_src[offsets[d4.z] + 1 + r4.z] = s4.z;
  srt_src[offsets[d4.w] + 1 + r4.w] = s4.w;
}

// ---------------- merged prep: temb + weight-prep + cvt_x + cond_proj + attvec ----------------
__global__ __launch_bounds__(256) void prep_all(const float* __restrict__ timesteps,
                                                const float* __restrict__ fw,
                                                const float* __restrict__ tW1,
                                                const float* __restrict__ tb1,
                                                unsigned short* __restrict__ hid,
                                                const float* __restrict__ linW,
                                                const float* __restrict__ resW,
                                                const float* __restrict__ tW2,
                                                const float* __restrict__ pxW,
                                                const float* __restrict__ dW1,
                                                unsigned short* __restrict__ Bt2,
                                                unsigned short* __restrict__ Bt_init,
                                                unsigned short* __restrict__ Bt_d1,
                                                const float* __restrict__ x,
                                                unsigned short* __restrict__ xbf,
                                                const float* __restrict__ cond,
                                                const float* __restrict__ pcW,
                                                const float* __restrict__ pcb,
                                                float* __restrict__ cproj,
                                                const float* __restrict__ attS,
                                                const float* __restrict__ attD,
                                                float* __restrict__ uv){
  __shared__ float sfour[32][17];
  __shared__ float sW[17][128];
  const int bid = blockIdx.x, tid = threadIdx.x;

  if (bid < PREP_T0){
    // ---- temb_hidden
    int row0 = bid * 32;
    if (tid < 32){
      int gr = row0 + tid;
      float t = (gr < N_NODES) ? timesteps[gr] : 0.f;
      sfour[tid][0] = t;
      #pragma unroll
      for (int q = 0; q < 8; q++){
        float f = t * fw[q] * 6.2831853071795864769f;
        float sv, cv;
        sincosf(f, &sv, &cv);
        sfour[tid][1+q] = sv;
        sfour[tid][9+q] = cv;
      }
    }
    for (int i = tid; i < 17*128; i += 256) sW[i>>7][i&127] = tW1[i];
    __syncthreads();
    int j = tid & 127, rg = tid >> 7;
    float b = tb1[j];
    #pragma unroll
    for (int r = 0; r < 16; r++){
      int row = rg*16 + r;
      float acc = b;
      #pragma unroll
      for (int k = 0; k < 17; k++) acc += sfour[row][k]*sW[k][j];
      int gr = row0 + row;
      if (gr < N_NODES) hid[gr*128 + j] = f2bf(silu(acc));
    }
  } else if (bid < PREP_T1){
    // ---- prep_weights
    int idx = (bid - PREP_T0)*256 + tid;
    if (idx < 98304){
      int j = idx >> 14, e = idx & 16383;
      int l = j >> 1, isres = j & 1;
      int k = e >> 7, c = e & 127;
      const float* src = (isres ? resW : linW) + l*16384;
      Bt2[(size_t)l*32768 + (size_t)(isres*128 + c)*128 + k] = f2bf(src[k*128 + c]);
    } else if (idx < 114688){
      int e = idx - 98304; int k = e >> 7, c = e & 127;
      Bt_init[c*192 + k] = f2bf(tW2[k*128 + c]);
    } else if (idx < 122880){
      int e = idx - 114688; int k = e >> 7, c = e & 127;
      Bt_init[c*192 + 128 + k] = f2bf(pxW[k*128 + c]);
    } else if (idx < 139264){
      int e = idx - 122880; int k = e >> 7, c = e & 127;
      Bt_d1[c*128 + k] = f2bf(dW1[k*128 + c]);
    }
  } else if (bid < PREP_T2){
    // ---- cvt_x (float4 -> 4 bf16)
    int i = (bid - PREP_T1)*256 + tid;   // < 800000 exactly
    float4 v = ((const float4*)x)[i];
    ushort4 o;
    o.x = f2bf(v.x); o.y = f2bf(v.y); o.z = f2bf(v.z); o.w = f2bf(v.w);
    *(ushort4*)&xbf[(size_t)i*4] = o;
  } else if (bid < PREP_T3){
    // ---- cond_proj
    int g = (bid - PREP_T2)*256 + tid;   // < 6400
    int b = g >> 7, j = g & 127;
    float acc = pcb[j];
    for (int k = 0; k < 32; k++) acc += cond[b*32+k]*pcW[k*128+j];
    cproj[b*128+j] = acc;
  } else {
    // ---- attvec
    int g = (bid - PREP_T3)*256 + tid;   // < 768
    if (g < 768){
      int l = g >> 8, s = (g >> 7) & 1, k = g & 127;
      const float* att = s ? (attD + l*128) : (attS + l*128);
      const float* row = linW + (l*128 + k)*128;
      float acc = 0.f;
      for (int j = 0; j < 128; j++) acc += row[j]*att[j];
      uv[(l*2 + s)*128 + k] = acc;
    }
  }
}

// ---------------- MFMA GEMM ----------------
// A-frag: row=lane&15, k=(lane>>4)*8+i. B-frag same from B^T. D: col=lane&15, row=(lane>>4)*4+reg.
// SWZ: flat grid, XCD-grouped. DOTS: nb==0 blocks also compute a_src/a_dst from the staged
// A tile (full 128-col h row in LDS) — replaces the standalone dotpair kernel for layer 0.
template<int KD, int EPI, bool SWZ, bool DOTS>
__global__ __launch_bounds__(256) void mfma_gemm(const unsigned short* __restrict__ A0,
                                                 const unsigned short* __restrict__ A1,
                                                 const unsigned short* __restrict__ Bt,
                                                 const float* __restrict__ bias0,
                                                 const float* __restrict__ bias1,
                                                 const float* __restrict__ cproj,
                                                 unsigned short* __restrict__ O0,
                                                 unsigned short* __restrict__ O1,
                                                 const float* __restrict__ uv_l,
                                                 float* __restrict__ a_srcO,
                                                 float* __restrict__ a_dstO){
  constexpr int CHR  = KD / 8;
  constexpr int ROWB = KD * 2;
  constexpr int KS   = KD / 32;
  __shared__ alignas(16) char sA[64 * ROWB];
  const int tid  = threadIdx.x;
  int bx, nb;
  if constexpr (SWZ){
    int id = blockIdx.x;
    int nper = gridDim.x >> 3;          // gridDim.x % 8 == 0
    int lin = (id & 7) * nper + (id >> 3);
    bx = lin >> 2; nb = lin & 3;
  } else {
    bx = blockIdx.x; nb = blockIdx.y;
  }
  const int m0   = bx * 64;
  const int lane = tid & 63, w = tid >> 6;
  const int lr   = lane & 15, lk = lane >> 4;

  bf16x8 bfr[4][KS];
  #pragma unroll
  for (int nt = 0; nt < 4; nt++){
    int c = nb*64 + nt*16 + lr;
    #pragma unroll
    for (int ks = 0; ks < KS; ks++)
      bfr[nt][ks] = *(const bf16x8*)&Bt[(size_t)c*KD + ks*32 + lk*8];
  }

  for (int i = tid; i < 64*CHR; i += 256){
    int r = i / CHR, ch = i % CHR;
    int grow = m0 + r;
    u16x8 v;
    #pragma unroll
    for (int q = 0; q < 8; q++) v[q] = 0;
    if (grow < N_NODES){
      if constexpr (KD == 128){
        v = *(const u16x8*)&A0[(size_t)grow*128 + ch*8];
      } else {
        if (ch < 16) v = *(const u16x8*)&A0[(size_t)grow*128 + ch*8];
        else         v = *(const u16x8*)&A1[(size_t)grow*64 + (ch-16)*8];
      }
    }
    *(u16x8*)&sA[r*ROWB + ((ch*16) ^ ((r & 7) << 4))] = v;
  }
  __syncthreads();

  f32x4 acc[4];
  #pragma unroll
  for (int nt = 0; nt < 4; nt++)
    #pragma unroll
    for (int q = 0; q < 4; q++) acc[nt][q] = 0.f;

  const int arow = w*16 + lr;
  #pragma unroll
  for (int ks = 0; ks < KS; ks++){
    bf16x8 a = *(const bf16x8*)&sA[arow*ROWB + ((ks*64 + lk*16) ^ ((arow & 7) << 4))];
    #pragma unroll
    for (int nt = 0; nt < 4; nt++)
      acc[nt] = __builtin_amdgcn_mfma_f32_16x16x32_bf16(a, bfr[nt][ks], acc[nt], 0, 0, 0);
  }

  if constexpr (DOTS){
    // attention dots from the staged h tile: 4 lanes per row, 32 cols each
    if (nb == 0){
      int r = tid >> 2;
      int row = m0 + r;
      if (row < N_NODES){
        float ps = 0.f, pd = 0.f;
        #pragma unroll
        for (int cc = 0; cc < 4; cc++){
          int ch = (tid & 3)*4 + cc;
          u16x8 av = *(const u16x8*)&sA[r*ROWB + ((ch*16) ^ ((r & 7) << 4))];
          int c0 = ch*8;
          const float4 u0 = *(const float4*)&uv_l[c0];
          const float4 u1 = *(const float4*)&uv_l[c0+4];
          const float4 v0 = *(const float4*)&uv_l[128+c0];
          const float4 v1 = *(const float4*)&uv_l[128+c0+4];
          const float uu[8] = {u0.x,u0.y,u0.z,u0.w,u1.x,u1.y,u1.z,u1.w};
          const float vv[8] = {v0.x,v0.y,v0.z,v0.w,v1.x,v1.y,v1.z,v1.w};
          #pragma unroll
          for (int q = 0; q < 8; q++){
            float hv = bf2f(av[q]);
            ps += hv*uu[q];
            pd += hv*vv[q];
          }
        }
        ps += __shfl_xor(ps, 1, 64); ps += __shfl_xor(ps, 2, 64);
        pd += __shfl_xor(pd, 1, 64); pd += __shfl_xor(pd, 2, 64);
        if ((tid & 3) == 0){ a_srcO[row] = ps; a_dstO[row] = pd; }
      }
    }
  }

  const int rbase = m0 + w*16 + lk*4;
  #pragma unroll
  for (int nt = 0; nt < 4; nt++){
    int c = nb*64 + nt*16 + lr;
    #pragma unroll
    for (int rg = 0; rg < 4; rg++){
      int row = rbase + rg;
      if (row >= N_NODES) continue;
      float v = acc[nt][rg];
      if constexpr (EPI == 0){
        if (c < 128) O0[(size_t)row*128 + c]       = f2bf(v);
        else         O1[(size_t)row*128 + (c-128)] = f2bf(v);
      } else if constexpr (EPI == 1){
        v += bias0[c] + bias1[c] + cproj[(row/NPB)*128 + c];
        O0[(size_t)row*128 + c] = f2bf(v);
      } else {
        v = gelu_exact(v + bias0[c]);
        O0[(size_t)row*128 + c] = f2bf(v);
      }
    }
  }
}

// ---------------- GAT aggregation: 16-lane groups; optionally fuse next-layer dots ----------------
// NOTE: a_src_o/a_dst_o MUST NOT alias a_src/a_dst (cross-block race) — double-buffered by caller.
template<bool FUSE>
__global__ __launch_bounds__(256) void aggregate(const unsigned short* __restrict__ xl,
                                                 const float* __restrict__ a_src,
                                                 const float* __restrict__ a_dst,
                                                 const unsigned short* __restrict__ hres,
                                                 const float* __restrict__ gbias_l,
                                                 const int* __restrict__ offsets,
                                                 const int* __restrict__ srt_src,
                                                 unsigned short* __restrict__ h_out,
                                                 const float* __restrict__ uv_next,
                                                 float* __restrict__ a_src_o,
                                                 float* __restrict__ a_dst_o){
  const int tid  = threadIdx.x;
  const int lane = tid & 63;
  const int l16  = lane & 15;
  const int i    = blockIdx.x*16 + (tid >> 4);   // grid exactly N/16
  const int beg  = offsets[i];
  const int deg  = offsets[i+1] - beg;
  const float adst = a_dst[i];

  // ---- phase 1: online softmax stats over 16-edge chunks
  int   s0  = 0;
  float ev0 = -INFINITY;
  if (l16 < deg){
    s0 = srt_src[beg + l16];
    float t = a_src[s0] + adst;
    ev0 = (t > 0.f) ? t : 0.2f*t;
  }
  float m = ev0;
  #pragma unroll
  for (int off = 1; off < 16; off <<= 1) m = fmaxf(m, __shfl_xor(m, off, 64));
  float den = (l16 < deg) ? __expf(ev0 - m) : 0.f;
  #pragma unroll
  for (int off = 1; off < 16; off <<= 1) den += __shfl_xor(den, off, 64);
  for (int c0 = 16; c0 < deg; c0 += 16){
    float ev = -INFINITY;
    if (c0 + l16 < deg){
      int s = srt_src[beg + c0 + l16];
      float t = a_src[s] + adst;
      ev = (t > 0.f) ? t : 0.2f*t;
    }
    float cm = ev;
    #pragma unroll
    for (int off = 1; off < 16; off <<= 1) cm = fmaxf(cm, __shfl_xor(cm, off, 64));
    if (cm > m){ den *= __expf(m - cm); m = cm; }
    float wv = (c0 + l16 < deg) ? __expf(ev - m) : 0.f;
    #pragma unroll
    for (int off = 1; off < 16; off <<= 1) wv += __shfl_xor(wv, off, 64);
    den += wv;
  }
  const float inv = 1.f / den;
  float w0 = (l16 < deg) ? __expf(ev0 - m) * inv : 0.f;

  // ---- phase 2: weighted gather (alpha pre-folded into w)
  float acc[8];
  #pragma unroll
  for (int k = 0; k < 8; k++) acc[k] = 0.f;
  const int gbb = (lane & 48) << 2;   // group-base byte addr for bpermute

  int lim0 = deg < 16 ? deg : 16;
  for (int q = 0; q < lim0; q++){
    int addr = gbb + q*4;
    int s    = __builtin_amdgcn_ds_bpermute(addr, s0);
    float wq = __builtin_bit_cast(float, __builtin_amdgcn_ds_bpermute(addr, __builtin_bit_cast(int, w0)));
    const int4 xv = *(const int4*)&xl[((size_t)s << 7) + (l16 << 3)];
    const int xd[4] = {xv.x, xv.y, xv.z, xv.w};
    #pragma unroll
    for (int k = 0; k < 4; k++){
      acc[2*k]   += wq * __builtin_bit_cast(float, xd[k] << 16);
      acc[2*k+1] += wq * __builtin_bit_cast(float, xd[k] & 0xffff0000);
    }
  }
  for (int c0 = 16; c0 < deg; c0 += 16){
    int s1 = 0; float w1 = 0.f;
    if (c0 + l16 < deg){
      s1 = srt_src[beg + c0 + l16];
      float t = a_src[s1] + adst;
      float ev = (t > 0.f) ? t : 0.2f*t;
      w1 = __expf(ev - m) * inv;
    }
    int lim = deg - c0; if (lim > 16) lim = 16;
    for (int q = 0; q < lim; q++){
      int addr = gbb + q*4;
      int s    = __builtin_amdgcn_ds_bpermute(addr, s1);
      float wq = __builtin_bit_cast(float, __builtin_amdgcn_ds_bpermute(addr, __builtin_bit_cast(int, w1)));
      const int4 xv = *(const int4*)&xl[((size_t)s << 7) + (l16 << 3)];
      const int xd[4] = {xv.x, xv.y, xv.z, xv.w};
      #pragma unroll
      for (int k = 0; k < 4; k++){
        acc[2*k]   += wq * __builtin_bit_cast(float, xd[k] << 16);
        acc[2*k+1] += wq * __builtin_bit_cast(float, xd[k] & 0xffff0000);
      }
    }
  }

  // ---- epilogue: + gbias + hres, gelu, bf16 store; optionally next-layer dots
  const int4 hr = *(const int4*)&hres[((size_t)i << 7) + (l16 << 3)];
  const int hd[4] = {hr.x, hr.y, hr.z, hr.w};
  const float4 gb0 = *(const float4*)&gbias_l[l16*8];
  const float4 gb1 = *(const float4*)&gbias_l[l16*8 + 4];
  const float gbv[8] = {gb0.x, gb0.y, gb0.z, gb0.w, gb1.x, gb1.y, gb1.z, gb1.w};
  float uu[8], vv[8];
  if constexpr (FUSE){
    const float4 a0 = *(const float4*)&uv_next[l16*8];
    const float4 a1 = *(const float4*)&uv_next[l16*8 + 4];
    const float4 b0 = *(const float4*)&uv_next[128 + l16*8];
    const float4 b1 = *(const float4*)&uv_next[128 + l16*8 + 4];
    uu[0]=a0.x; uu[1]=a0.y; uu[2]=a0.z; uu[3]=a0.w; uu[4]=a1.x; uu[5]=a1.y; uu[6]=a1.z; uu[7]=a1.w;
    vv[0]=b0.x; vv[1]=b0.y; vv[2]=b0.z; vv[3]=b0.w; vv[4]=b1.x; vv[5]=b1.y; vv[6]=b1.z; vv[7]=b1.w;
  }
  float ps = 0.f, pd = 0.f;
  int od[4];
  #pragma unroll
  for (int k = 0; k < 4; k++){
    float r0 = acc[2*k]   + gbv[2*k]   + __builtin_bit_cast(float, hd[k] << 16);
    float r1 = acc[2*k+1] + gbv[2*k+1] + __builtin_bit_cast(float, hd[k] & 0xffff0000);
    float g0 = gelu_exact(r0);
    float g1 = gelu_exact(r1);
    if constexpr (FUSE){
      ps += g0*uu[2*k] + g1*uu[2*k+1];
      pd += g0*vv[2*k] + g1*vv[2*k+1];
    }
    unsigned lo = f2bf(g0);
    unsigned hi = f2bf(g1);
    od[k] = (int)(lo | (hi << 16));
  }
  *(int4*)&h_out[((size_t)i << 7) + (l16 << 3)] = make_int4(od[0], od[1], od[2], od[3]);
  if constexpr (FUSE){
    #pragma unroll
    for (int off = 1; off < 16; off <<= 1){
      ps += __shfl_xor(ps, off, 64);
      pd += __shfl_xor(pd, off, 64);
    }
    if (l16 == 0){ a_src_o[i] = ps; a_dst_o[i] = pd; }
  }
}

// ---------------- out = g@dW2 + db2 (16-lane groups) ----------------
__global__ __launch_bounds__(256) void head2(const unsigned short* __restrict__ g,
                                             const float* __restrict__ dW2,
                                             const float* __restrict__ db2,
                                             float* __restrict__ out){
  const int tid = threadIdx.x;
  const int l16 = tid & 15;
  const int i   = blockIdx.x*16 + (tid >> 4);
  const int4 gv = *(const int4*)&g[((size_t)i << 7) + (l16 << 3)];
  const int gd[4] = {gv.x, gv.y, gv.z, gv.w};
  float wk[16];
  #pragma unroll
  for (int q = 0; q < 4; q++){
    const float4 wq = *(const float4*)&dW2[l16*16 + q*4];
    wk[q*4+0]=wq.x; wk[q*4+1]=wq.y; wk[q*4+2]=wq.z; wk[q*4+3]=wq.w;
  }
  float p0 = 0.f, p1 = 0.f;
  #pragma unroll
  for (int k = 0; k < 4; k++){
    float lo = __builtin_bit_cast(float, gd[k] << 16);
    float hi = __builtin_bit_cast(float, gd[k] & 0xffff0000);
    p0 += lo*wk[4*k+0] + hi*wk[4*k+2];
    p1 += lo*wk[4*k+1] + hi*wk[4*k+3];
  }
  #pragma unroll
  for (int off = 1; off < 16; off <<= 1){
    p0 += __shfl_xor(p0, off, 64);
    p1 += __shfl_xor(p1, off, 64);
  }
  if (l16 == 0){
    float2 o; o.x = p0 + db2[0]; o.y = p1 + db2[1];
    *(float2*)&out[i*2] = o;
  }
}

extern "C" void kernel_launch(void* const* d_in, const int* in_sizes, int n_in,
                              void* d_out, int out_size, void* d_ws, size_t ws_size,
                              hipStream_t stream) {
  const float* x   = (const float*)d_in[0];
  const int*   adj = (const int*)  d_in[1];
  const float* timesteps = (const float*)d_in[3];
  const float* cond = (const float*)d_in[4];
  const float* fw   = (const float*)d_in[5];
  const float* tW1  = (const float*)d_in[6];
  const float* tb1  = (const float*)d_in[7];
  const float* tW2  = (const float*)d_in[8];
  const float* tb2  = (const float*)d_in[9];
  const float* pxW  = (const float*)d_in[10];
  const float* pxb  = (const float*)d_in[11];
  const float* pcW  = (const float*)d_in[12];
  const float* pcb  = (const float*)d_in[13];
  const float* linW = (const float*)d_in[14];
  const float* attS = (const float*)d_in[15];
  const float* attD = (const float*)d_in[16];
  const float* gbias= (const float*)d_in[17];
  const float* resW = (const float*)d_in[18];
  const float* dW1  = (const float*)d_in[19];
  const float* db1  = (const float*)d_in[20];
  const float* dW2  = (const float*)d_in[21];
  const float* db2  = (const float*)d_in[22];
  float* out = (float*)d_out;

  char* w = (char*)d_ws;
  size_t off = 0;
  auto carve = [&](size_t bytes) -> void* {
    void* p = w + off;
    off = (off + bytes + 255) & ~(size_t)255;
    return p;
  };
  unsigned short* h_bf    = (unsigned short*)carve((size_t)N_NODES*128*2);
  unsigned short* xl_bf   = (unsigned short*)carve((size_t)N_NODES*128*2); // also hid_bf, also g_bf
  unsigned short* hres_bf = (unsigned short*)carve((size_t)N_NODES*128*2);
  unsigned short* x_bf    = (unsigned short*)carve((size_t)N_NODES*64*2);
  float* a_src0 = (float*)carve((size_t)N_NODES*4);
  float* a_dst0 = (float*)carve((size_t)N_NODES*4);
  float* a_src1 = (float*)carve((size_t)N_NODES*4);
  float* a_dst1 = (float*)carve((size_t)N_NODES*4);
  float* cproj = (float*)carve(50*128*4);
  float* uv    = (float*)carve(6*128*4);
  int* counts  = (int*)carve((size_t)N_NODES*4);
  int* rank    = (int*)carve((size_t)N_EDGES*4);
  int* offsets = (int*)carve((size_t)(N_NODES+1)*4);
  int* srt_src = (int*)carve((size_t)TOT_EDGES*4);
  int* blksum  = (int*)carve(SCAN_BLK*4);
  unsigned short* Bt2     = (unsigned short*)carve((size_t)3*256*128*2);
  unsigned short* Bt_init = (unsigned short*)carve((size_t)128*192*2);
  unsigned short* Bt_d1   = (unsigned short*)carve((size_t)128*128*2);
  (void)ws_size; (void)in_sizes; (void)n_in; (void)out_size;

  const int edge4_blocks = (N_EDGES/4 + 255)/256;    // 586
  const int gemm_gx      = (N_NODES + 63)/64;         // 782
  const int grp_blocks   = N_NODES/16;                // 3125

  // CSR build (atomic count+rank, scan with implicit self-loop, atomic-free scatter)
  hipMemsetAsync(counts, 0, (size_t)N_NODES*4, stream);
  count_deg<<<edge4_blocks, 256, 0, stream>>>(adj, counts, rank);
  scan_part<<<SCAN_BLK, 256, 0, stream>>>(counts, blksum);
  scan_final<<<SCAN_BLK, 256, 0, stream>>>(counts, blksum, offsets, srt_src);
  scatter_edges<<<edge4_blocks, 256, 0, stream>>>(adj, rank, offsets, srt_src);

  // merged prep (temb + weights + cvt_x + cond_proj + attvec)
  prep_all<<<PREP_T4, 256, 0, stream>>>(timesteps, fw, tW1, tb1, xl_bf /*hid*/,
                                        linW, resW, tW2, pxW, dW1, Bt2, Bt_init, Bt_d1,
                                        x, x_bf, cond, pcW, pcb, cproj, attS, attD, uv);

  // initial h = [hid | x] @ [tW2 ; pxW] + biases + cproj
  mfma_gemm<192,1,false,false><<<dim3(gemm_gx,2), 256, 0, stream>>>(xl_bf /*hid*/, x_bf, Bt_init, tb2, pxb, cproj, h_bf, nullptr, nullptr, nullptr, nullptr);

  // GAT layers; layer-0 gemm also computes the layer-0 attention dots from staged h.
  // Logit buffers double-buffered across layers (cross-block race avoidance).
  float* asrc_in = a_src0; float* adst_in = a_dst0;
  float* asrc_out = a_src1; float* adst_out = a_dst1;
  for (int l = 0; l < 3; l++){
    if (l == 0){
      mfma_gemm<128,0,true,true><<<gemm_gx*4, 256, 0, stream>>>(h_bf, nullptr, Bt2, nullptr, nullptr, nullptr, xl_bf, hres_bf, uv, asrc_in, adst_in);
    } else {
      mfma_gemm<128,0,true,false><<<gemm_gx*4, 256, 0, stream>>>(h_bf, nullptr, Bt2 + (size_t)l*32768, nullptr, nullptr, nullptr, xl_bf, hres_bf, nullptr, nullptr, nullptr);
    }
    if (l < 2){
      aggregate<true><<<grp_blocks, 256, 0, stream>>>(xl_bf, asrc_in, adst_in, hres_bf, gbias + l*128,
                                                      offsets, srt_src, h_bf, uv + (l+1)*256, asrc_out, adst_out);
      float* t0 = asrc_in; asrc_in = asrc_out; asrc_out = t0;
      float* t1 = adst_in; adst_in = adst_out; adst_out = t1;
    } else {
      aggregate<false><<<grp_blocks, 256, 0, stream>>>(xl_bf, asrc_in, adst_in, hres_bf, gbias + l*128,
                                                       offsets, srt_src, h_bf, nullptr, nullptr, nullptr);
    }
  }

  // head
  mfma_gemm<128,2,false,false><<<dim3(gemm_gx,2), 256, 0, stream>>>(h_bf, nullptr, Bt_d1, db1, nullptr, nullptr, xl_bf /*g*/, nullptr, nullptr, nullptr, nullptr);
  head2<<<grp_blocks, 256, 0, stream>>>(xl_bf /*g*/, dW2, db2, out);
}

// Round 10
// 409.663 us; speedup vs baseline: 3.6668x; 1.1299x over previous
//
#include <hip/hip_runtime.h>
#include <hip/hip_bf16.h>

#define N_NODES 50000
#define N_EDGES 600000
#define TOT_EDGES (N_EDGES + N_NODES)
#define NPB 1000     // nodes per cond row (N/B)
#define SCAN_BLK 49  // ceil(N_NODES/1024)

// prep_all block ranges
#define PREP_T0 1563                 // temb: (N+31)/32
#define PREP_T1 (PREP_T0 + 544)     // prep_weights: 139264/256
#define PREP_T2 (PREP_T1 + 3125)    // cvt_x: N*64/4/256
#define PREP_T3 (PREP_T2 + 25)      // cond_proj: 50*128/256
#define PREP_T4 (PREP_T3 + 3)       // attvec: 768/256

typedef __bf16 bf16x8 __attribute__((ext_vector_type(8)));
typedef float f32x4 __attribute__((ext_vector_type(4)));
typedef unsigned short u16x8 __attribute__((ext_vector_type(8)));

__device__ __forceinline__ float gelu_exact(float v){
  return 0.5f * v * (1.f + erff(v * 0.70710678118654752f));
}
__device__ __forceinline__ float silu(float v){
  return v / (1.f + expf(-v));
}
__device__ __forceinline__ unsigned short f2bf(float f){
  unsigned u = __builtin_bit_cast(unsigned, f);
  unsigned r = (u + 0x7FFFu + ((u >> 16) & 1u)) >> 16;
  return (unsigned short)r;
}
__device__ __forceinline__ float bf2f(unsigned short u){
  return __builtin_bit_cast(float, ((unsigned)u) << 16);
}

// ---------------- CSR build ----------------
// Pass A: count edge in-degree AND record each edge's arrival rank (atomic return).
__global__ __launch_bounds__(256) void count_deg(const int* __restrict__ adj,
                                                 int* __restrict__ counts,
                                                 int* __restrict__ rank){
  int t = blockIdx.x*256 + threadIdx.x;
  if (t >= N_EDGES/4) return;
  int j4 = t*4;
  const int4 d4 = *(const int4*)&adj[N_EDGES + j4];
  int4 r4;
  r4.x = atomicAdd(&counts[d4.x], 1);
  r4.y = atomicAdd(&counts[d4.y], 1);
  r4.z = atomicAdd(&counts[d4.z], 1);
  r4.w = atomicAdd(&counts[d4.w], 1);
  *(int4*)&rank[j4] = r4;
}

// Per-node slot count = counts[i] + 1 (self loop).
__global__ __launch_bounds__(256) void scan_part(const int* __restrict__ counts, int* __restrict__ blksum){
  int tid = threadIdx.x;
  int base = blockIdx.x*1024 + tid*4;
  int s = 0;
  #pragma unroll
  for (int k = 0; k < 4; k++){ int idx = base+k; if (idx < N_NODES) s += counts[idx] + 1; }
  #pragma unroll
  for (int off = 1; off < 64; off <<= 1) s += __shfl_xor(s, off, 64);
  __shared__ int ws[4];
  int lane = tid & 63, wid = tid >> 6;
  if (lane == 0) ws[wid] = s;
  __syncthreads();
  if (tid == 0) blksum[blockIdx.x] = ws[0]+ws[1]+ws[2]+ws[3];
}

// Computes offsets AND writes the self-loop entry srt_src[offsets[i]] = i.
__global__ __launch_bounds__(256) void scan_final(const int* __restrict__ counts,
                                                  const int* __restrict__ blksum,
                                                  int* __restrict__ offsets,
                                                  int* __restrict__ srt_src){
  int tid = threadIdx.x; int lane = tid & 63, wid = tid >> 6;
  __shared__ int ws[4];
  __shared__ int sbase;
  int base = blockIdx.x*1024 + tid*4;
  int v[4]; int s = 0;
  #pragma unroll
  for (int k = 0; k < 4; k++){ int idx = base+k; v[k] = (idx < N_NODES) ? (counts[idx] + 1) : 0; s += v[k]; }
  int x = s;
  #pragma unroll
  for (int off = 1; off < 64; off <<= 1){
    int y = __shfl_up(x, off, 64);
    if (lane >= off) x += y;
  }
  if (lane == 63) ws[wid] = x;
  if (tid < 64){
    int bv = (tid < SCAN_BLK) ? blksum[tid] : 0;
    int bx = bv;
    #pragma unroll
    for (int off = 1; off < 64; off <<= 1){
      int y = __shfl_up(bx, off, 64);
      if (tid >= off) bx += y;
    }
    int basev = (blockIdx.x == 0) ? 0 : __shfl(bx, blockIdx.x - 1, 64);
    int total = __shfl(bx, SCAN_BLK - 1, 64);
    if (tid == 0){
      sbase = basev;
      if (blockIdx.x == SCAN_BLK-1) offsets[N_NODES] = total;
    }
  }
  __syncthreads();
  int run = sbase;
  for (int q = 0; q < wid; q++) run += ws[q];
  run += x - s;   // exclusive within wave
  #pragma unroll
  for (int k = 0; k < 4; k++){
    int idx = base+k;
    if (idx < N_NODES){
      offsets[idx] = run;
      srt_src[run] = idx;   // self-loop in slot 0 of the segment
    }
    run += v[k];
  }
}

// Pass B: atomic-free scatter using precomputed rank.
__global__ __launch_bounds__(256) void scatter_edges(const int* __restrict__ adj,
                                                     const int* __restrict__ rank,
                                                     const int* __restrict__ offsets,
                                                     int* __restrict__ srt_src){
  int t = blockIdx.x*256 + threadIdx.x;
  if (t >= N_EDGES/4) return;
  int j4 = t*4;
  const int4 s4 = *(const int4*)&adj[j4];
  const int4 d4 = *(const int4*)&adj[N_EDGES + j4];
  const int4 r4 = *(const int4*)&rank[j4];
  srt_src[offsets[d4.x] + 1 + r4.x] = s4.x;
  srt_src[offsets[d4.y] + 1 + r4.y] = s4.y;
  srt_src[offsets[d4.z] + 1 + r4.z] = s4.z;
  srt_src[offsets[d4.w] + 1 + r4.w] = s4.w;
}

// ---------------- merged prep: temb + weight-prep + cvt_x + cond_proj + attvec ----------------
__global__ __launch_bounds__(256) void prep_all(const float* __restrict__ timesteps,
                                                const float* __restrict__ fw,
                                                const float* __restrict__ tW1,
                                                const float* __restrict__ tb1,
                                                unsigned short* __restrict__ hid,
                                                const float* __restrict__ linW,
                                                const float* __restrict__ resW,
                                                const float* __restrict__ tW2,
                                                const float* __restrict__ pxW,
                                                const float* __restrict__ dW1,
                                                unsigned short* __restrict__ Bt2,
                                                unsigned short* __restrict__ Bt_init,
                                                unsigned short* __restrict__ Bt_d1,
                                                const float* __restrict__ x,
                                                unsigned short* __restrict__ xbf,
                                                const float* __restrict__ cond,
                                                const float* __restrict__ pcW,
                                                const float* __restrict__ pcb,
                                                float* __restrict__ cproj,
                                                const float* __restrict__ attS,
                                                const float* __restrict__ attD,
                                                float* __restrict__ uv){
  __shared__ float sfour[32][17];
  __shared__ float sW[17][128];
  const int bid = blockIdx.x, tid = threadIdx.x;

  if (bid < PREP_T0){
    // ---- temb_hidden
    int row0 = bid * 32;
    if (tid < 32){
      int gr = row0 + tid;
      float t = (gr < N_NODES) ? timesteps[gr] : 0.f;
      sfour[tid][0] = t;
      #pragma unroll
      for (int q = 0; q < 8; q++){
        float f = t * fw[q] * 6.2831853071795864769f;
        float sv, cv;
        sincosf(f, &sv, &cv);
        sfour[tid][1+q] = sv;
        sfour[tid][9+q] = cv;
      }
    }
    for (int i = tid; i < 17*128; i += 256) sW[i>>7][i&127] = tW1[i];
    __syncthreads();
    int j = tid & 127, rg = tid >> 7;
    float b = tb1[j];
    #pragma unroll
    for (int r = 0; r < 16; r++){
      int row = rg*16 + r;
      float acc = b;
      #pragma unroll
      for (int k = 0; k < 17; k++) acc += sfour[row][k]*sW[k][j];
      int gr = row0 + row;
      if (gr < N_NODES) hid[gr*128 + j] = f2bf(silu(acc));
    }
  } else if (bid < PREP_T1){
    // ---- prep_weights
    int idx = (bid - PREP_T0)*256 + tid;
    if (idx < 98304){
      int j = idx >> 14, e = idx & 16383;
      int l = j >> 1, isres = j & 1;
      int k = e >> 7, c = e & 127;
      const float* src = (isres ? resW : linW) + l*16384;
      Bt2[(size_t)l*32768 + (size_t)(isres*128 + c)*128 + k] = f2bf(src[k*128 + c]);
    } else if (idx < 114688){
      int e = idx - 98304; int k = e >> 7, c = e & 127;
      Bt_init[c*192 + k] = f2bf(tW2[k*128 + c]);
    } else if (idx < 122880){
      int e = idx - 114688; int k = e >> 7, c = e & 127;
      Bt_init[c*192 + 128 + k] = f2bf(pxW[k*128 + c]);
    } else if (idx < 139264){
      int e = idx - 122880; int k = e >> 7, c = e & 127;
      Bt_d1[c*128 + k] = f2bf(dW1[k*128 + c]);
    }
  } else if (bid < PREP_T2){
    // ---- cvt_x (float4 -> 4 bf16)
    int i = (bid - PREP_T1)*256 + tid;   // < 800000 exactly
    float4 v = ((const float4*)x)[i];
    ushort4 o;
    o.x = f2bf(v.x); o.y = f2bf(v.y); o.z = f2bf(v.z); o.w = f2bf(v.w);
    *(ushort4*)&xbf[(size_t)i*4] = o;
  } else if (bid < PREP_T3){
    // ---- cond_proj
    int g = (bid - PREP_T2)*256 + tid;   // < 6400
    int b = g >> 7, j = g & 127;
    float acc = pcb[j];
    for (int k = 0; k < 32; k++) acc += cond[b*32+k]*pcW[k*128+j];
    cproj[b*128+j] = acc;
  } else {
    // ---- attvec
    int g = (bid - PREP_T3)*256 + tid;   // < 768
    if (g < 768){
      int l = g >> 8, s = (g >> 7) & 1, k = g & 127;
      const float* att = s ? (attD + l*128) : (attS + l*128);
      const float* row = linW + (l*128 + k)*128;
      float acc = 0.f;
      for (int j = 0; j < 128; j++) acc += row[j]*att[j];
      uv[(l*2 + s)*128 + k] = acc;
    }
  }
}

// ---------------- MFMA GEMM: one block per 64-row tile, ALL NC cols ----------------
// A-frag: row=lane&15, k=(lane>>4)*8+i. B-frag same from B^T row = output col.
// D: col=lane&15, row=(lane>>4)*4+reg. A and B both LDS-staged with XOR swizzle
// byte ^= (row&7)<<4 (G4). Per wave: NT*KS MFMAs fed from LDS; A-frags in regs.
// DOTS: every block computes a_src/a_dst for its 64 rows from the staged A tile.
template<int KD, int NC, int EPI, bool DOTS>
__global__ __launch_bounds__(256) void mfma_gemm(const unsigned short* __restrict__ A0,
                                                 const unsigned short* __restrict__ A1,
                                                 const unsigned short* __restrict__ Bt,
                                                 const float* __restrict__ bias0,
                                                 const float* __restrict__ bias1,
                                                 const float* __restrict__ cproj,
                                                 unsigned short* __restrict__ O0,
                                                 unsigned short* __restrict__ O1,
                                                 const float* __restrict__ uv_l,
                                                 float* __restrict__ a_srcO,
                                                 float* __restrict__ a_dstO){
  constexpr int CHR  = KD / 8;    // 16B chunks per row
  constexpr int ROWB = KD * 2;    // bytes per row
  constexpr int KS   = KD / 32;   // mfma k-steps
  constexpr int NT   = NC / 16;   // 16-col groups
  __shared__ alignas(16) char sA[64 * ROWB];
  __shared__ alignas(16) char sB[NC * ROWB];
  const int tid  = threadIdx.x;
  const int m0   = blockIdx.x * 64;
  const int lane = tid & 63, w = tid >> 6;
  const int lr   = lane & 15, lk = lane >> 4;

  // stage A tile (64 rows x KD bf16)
  for (int i = tid; i < 64*CHR; i += 256){
    int r = i / CHR, ch = i % CHR;
    int grow = m0 + r;
    u16x8 v;
    #pragma unroll
    for (int q = 0; q < 8; q++) v[q] = 0;
    if (grow < N_NODES){
      if constexpr (KD == 128){
        v = *(const u16x8*)&A0[(size_t)grow*128 + ch*8];
      } else {
        if (ch < 16) v = *(const u16x8*)&A0[(size_t)grow*128 + ch*8];
        else         v = *(const u16x8*)&A1[(size_t)grow*64 + (ch-16)*8];
      }
    }
    *(u16x8*)&sA[r*ROWB + ((ch*16) ^ ((r & 7) << 4))] = v;
  }
  // stage B (NC rows x KD bf16), same swizzle
  for (int i = tid; i < NC*CHR; i += 256){
    int r = i / CHR, ch = i % CHR;
    u16x8 v = *(const u16x8*)&Bt[(size_t)r*KD + ch*8];
    *(u16x8*)&sB[r*ROWB + ((ch*16) ^ ((r & 7) << 4))] = v;
  }
  __syncthreads();

  // A-frags in registers for the whole block
  bf16x8 afr[KS];
  const int arow = w*16 + lr;
  #pragma unroll
  for (int ks = 0; ks < KS; ks++)
    afr[ks] = *(const bf16x8*)&sA[arow*ROWB + ((ks*64 + lk*16) ^ ((arow & 7) << 4))];

  f32x4 acc[NT];
  #pragma unroll
  for (int nt = 0; nt < NT; nt++)
    #pragma unroll
    for (int q = 0; q < 4; q++) acc[nt][q] = 0.f;

  #pragma unroll
  for (int nt = 0; nt < NT; nt++){
    const int brow = nt*16 + lr;
    #pragma unroll
    for (int ks = 0; ks < KS; ks++){
      bf16x8 b = *(const bf16x8*)&sB[brow*ROWB + ((ks*64 + lk*16) ^ ((brow & 7) << 4))];
      acc[nt] = __builtin_amdgcn_mfma_f32_16x16x32_bf16(afr[ks], b, acc[nt], 0, 0, 0);
    }
  }

  if constexpr (DOTS){
    // attention dots from the staged h tile: 4 lanes per row, 32 cols each
    int r = tid >> 2;
    int row = m0 + r;
    if (row < N_NODES){
      float ps = 0.f, pd = 0.f;
      #pragma unroll
      for (int cc = 0; cc < 4; cc++){
        int ch = (tid & 3)*4 + cc;
        u16x8 av = *(const u16x8*)&sA[r*ROWB + ((ch*16) ^ ((r & 7) << 4))];
        int c0 = ch*8;
        const float4 u0 = *(const float4*)&uv_l[c0];
        const float4 u1 = *(const float4*)&uv_l[c0+4];
        const float4 v0 = *(const float4*)&uv_l[128+c0];
        const float4 v1 = *(const float4*)&uv_l[128+c0+4];
        const float uu[8] = {u0.x,u0.y,u0.z,u0.w,u1.x,u1.y,u1.z,u1.w};
        const float vv[8] = {v0.x,v0.y,v0.z,v0.w,v1.x,v1.y,v1.z,v1.w};
        #pragma unroll
        for (int q = 0; q < 8; q++){
          float hv = bf2f(av[q]);
          ps += hv*uu[q];
          pd += hv*vv[q];
        }
      }
      ps += __shfl_xor(ps, 1, 64); ps += __shfl_xor(ps, 2, 64);
      pd += __shfl_xor(pd, 1, 64); pd += __shfl_xor(pd, 2, 64);
      if ((tid & 3) == 0){ a_srcO[row] = ps; a_dstO[row] = pd; }
    }
  }

  const int rbase = m0 + w*16 + lk*4;
  #pragma unroll
  for (int nt = 0; nt < NT; nt++){
    int c = nt*16 + lr;
    #pragma unroll
    for (int rg = 0; rg < 4; rg++){
      int row = rbase + rg;
      if (row >= N_NODES) continue;
      float v = acc[nt][rg];
      if constexpr (EPI == 0){
        if (c < 128) O0[(size_t)row*128 + c]       = f2bf(v);
        else         O1[(size_t)row*128 + (c-128)] = f2bf(v);
      } else if constexpr (EPI == 1){
        v += bias0[c] + bias1[c] + cproj[(row/NPB)*128 + c];
        O0[(size_t)row*128 + c] = f2bf(v);
      } else {
        v = gelu_exact(v + bias0[c]);
        O0[(size_t)row*128 + c] = f2bf(v);
      }
    }
  }
}

// ---------------- GAT aggregation: 16-lane groups; optionally fuse next-layer dots ----------------
// NOTE: a_src_o/a_dst_o MUST NOT alias a_src/a_dst (cross-block race) — double-buffered by caller.
template<bool FUSE>
__global__ __launch_bounds__(256) void aggregate(const unsigned short* __restrict__ xl,
                                                 const float* __restrict__ a_src,
                                                 const float* __restrict__ a_dst,
                                                 const unsigned short* __restrict__ hres,
                                                 const float* __restrict__ gbias_l,
                                                 const int* __restrict__ offsets,
                                                 const int* __restrict__ srt_src,
                                                 unsigned short* __restrict__ h_out,
                                                 const float* __restrict__ uv_next,
                                                 float* __restrict__ a_src_o,
                                                 float* __restrict__ a_dst_o){
  const int tid  = threadIdx.x;
  const int lane = tid & 63;
  const int l16  = lane & 15;
  const int i    = blockIdx.x*16 + (tid >> 4);   // grid exactly N/16
  const int beg  = offsets[i];
  const int deg  = offsets[i+1] - beg;
  const float adst = a_dst[i];

  // ---- phase 1: online softmax stats over 16-edge chunks
  int   s0  = 0;
  float ev0 = -INFINITY;
  if (l16 < deg){
    s0 = srt_src[beg + l16];
    float t = a_src[s0] + adst;
    ev0 = (t > 0.f) ? t : 0.2f*t;
  }
  float m = ev0;
  #pragma unroll
  for (int off = 1; off < 16; off <<= 1) m = fmaxf(m, __shfl_xor(m, off, 64));
  float den = (l16 < deg) ? __expf(ev0 - m) : 0.f;
  #pragma unroll
  for (int off = 1; off < 16; off <<= 1) den += __shfl_xor(den, off, 64);
  for (int c0 = 16; c0 < deg; c0 += 16){
    float ev = -INFINITY;
    if (c0 + l16 < deg){
      int s = srt_src[beg + c0 + l16];
      float t = a_src[s] + adst;
      ev = (t > 0.f) ? t : 0.2f*t;
    }
    float cm = ev;
    #pragma unroll
    for (int off = 1; off < 16; off <<= 1) cm = fmaxf(cm, __shfl_xor(cm, off, 64));
    if (cm > m){ den *= __expf(m - cm); m = cm; }
    float wv = (c0 + l16 < deg) ? __expf(ev - m) : 0.f;
    #pragma unroll
    for (int off = 1; off < 16; off <<= 1) wv += __shfl_xor(wv, off, 64);
    den += wv;
  }
  const float inv = 1.f / den;
  float w0 = (l16 < deg) ? __expf(ev0 - m) * inv : 0.f;

  // ---- phase 2: weighted gather (alpha pre-folded into w)
  float acc[8];
  #pragma unroll
  for (int k = 0; k < 8; k++) acc[k] = 0.f;
  const int gbb = (lane & 48) << 2;   // group-base byte addr for bpermute

  int lim0 = deg < 16 ? deg : 16;
  for (int q = 0; q < lim0; q++){
    int addr = gbb + q*4;
    int s    = __builtin_amdgcn_ds_bpermute(addr, s0);
    float wq = __builtin_bit_cast(float, __builtin_amdgcn_ds_bpermute(addr, __builtin_bit_cast(int, w0)));
    const int4 xv = *(const int4*)&xl[((size_t)s << 7) + (l16 << 3)];
    const int xd[4] = {xv.x, xv.y, xv.z, xv.w};
    #pragma unroll
    for (int k = 0; k < 4; k++){
      acc[2*k]   += wq * __builtin_bit_cast(float, xd[k] << 16);
      acc[2*k+1] += wq * __builtin_bit_cast(float, xd[k] & 0xffff0000);
    }
  }
  for (int c0 = 16; c0 < deg; c0 += 16){
    int s1 = 0; float w1 = 0.f;
    if (c0 + l16 < deg){
      s1 = srt_src[beg + c0 + l16];
      float t = a_src[s1] + adst;
      float ev = (t > 0.f) ? t : 0.2f*t;
      w1 = __expf(ev - m) * inv;
    }
    int lim = deg - c0; if (lim > 16) lim = 16;
    for (int q = 0; q < lim; q++){
      int addr = gbb + q*4;
      int s    = __builtin_amdgcn_ds_bpermute(addr, s1);
      float wq = __builtin_bit_cast(float, __builtin_amdgcn_ds_bpermute(addr, __builtin_bit_cast(int, w1)));
      const int4 xv = *(const int4*)&xl[((size_t)s << 7) + (l16 << 3)];
      const int xd[4] = {xv.x, xv.y, xv.z, xv.w};
      #pragma unroll
      for (int k = 0; k < 4; k++){
        acc[2*k]   += wq * __builtin_bit_cast(float, xd[k] << 16);
        acc[2*k+1] += wq * __builtin_bit_cast(float, xd[k] & 0xffff0000);
      }
    }
  }

  // ---- epilogue: + gbias + hres, gelu, bf16 store; optionally next-layer dots
  const int4 hr = *(const int4*)&hres[((size_t)i << 7) + (l16 << 3)];
  const int hd[4] = {hr.x, hr.y, hr.z, hr.w};
  const float4 gb0 = *(const float4*)&gbias_l[l16*8];
  const float4 gb1 = *(const float4*)&gbias_l[l16*8 + 4];
  const float gbv[8] = {gb0.x, gb0.y, gb0.z, gb0.w, gb1.x, gb1.y, gb1.z, gb1.w};
  float uu[8], vv[8];
  if constexpr (FUSE){
    const float4 a0 = *(const float4*)&uv_next[l16*8];
    const float4 a1 = *(const float4*)&uv_next[l16*8 + 4];
    const float4 b0 = *(const float4*)&uv_next[128 + l16*8];
    const float4 b1 = *(const float4*)&uv_next[128 + l16*8 + 4];
    uu[0]=a0.x; uu[1]=a0.y; uu[2]=a0.z; uu[3]=a0.w; uu[4]=a1.x; uu[5]=a1.y; uu[6]=a1.z; uu[7]=a1.w;
    vv[0]=b0.x; vv[1]=b0.y; vv[2]=b0.z; vv[3]=b0.w; vv[4]=b1.x; vv[5]=b1.y; vv[6]=b1.z; vv[7]=b1.w;
  }
  float ps = 0.f, pd = 0.f;
  int od[4];
  #pragma unroll
  for (int k = 0; k < 4; k++){
    float r0 = acc[2*k]   + gbv[2*k]   + __builtin_bit_cast(float, hd[k] << 16);
    float r1 = acc[2*k+1] + gbv[2*k+1] + __builtin_bit_cast(float, hd[k] & 0xffff0000);
    float g0 = gelu_exact(r0);
    float g1 = gelu_exact(r1);
    if constexpr (FUSE){
      ps += g0*uu[2*k] + g1*uu[2*k+1];
      pd += g0*vv[2*k] + g1*vv[2*k+1];
    }
    unsigned lo = f2bf(g0);
    unsigned hi = f2bf(g1);
    od[k] = (int)(lo | (hi << 16));
  }
  *(int4*)&h_out[((size_t)i << 7) + (l16 << 3)] = make_int4(od[0], od[1], od[2], od[3]);
  if constexpr (FUSE){
    #pragma unroll
    for (int off = 1; off < 16; off <<= 1){
      ps += __shfl_xor(ps, off, 64);
      pd += __shfl_xor(pd, off, 64);
    }
    if (l16 == 0){ a_src_o[i] = ps; a_dst_o[i] = pd; }
  }
}

// ---------------- out = g@dW2 + db2 (16-lane groups) ----------------
__global__ __launch_bounds__(256) void head2(const unsigned short* __restrict__ g,
                                             const float* __restrict__ dW2,
                                             const float* __restrict__ db2,
                                             float* __restrict__ out){
  const int tid = threadIdx.x;
  const int l16 = tid & 15;
  const int i   = blockIdx.x*16 + (tid >> 4);
  const int4 gv = *(const int4*)&g[((size_t)i << 7) + (l16 << 3)];
  const int gd[4] = {gv.x, gv.y, gv.z, gv.w};
  float wk[16];
  #pragma unroll
  for (int q = 0; q < 4; q++){
    const float4 wq = *(const float4*)&dW2[l16*16 + q*4];
    wk[q*4+0]=wq.x; wk[q*4+1]=wq.y; wk[q*4+2]=wq.z; wk[q*4+3]=wq.w;
  }
  float p0 = 0.f, p1 = 0.f;
  #pragma unroll
  for (int k = 0; k < 4; k++){
    float lo = __builtin_bit_cast(float, gd[k] << 16);
    float hi = __builtin_bit_cast(float, gd[k] & 0xffff0000);
    p0 += lo*wk[4*k+0] + hi*wk[4*k+2];
    p1 += lo*wk[4*k+1] + hi*wk[4*k+3];
  }
  #pragma unroll
  for (int off = 1; off < 16; off <<= 1){
    p0 += __shfl_xor(p0, off, 64);
    p1 += __shfl_xor(p1, off, 64);
  }
  if (l16 == 0){
    float2 o; o.x = p0 + db2[0]; o.y = p1 + db2[1];
    *(float2*)&out[i*2] = o;
  }
}

extern "C" void kernel_launch(void* const* d_in, const int* in_sizes, int n_in,
                              void* d_out, int out_size, void* d_ws, size_t ws_size,
                              hipStream_t stream) {
  const float* x   = (const float*)d_in[0];
  const int*   adj = (const int*)  d_in[1];
  const float* timesteps = (const float*)d_in[3];
  const float* cond = (const float*)d_in[4];
  const float* fw   = (const float*)d_in[5];
  const float* tW1  = (const float*)d_in[6];
  const float* tb1  = (const float*)d_in[7];
  const float* tW2  = (const float*)d_in[8];
  const float* tb2  = (const float*)d_in[9];
  const float* pxW  = (const float*)d_in[10];
  const float* pxb  = (const float*)d_in[11];
  const float* pcW  = (const float*)d_in[12];
  const float* pcb  = (const float*)d_in[13];
  const float* linW = (const float*)d_in[14];
  const float* attS = (const float*)d_in[15];
  const float* attD = (const float*)d_in[16];
  const float* gbias= (const float*)d_in[17];
  const float* resW = (const float*)d_in[18];
  const float* dW1  = (const float*)d_in[19];
  const float* db1  = (const float*)d_in[20];
  const float* dW2  = (const float*)d_in[21];
  const float* db2  = (const float*)d_in[22];
  float* out = (float*)d_out;

  char* w = (char*)d_ws;
  size_t off = 0;
  auto carve = [&](size_t bytes) -> void* {
    void* p = w + off;
    off = (off + bytes + 255) & ~(size_t)255;
    return p;
  };
  unsigned short* h_bf    = (unsigned short*)carve((size_t)N_NODES*128*2);
  unsigned short* xl_bf   = (unsigned short*)carve((size_t)N_NODES*128*2); // also hid_bf, also g_bf
  unsigned short* hres_bf = (unsigned short*)carve((size_t)N_NODES*128*2);
  unsigned short* x_bf    = (unsigned short*)carve((size_t)N_NODES*64*2);
  float* a_src0 = (float*)carve((size_t)N_NODES*4);
  float* a_dst0 = (float*)carve((size_t)N_NODES*4);
  float* a_src1 = (float*)carve((size_t)N_NODES*4);
  float* a_dst1 = (float*)carve((size_t)N_NODES*4);
  float* cproj = (float*)carve(50*128*4);
  float* uv    = (float*)carve(6*128*4);
  int* counts  = (int*)carve((size_t)N_NODES*4);
  int* rank    = (int*)carve((size_t)N_EDGES*4);
  int* offsets = (int*)carve((size_t)(N_NODES+1)*4);
  int* srt_src = (int*)carve((size_t)TOT_EDGES*4);
  int* blksum  = (int*)carve(SCAN_BLK*4);
  unsigned short* Bt2     = (unsigned short*)carve((size_t)3*256*128*2);
  unsigned short* Bt_init = (unsigned short*)carve((size_t)128*192*2);
  unsigned short* Bt_d1   = (unsigned short*)carve((size_t)128*128*2);
  (void)ws_size; (void)in_sizes; (void)n_in; (void)out_size;

  const int edge4_blocks = (N_EDGES/4 + 255)/256;    // 586
  const int gemm_gx      = (N_NODES + 63)/64;         // 782
  const int grp_blocks   = N_NODES/16;                // 3125

  // CSR build (atomic count+rank, scan with implicit self-loop, atomic-free scatter)
  hipMemsetAsync(counts, 0, (size_t)N_NODES*4, stream);
  count_deg<<<edge4_blocks, 256, 0, stream>>>(adj, counts, rank);
  scan_part<<<SCAN_BLK, 256, 0, stream>>>(counts, blksum);
  scan_final<<<SCAN_BLK, 256, 0, stream>>>(counts, blksum, offsets, srt_src);
  scatter_edges<<<edge4_blocks, 256, 0, stream>>>(adj, rank, offsets, srt_src);

  // merged prep (temb + weights + cvt_x + cond_proj + attvec)
  prep_all<<<PREP_T4, 256, 0, stream>>>(timesteps, fw, tW1, tb1, xl_bf /*hid*/,
                                        linW, resW, tW2, pxW, dW1, Bt2, Bt_init, Bt_d1,
                                        x, x_bf, cond, pcW, pcb, cproj, attS, attD, uv);

  // initial h = [hid | x] @ [tW2 ; pxW] + biases + cproj
  mfma_gemm<192,128,1,false><<<gemm_gx, 256, 0, stream>>>(xl_bf /*hid*/, x_bf, Bt_init, tb2, pxb, cproj, h_bf, nullptr, nullptr, nullptr, nullptr);

  // GAT layers; layer-0 gemm also computes the layer-0 attention dots from staged h.
  // Logit buffers double-buffered across layers (cross-block race avoidance).
  float* asrc_in = a_src0; float* adst_in = a_dst0;
  float* asrc_out = a_src1; float* adst_out = a_dst1;
  for (int l = 0; l < 3; l++){
    if (l == 0){
      mfma_gemm<128,256,0,true><<<gemm_gx, 256, 0, stream>>>(h_bf, nullptr, Bt2, nullptr, nullptr, nullptr, xl_bf, hres_bf, uv, asrc_in, adst_in);
    } else {
      mfma_gemm<128,256,0,false><<<gemm_gx, 256, 0, stream>>>(h_bf, nullptr, Bt2 + (size_t)l*32768, nullptr, nullptr, nullptr, xl_bf, hres_bf, nullptr, nullptr, nullptr);
    }
    if (l < 2){
      aggregate<true><<<grp_blocks, 256, 0, stream>>>(xl_bf, asrc_in, adst_in, hres_bf, gbias + l*128,
                                                      offsets, srt_src, h_bf, uv + (l+1)*256, asrc_out, adst_out);
      float* t0 = asrc_in; asrc_in = asrc_out; asrc_out = t0;
      float* t1 = adst_in; adst_in = adst_out; adst_out = t1;
    } else {
      aggregate<false><<<grp_blocks, 256, 0, stream>>>(xl_bf, asrc_in, adst_in, hres_bf, gbias + l*128,
                                                       offsets, srt_src, h_bf, nullptr, nullptr, nullptr);
    }
  }

  // head
  mfma_gemm<128,128,2,false><<<gemm_gx, 256, 0, stream>>>(h_bf, nullptr, Bt_d1, db1, nullptr, nullptr, xl_bf /*g*/, nullptr, nullptr, nullptr, nullptr);
  head2<<<grp_blocks, 256, 0, stream>>>(xl_bf /*g*/, dW2, db2, out);
}

// Round 11
// 387.570 us; speedup vs baseline: 3.8759x; 1.0570x over previous
//
#include <hip/hip_runtime.h>
#include <hip/hip_bf16.h>

#define N_NODES 50000
#define N_EDGES 600000
#define TOT_EDGES (N_EDGES + N_NODES)
#define NPB 1000     // nodes per cond row (N/B)
#define SCAN_BLK 49  // ceil(N_NODES/1024)
#define GEMM_GX 782  // (N_NODES+63)/64
#define CD_BLKS 586  // ceil(N_EDGES/4/256)

// prep_count block ranges (count blocks FIRST so atomics issue earliest)
#define PC_T0 (CD_BLKS + 1563)      // temb: (N+31)/32
#define PC_T1 (PC_T0 + 544)         // prep_weights: 139264/256
#define PC_T2 (PC_T1 + 3125)        // cvt_x: N*64/4/256
#define PC_T3 (PC_T2 + 25)          // cond_proj: 50*128/256
#define PC_T4 (PC_T3 + 3)           // attvec: 768/256  -> total grid

typedef __bf16 bf16x8 __attribute__((ext_vector_type(8)));
typedef float f32x4 __attribute__((ext_vector_type(4)));
typedef unsigned short u16x8 __attribute__((ext_vector_type(8)));

__device__ __forceinline__ float gelu_exact(float v){
  return 0.5f * v * (1.f + erff(v * 0.70710678118654752f));
}
__device__ __forceinline__ float silu(float v){
  return v / (1.f + expf(-v));
}
__device__ __forceinline__ unsigned short f2bf(float f){
  unsigned u = __builtin_bit_cast(unsigned, f);
  unsigned r = (u + 0x7FFFu + ((u >> 16) & 1u)) >> 16;
  return (unsigned short)r;
}
__device__ __forceinline__ float bf2f(unsigned short u){
  return __builtin_bit_cast(float, ((unsigned)u) << 16);
}

// ---------------- merged: count_deg (atomic histogram + rank) AND all prep work ----------------
__global__ __launch_bounds__(256) void prep_count(const int* __restrict__ adj,
                                                  int* __restrict__ counts,
                                                  int* __restrict__ rank,
                                                  const float* __restrict__ timesteps,
                                                  const float* __restrict__ fw,
                                                  const float* __restrict__ tW1,
                                                  const float* __restrict__ tb1,
                                                  unsigned short* __restrict__ hid,
                                                  const float* __restrict__ linW,
                                                  const float* __restrict__ resW,
                                                  const float* __restrict__ tW2,
                                                  const float* __restrict__ pxW,
                                                  const float* __restrict__ dW1,
                                                  unsigned short* __restrict__ Bt2,
                                                  unsigned short* __restrict__ Bt_init,
                                                  unsigned short* __restrict__ Bt_d1,
                                                  const float* __restrict__ x,
                                                  unsigned short* __restrict__ xbf,
                                                  const float* __restrict__ cond,
                                                  const float* __restrict__ pcW,
                                                  const float* __restrict__ pcb,
                                                  float* __restrict__ cproj,
                                                  const float* __restrict__ attS,
                                                  const float* __restrict__ attD,
                                                  float* __restrict__ uv){
  __shared__ float sfour[32][17];
  __shared__ float sW[17][128];
  const int bid = blockIdx.x, tid = threadIdx.x;

  if (bid < CD_BLKS){
    // ---- count_deg: 4 edges/thread, record arrival rank
    int t = bid*256 + tid;
    if (t < N_EDGES/4){
      int j4 = t*4;
      const int4 d4 = *(const int4*)&adj[N_EDGES + j4];
      int4 r4;
      r4.x = atomicAdd(&counts[d4.x], 1);
      r4.y = atomicAdd(&counts[d4.y], 1);
      r4.z = atomicAdd(&counts[d4.z], 1);
      r4.w = atomicAdd(&counts[d4.w], 1);
      *(int4*)&rank[j4] = r4;
    }
  } else if (bid < PC_T0){
    // ---- temb_hidden
    int row0 = (bid - CD_BLKS) * 32;
    if (tid < 32){
      int gr = row0 + tid;
      float t = (gr < N_NODES) ? timesteps[gr] : 0.f;
      sfour[tid][0] = t;
      #pragma unroll
      for (int q = 0; q < 8; q++){
        float f = t * fw[q] * 6.2831853071795864769f;
        float sv, cv;
        sincosf(f, &sv, &cv);
        sfour[tid][1+q] = sv;
        sfour[tid][9+q] = cv;
      }
    }
    for (int i = tid; i < 17*128; i += 256) sW[i>>7][i&127] = tW1[i];
    __syncthreads();
    int j = tid & 127, rg = tid >> 7;
    float b = tb1[j];
    #pragma unroll
    for (int r = 0; r < 16; r++){
      int row = rg*16 + r;
      float acc = b;
      #pragma unroll
      for (int k = 0; k < 17; k++) acc += sfour[row][k]*sW[k][j];
      int gr = row0 + row;
      if (gr < N_NODES) hid[gr*128 + j] = f2bf(silu(acc));
    }
  } else if (bid < PC_T1){
    // ---- prep_weights
    int idx = (bid - PC_T0)*256 + tid;
    if (idx < 98304){
      int j = idx >> 14, e = idx & 16383;
      int l = j >> 1, isres = j & 1;
      int k = e >> 7, c = e & 127;
      const float* src = (isres ? resW : linW) + l*16384;
      Bt2[(size_t)l*32768 + (size_t)(isres*128 + c)*128 + k] = f2bf(src[k*128 + c]);
    } else if (idx < 114688){
      int e = idx - 98304; int k = e >> 7, c = e & 127;
      Bt_init[c*192 + k] = f2bf(tW2[k*128 + c]);
    } else if (idx < 122880){
      int e = idx - 114688; int k = e >> 7, c = e & 127;
      Bt_init[c*192 + 128 + k] = f2bf(pxW[k*128 + c]);
    } else if (idx < 139264){
      int e = idx - 122880; int k = e >> 7, c = e & 127;
      Bt_d1[c*128 + k] = f2bf(dW1[k*128 + c]);
    }
  } else if (bid < PC_T2){
    // ---- cvt_x (float4 -> 4 bf16)
    int i = (bid - PC_T1)*256 + tid;   // < 800000 exactly
    float4 v = ((const float4*)x)[i];
    ushort4 o;
    o.x = f2bf(v.x); o.y = f2bf(v.y); o.z = f2bf(v.z); o.w = f2bf(v.w);
    *(ushort4*)&xbf[(size_t)i*4] = o;
  } else if (bid < PC_T3){
    // ---- cond_proj
    int g = (bid - PC_T2)*256 + tid;   // < 6400
    int b = g >> 7, j = g & 127;
    float acc = pcb[j];
    for (int k = 0; k < 32; k++) acc += cond[b*32+k]*pcW[k*128+j];
    cproj[b*128+j] = acc;
  } else {
    // ---- attvec
    int g = (bid - PC_T3)*256 + tid;   // < 768
    if (g < 768){
      int l = g >> 8, s = (g >> 7) & 1, k = g & 127;
      const float* att = s ? (attD + l*128) : (attS + l*128);
      const float* row = linW + (l*128 + k)*128;
      float acc = 0.f;
      for (int j = 0; j < 128; j++) acc += row[j]*att[j];
      uv[(l*2 + s)*128 + k] = acc;
    }
  }
}

// Per-node slot count = counts[i] + 1 (self loop).
__global__ __launch_bounds__(256) void scan_part(const int* __restrict__ counts, int* __restrict__ blksum){
  int tid = threadIdx.x;
  int base = blockIdx.x*1024 + tid*4;
  int s = 0;
  #pragma unroll
  for (int k = 0; k < 4; k++){ int idx = base+k; if (idx < N_NODES) s += counts[idx] + 1; }
  #pragma unroll
  for (int off = 1; off < 64; off <<= 1) s += __shfl_xor(s, off, 64);
  __shared__ int ws[4];
  int lane = tid & 63, wid = tid >> 6;
  if (lane == 0) ws[wid] = s;
  __syncthreads();
  if (tid == 0) blksum[blockIdx.x] = ws[0]+ws[1]+ws[2]+ws[3];
}

// Computes offsets AND writes the self-loop entry srt_src[offsets[i]] = i.
__global__ __launch_bounds__(256) void scan_final(const int* __restrict__ counts,
                                                  const int* __restrict__ blksum,
                                                  int* __restrict__ offsets,
                                                  int* __restrict__ srt_src){
  int tid = threadIdx.x; int lane = tid & 63, wid = tid >> 6;
  __shared__ int ws[4];
  __shared__ int sbase;
  int base = blockIdx.x*1024 + tid*4;
  int v[4]; int s = 0;
  #pragma unroll
  for (int k = 0; k < 4; k++){ int idx = base+k; v[k] = (idx < N_NODES) ? (counts[idx] + 1) : 0; s += v[k]; }
  int x = s;
  #pragma unroll
  for (int off = 1; off < 64; off <<= 1){
    int y = __shfl_up(x, off, 64);
    if (lane >= off) x += y;
  }
  if (lane == 63) ws[wid] = x;
  if (tid < 64){
    int bv = (tid < SCAN_BLK) ? blksum[tid] : 0;
    int bx = bv;
    #pragma unroll
    for (int off = 1; off < 64; off <<= 1){
      int y = __shfl_up(bx, off, 64);
      if (tid >= off) bx += y;
    }
    int basev = (blockIdx.x == 0) ? 0 : __shfl(bx, blockIdx.x - 1, 64);
    int total = __shfl(bx, SCAN_BLK - 1, 64);
    if (tid == 0){
      sbase = basev;
      if (blockIdx.x == SCAN_BLK-1) offsets[N_NODES] = total;
    }
  }
  __syncthreads();
  int run = sbase;
  for (int q = 0; q < wid; q++) run += ws[q];
  run += x - s;   // exclusive within wave
  #pragma unroll
  for (int k = 0; k < 4; k++){
    int idx = base+k;
    if (idx < N_NODES){
      offsets[idx] = run;
      srt_src[run] = idx;   // self-loop in slot 0 of the segment
    }
    run += v[k];
  }
}

// ---------------- MFMA GEMM: one block per 64-row tile, ALL NC cols ----------------
// A-frag: row=lane&15, k=(lane>>4)*8+i. B-frag same from B^T row = output col.
// D: col=lane&15, row=(lane>>4)*4+reg. A and B both LDS-staged with XOR swizzle.
// DOTS: blocks also compute a_src/a_dst for their 64 rows from the staged A tile.
// SCAT: blocks with blockIdx.x >= GEMM_GX perform the atomic-free edge scatter and exit.
// EPI=3 (fused head): g=gelu(acc+bias0); out=g@dW2+db2 with dW2 passed via `cproj`,
//   db2 via bias1, out via `fout` — per-row 16-lane shfl reduction, no g round-trip.
template<int KD, int NC, int EPI, bool DOTS, bool SCAT>
__global__ __launch_bounds__(256) void mfma_gemm(const unsigned short* __restrict__ A0,
                                                 const unsigned short* __restrict__ A1,
                                                 const unsigned short* __restrict__ Bt,
                                                 const float* __restrict__ bias0,
                                                 const float* __restrict__ bias1,
                                                 const float* __restrict__ cproj,
                                                 unsigned short* __restrict__ O0,
                                                 unsigned short* __restrict__ O1,
                                                 const float* __restrict__ uv_l,
                                                 float* __restrict__ a_srcO,
                                                 float* __restrict__ a_dstO,
                                                 float* __restrict__ fout,
                                                 const int* __restrict__ adj,
                                                 const int* __restrict__ rank,
                                                 const int* __restrict__ offsets,
                                                 int* __restrict__ srt_src){
  constexpr int CHR  = KD / 8;    // 16B chunks per row
  constexpr int ROWB = KD * 2;    // bytes per row
  constexpr int KS   = KD / 32;   // mfma k-steps
  constexpr int NT   = NC / 16;   // 16-col groups
  __shared__ alignas(16) char sA[64 * ROWB];
  __shared__ alignas(16) char sB[NC * ROWB];
  const int tid  = threadIdx.x;

  if constexpr (SCAT){
    if (blockIdx.x >= GEMM_GX){
      int t = (blockIdx.x - GEMM_GX)*256 + tid;
      if (t < N_EDGES/4){
        int j4 = t*4;
        const int4 s4 = *(const int4*)&adj[j4];
        const int4 d4 = *(const int4*)&adj[N_EDGES + j4];
        const int4 r4 = *(const int4*)&rank[j4];
        srt_src[offsets[d4.x] + 1 + r4.x] = s4.x;
        srt_src[offsets[d4.y] + 1 + r4.y] = s4.y;
        srt_src[offsets[d4.z] + 1 + r4.z] = s4.z;
        srt_src[offsets[d4.w] + 1 + r4.w] = s4.w;
      }
      return;   // uniform exit for the whole block
    }
  }

  const int m0   = blockIdx.x * 64;
  const int lane = tid & 63, w = tid >> 6;
  const int lr   = lane & 15, lk = lane >> 4;

  // stage A tile (64 rows x KD bf16)
  for (int i = tid; i < 64*CHR; i += 256){
    int r = i / CHR, ch = i % CHR;
    int grow = m0 + r;
    u16x8 v;
    #pragma unroll
    for (int q = 0; q < 8; q++) v[q] = 0;
    if (grow < N_NODES){
      if constexpr (KD == 128){
        v = *(const u16x8*)&A0[(size_t)grow*128 + ch*8];
      } else {
        if (ch < 16) v = *(const u16x8*)&A0[(size_t)grow*128 + ch*8];
        else         v = *(const u16x8*)&A1[(size_t)grow*64 + (ch-16)*8];
      }
    }
    *(u16x8*)&sA[r*ROWB + ((ch*16) ^ ((r & 7) << 4))] = v;
  }
  // stage B (NC rows x KD bf16), same swizzle
  for (int i = tid; i < NC*CHR; i += 256){
    int r = i / CHR, ch = i % CHR;
    u16x8 v = *(const u16x8*)&Bt[(size_t)r*KD + ch*8];
    *(u16x8*)&sB[r*ROWB + ((ch*16) ^ ((r & 7) << 4))] = v;
  }
  __syncthreads();

  // A-frags in registers for the whole block
  bf16x8 afr[KS];
  const int arow = w*16 + lr;
  #pragma unroll
  for (int ks = 0; ks < KS; ks++)
    afr[ks] = *(const bf16x8*)&sA[arow*ROWB + ((ks*64 + lk*16) ^ ((arow & 7) << 4))];

  f32x4 acc[NT];
  #pragma unroll
  for (int nt = 0; nt < NT; nt++)
    #pragma unroll
    for (int q = 0; q < 4; q++) acc[nt][q] = 0.f;

  #pragma unroll
  for (int nt = 0; nt < NT; nt++){
    const int brow = nt*16 + lr;
    #pragma unroll
    for (int ks = 0; ks < KS; ks++){
      bf16x8 b = *(const bf16x8*)&sB[brow*ROWB + ((ks*64 + lk*16) ^ ((brow & 7) << 4))];
      acc[nt] = __builtin_amdgcn_mfma_f32_16x16x32_bf16(afr[ks], b, acc[nt], 0, 0, 0);
    }
  }

  if constexpr (DOTS){
    // attention dots from the staged h tile: 4 lanes per row, 32 cols each
    int r = tid >> 2;
    int row = m0 + r;
    if (row < N_NODES){
      float ps = 0.f, pd = 0.f;
      #pragma unroll
      for (int cc = 0; cc < 4; cc++){
        int ch = (tid & 3)*4 + cc;
        u16x8 av = *(const u16x8*)&sA[r*ROWB + ((ch*16) ^ ((r & 7) << 4))];
        int c0 = ch*8;
        const float4 u0 = *(const float4*)&uv_l[c0];
        const float4 u1 = *(const float4*)&uv_l[c0+4];
        const float4 v0 = *(const float4*)&uv_l[128+c0];
        const float4 v1 = *(const float4*)&uv_l[128+c0+4];
        const float uu[8] = {u0.x,u0.y,u0.z,u0.w,u1.x,u1.y,u1.z,u1.w};
        const float vv[8] = {v0.x,v0.y,v0.z,v0.w,v1.x,v1.y,v1.z,v1.w};
        #pragma unroll
        for (int q = 0; q < 8; q++){
          float hv = bf2f(av[q]);
          ps += hv*uu[q];
          pd += hv*vv[q];
        }
      }
      ps += __shfl_xor(ps, 1, 64); ps += __shfl_xor(ps, 2, 64);
      pd += __shfl_xor(pd, 1, 64); pd += __shfl_xor(pd, 2, 64);
      if ((tid & 3) == 0){ a_srcO[row] = ps; a_dstO[row] = pd; }
    }
  }

  const int rbase = m0 + w*16 + lk*4;
  if constexpr (EPI < 3){
    #pragma unroll
    for (int nt = 0; nt < NT; nt++){
      int c = nt*16 + lr;
      #pragma unroll
      for (int rg = 0; rg < 4; rg++){
        int row = rbase + rg;
        if (row >= N_NODES) continue;
        float v = acc[nt][rg];
        if constexpr (EPI == 0){
          if (c < 128) O0[(size_t)row*128 + c]       = f2bf(v);
          else         O1[(size_t)row*128 + (c-128)] = f2bf(v);
        } else if constexpr (EPI == 1){
          v += bias0[c] + bias1[c] + cproj[(row/NPB)*128 + c];
          O0[(size_t)row*128 + c] = f2bf(v);
        } else {
          v = gelu_exact(v + bias0[c]);
          O0[(size_t)row*128 + c] = f2bf(v);
        }
      }
    }
  } else {
    // EPI==3: fused head. For row rbase+rg, all 128 cols live in the 16 lanes
    // sharing this lk (lane = lk*16+lr), 8 cols per lane (nt*16+lr).
    float p0[4] = {0.f,0.f,0.f,0.f}, p1[4] = {0.f,0.f,0.f,0.f};
    #pragma unroll
    for (int nt = 0; nt < NT; nt++){
      int c = nt*16 + lr;
      const float2 wv = *(const float2*)&cproj[c*2];   // dW2[c][0..1]
      #pragma unroll
      for (int rg = 0; rg < 4; rg++){
        float g = gelu_exact(acc[nt][rg] + bias0[c]);
        p0[rg] += g * wv.x;
        p1[rg] += g * wv.y;
      }
    }
    #pragma unroll
    for (int off = 1; off < 16; off <<= 1){
      #pragma unroll
      for (int rg = 0; rg < 4; rg++){
        p0[rg] += __shfl_xor(p0[rg], off, 64);
        p1[rg] += __shfl_xor(p1[rg], off, 64);
      }
    }
    if (lr == 0){
      float b0 = bias1[0], b1 = bias1[1];
      #pragma unroll
      for (int rg = 0; rg < 4; rg++){
        int row = rbase + rg;
        if (row < N_NODES){
          float2 o; o.x = p0[rg] + b0; o.y = p1[rg] + b1;
          *(float2*)&fout[row*2] = o;
        }
      }
    }
  }
}

// ---------------- GAT aggregation: 16-lane groups; optionally fuse next-layer dots ----------------
// NOTE: a_src_o/a_dst_o MUST NOT alias a_src/a_dst (cross-block race) — double-buffered by caller.
template<bool FUSE>
__global__ __launch_bounds__(256) void aggregate(const unsigned short* __restrict__ xl,
                                                 const float* __restrict__ a_src,
                                                 const float* __restrict__ a_dst,
                                                 const unsigned short* __restrict__ hres,
                                                 const float* __restrict__ gbias_l,
                                                 const int* __restrict__ offsets,
                                                 const int* __restrict__ srt_src,
                                                 unsigned short* __restrict__ h_out,
                                                 const float* __restrict__ uv_next,
                                                 float* __restrict__ a_src_o,
                                                 float* __restrict__ a_dst_o){
  const int tid  = threadIdx.x;
  const int lane = tid & 63;
  const int l16  = lane & 15;
  const int i    = blockIdx.x*16 + (tid >> 4);   // grid exactly N/16
  const int beg  = offsets[i];
  const int deg  = offsets[i+1] - beg;
  const float adst = a_dst[i];

  // ---- phase 1: online softmax stats over 16-edge chunks
  int   s0  = 0;
  float ev0 = -INFINITY;
  if (l16 < deg){
    s0 = srt_src[beg + l16];
    float t = a_src[s0] + adst;
    ev0 = (t > 0.f) ? t : 0.2f*t;
  }
  float m = ev0;
  #pragma unroll
  for (int off = 1; off < 16; off <<= 1) m = fmaxf(m, __shfl_xor(m, off, 64));
  float den = (l16 < deg) ? __expf(ev0 - m) : 0.f;
  #pragma unroll
  for (int off = 1; off < 16; off <<= 1) den += __shfl_xor(den, off, 64);
  for (int c0 = 16; c0 < deg; c0 += 16){
    float ev = -INFINITY;
    if (c0 + l16 < deg){
      int s = srt_src[beg + c0 + l16];
      float t = a_src[s] + adst;
      ev = (t > 0.f) ? t : 0.2f*t;
    }
    float cm = ev;
    #pragma unroll
    for (int off = 1; off < 16; off <<= 1) cm = fmaxf(cm, __shfl_xor(cm, off, 64));
    if (cm > m){ den *= __expf(m - cm); m = cm; }
    float wv = (c0 + l16 < deg) ? __expf(ev - m) : 0.f;
    #pragma unroll
    for (int off = 1; off < 16; off <<= 1) wv += __shfl_xor(wv, off, 64);
    den += wv;
  }
  const float inv = 1.f / den;
  float w0 = (l16 < deg) ? __expf(ev0 - m) * inv : 0.f;

  // ---- phase 2: weighted gather (alpha pre-folded into w)
  float acc[8];
  #pragma unroll
  for (int k = 0; k < 8; k++) acc[k] = 0.f;
  const int gbb = (lane & 48) << 2;   // group-base byte addr for bpermute

  int lim0 = deg < 16 ? deg : 16;
  for (int q = 0; q < lim0; q++){
    int addr = gbb + q*4;
    int s    = __builtin_amdgcn_ds_bpermute(addr, s0);
    float wq = __builtin_bit_cast(float, __builtin_amdgcn_ds_bpermute(addr, __builtin_bit_cast(int, w0)));
    const int4 xv = *(const int4*)&xl[((size_t)s << 7) + (l16 << 3)];
    const int xd[4] = {xv.x, xv.y, xv.z, xv.w};
    #pragma unroll
    for (int k = 0; k < 4; k++){
      acc[2*k]   += wq * __builtin_bit_cast(float, xd[k] << 16);
      acc[2*k+1] += wq * __builtin_bit_cast(float, xd[k] & 0xffff0000);
    }
  }
  for (int c0 = 16; c0 < deg; c0 += 16){
    int s1 = 0; float w1 = 0.f;
    if (c0 + l16 < deg){
      s1 = srt_src[beg + c0 + l16];
      float t = a_src[s1] + adst;
      float ev = (t > 0.f) ? t : 0.2f*t;
      w1 = __expf(ev - m) * inv;
    }
    int lim = deg - c0; if (lim > 16) lim = 16;
    for (int q = 0; q < lim; q++){
      int addr = gbb + q*4;
      int s    = __builtin_amdgcn_ds_bpermute(addr, s1);
      float wq = __builtin_bit_cast(float, __builtin_amdgcn_ds_bpermute(addr, __builtin_bit_cast(int, w1)));
      const int4 xv = *(const int4*)&xl[((size_t)s << 7) + (l16 << 3)];
      const int xd[4] = {xv.x, xv.y, xv.z, xv.w};
      #pragma unroll
      for (int k = 0; k < 4; k++){
        acc[2*k]   += wq * __builtin_bit_cast(float, xd[k] << 16);
        acc[2*k+1] += wq * __builtin_bit_cast(float, xd[k] & 0xffff0000);
      }
    }
  }

  // ---- epilogue: + gbias + hres, gelu, bf16 store; optionally next-layer dots
  const int4 hr = *(const int4*)&hres[((size_t)i << 7) + (l16 << 3)];
  const int hd[4] = {hr.x, hr.y, hr.z, hr.w};
  const float4 gb0 = *(const float4*)&gbias_l[l16*8];
  const float4 gb1 = *(const float4*)&gbias_l[l16*8 + 4];
  const float gbv[8] = {gb0.x, gb0.y, gb0.z, gb0.w, gb1.x, gb1.y, gb1.z, gb1.w};
  float uu[8], vv[8];
  if constexpr (FUSE){
    const float4 a0 = *(const float4*)&uv_next[l16*8];
    const float4 a1 = *(const float4*)&uv_next[l16*8 + 4];
    const float4 b0 = *(const float4*)&uv_next[128 + l16*8];
    const float4 b1 = *(const float4*)&uv_next[128 + l16*8 + 4];
    uu[0]=a0.x; uu[1]=a0.y; uu[2]=a0.z; uu[3]=a0.w; uu[4]=a1.x; uu[5]=a1.y; uu[6]=a1.z; uu[7]=a1.w;
    vv[0]=b0.x; vv[1]=b0.y; vv[2]=b0.z; vv[3]=b0.w; vv[4]=b1.x; vv[5]=b1.y; vv[6]=b1.z; vv[7]=b1.w;
  }
  float ps = 0.f, pd = 0.f;
  int od[4];
  #pragma unroll
  for (int k = 0; k < 4; k++){
    float r0 = acc[2*k]   + gbv[2*k]   + __builtin_bit_cast(float, hd[k] << 16);
    float r1 = acc[2*k+1] + gbv[2*k+1] + __builtin_bit_cast(float, hd[k] & 0xffff0000);
    float g0 = gelu_exact(r0);
    float g1 = gelu_exact(r1);
    if constexpr (FUSE){
      ps += g0*uu[2*k] + g1*uu[2*k+1];
      pd += g0*vv[2*k] + g1*vv[2*k+1];
    }
    unsigned lo = f2bf(g0);
    unsigned hi = f2bf(g1);
    od[k] = (int)(lo | (hi << 16));
  }
  *(int4*)&h_out[((size_t)i << 7) + (l16 << 3)] = make_int4(od[0], od[1], od[2], od[3]);
  if constexpr (FUSE){
    #pragma unroll
    for (int off = 1; off < 16; off <<= 1){
      ps += __shfl_xor(ps, off, 64);
      pd += __shfl_xor(pd, off, 64);
    }
    if (l16 == 0){ a_src_o[i] = ps; a_dst_o[i] = pd; }
  }
}

extern "C" void kernel_launch(void* const* d_in, const int* in_sizes, int n_in,
                              void* d_out, int out_size, void* d_ws, size_t ws_size,
                              hipStream_t stream) {
  const float* x   = (const float*)d_in[0];
  const int*   adj = (const int*)  d_in[1];
  const float* timesteps = (const float*)d_in[3];
  const float* cond = (const float*)d_in[4];
  const float* fw   = (const float*)d_in[5];
  const float* tW1  = (const float*)d_in[6];
  const float* tb1  = (const float*)d_in[7];
  const float* tW2  = (const float*)d_in[8];
  const float* tb2  = (const float*)d_in[9];
  const float* pxW  = (const float*)d_in[10];
  const float* pxb  = (const float*)d_in[11];
  const float* pcW  = (const float*)d_in[12];
  const float* pcb  = (const float*)d_in[13];
  const float* linW = (const float*)d_in[14];
  const float* attS = (const float*)d_in[15];
  const float* attD = (const float*)d_in[16];
  const float* gbias= (const float*)d_in[17];
  const float* resW = (const float*)d_in[18];
  const float* dW1  = (const float*)d_in[19];
  const float* db1  = (const float*)d_in[20];
  const float* dW2  = (const float*)d_in[21];
  const float* db2  = (const float*)d_in[22];
  float* out = (float*)d_out;

  char* w = (char*)d_ws;
  size_t off = 0;
  auto carve = [&](size_t bytes) -> void* {
    void* p = w + off;
    off = (off + bytes + 255) & ~(size_t)255;
    return p;
  };
  unsigned short* h_bf    = (unsigned short*)carve((size_t)N_NODES*128*2);
  unsigned short* xl_bf   = (unsigned short*)carve((size_t)N_NODES*128*2); // also hid_bf
  unsigned short* hres_bf = (unsigned short*)carve((size_t)N_NODES*128*2);
  unsigned short* x_bf    = (unsigned short*)carve((size_t)N_NODES*64*2);
  float* a_src0 = (float*)carve((size_t)N_NODES*4);
  float* a_dst0 = (float*)carve((size_t)N_NODES*4);
  float* a_src1 = (float*)carve((size_t)N_NODES*4);
  float* a_dst1 = (float*)carve((size_t)N_NODES*4);
  float* cproj = (float*)carve(50*128*4);
  float* uv    = (float*)carve(6*128*4);
  int* counts  = (int*)carve((size_t)N_NODES*4);
  int* rank    = (int*)carve((size_t)N_EDGES*4);
  int* offsets = (int*)carve((size_t)(N_NODES+1)*4);
  int* srt_src = (int*)carve((size_t)TOT_EDGES*4);
  int* blksum  = (int*)carve(SCAN_BLK*4);
  unsigned short* Bt2     = (unsigned short*)carve((size_t)3*256*128*2);
  unsigned short* Bt_init = (unsigned short*)carve((size_t)128*192*2);
  unsigned short* Bt_d1   = (unsigned short*)carve((size_t)128*128*2);
  (void)ws_size; (void)in_sizes; (void)n_in; (void)out_size;

  const int grp_blocks = N_NODES/16;   // 3125

  // counts must start zeroed for the atomic histogram
  hipMemsetAsync(counts, 0, (size_t)N_NODES*4, stream);

  // merged: count_deg (first 586 blocks) + temb/weights/cvt_x/cond_proj/attvec
  prep_count<<<PC_T4, 256, 0, stream>>>(adj, counts, rank,
                                        timesteps, fw, tW1, tb1, xl_bf /*hid*/,
                                        linW, resW, tW2, pxW, dW1, Bt2, Bt_init, Bt_d1,
                                        x, x_bf, cond, pcW, pcb, cproj, attS, attD, uv);

  // scan (+1 self-loop slot per node; scan_final also writes the self-loop entries)
  scan_part<<<SCAN_BLK, 256, 0, stream>>>(counts, blksum);
  scan_final<<<SCAN_BLK, 256, 0, stream>>>(counts, blksum, offsets, srt_src);

  // init h = [hid | x] @ [tW2 ; pxW] + biases + cproj  (+ scatter blocks appended)
  mfma_gemm<192,128,1,false,true><<<GEMM_GX + CD_BLKS, 256, 0, stream>>>(
      xl_bf /*hid*/, x_bf, Bt_init, tb2, pxb, cproj, h_bf, nullptr,
      nullptr, nullptr, nullptr, nullptr, adj, rank, offsets, srt_src);

  // GAT layers; layer-0 gemm also computes the layer-0 attention dots from staged h.
  // Logit buffers double-buffered across layers (cross-block race avoidance).
  float* asrc_in = a_src0; float* adst_in = a_dst0;
  float* asrc_out = a_src1; float* adst_out = a_dst1;
  for (int l = 0; l < 3; l++){
    if (l == 0){
      mfma_gemm<128,256,0,true,false><<<GEMM_GX, 256, 0, stream>>>(
          h_bf, nullptr, Bt2, nullptr, nullptr, nullptr, xl_bf, hres_bf,
          uv, asrc_in, adst_in, nullptr, nullptr, nullptr, nullptr, nullptr);
    } else {
      mfma_gemm<128,256,0,false,false><<<GEMM_GX, 256, 0, stream>>>(
          h_bf, nullptr, Bt2 + (size_t)l*32768, nullptr, nullptr, nullptr, xl_bf, hres_bf,
          nullptr, nullptr, nullptr, nullptr, nullptr, nullptr, nullptr, nullptr);
    }
    if (l < 2){
      aggregate<true><<<grp_blocks, 256, 0, stream>>>(xl_bf, asrc_in, adst_in, hres_bf, gbias + l*128,
                                                      offsets, srt_src, h_bf, uv + (l+1)*256, asrc_out, adst_out);
      float* t0 = asrc_in; asrc_in = asrc_out; asrc_out = t0;
      float* t1 = adst_in; adst_in = adst_out; adst_out = t1;
    } else {
      aggregate<false><<<grp_blocks, 256, 0, stream>>>(xl_bf, asrc_in, adst_in, hres_bf, gbias + l*128,
                                                       offsets, srt_src, h_bf, nullptr, nullptr, nullptr);
    }
  }

  // fused head: out = gelu(h@dW1+db1) @ dW2 + db2   (dW2 via cproj slot, db2 via bias1)
  mfma_gemm<128,128,3,false,false><<<GEMM_GX, 256, 0, stream>>>(
      h_bf, nullptr, Bt_d1, db1, db2, dW2, nullptr, nullptr,
      nullptr, nullptr, nullptr, out, nullptr, nullptr, nullptr, nullptr);
}

// Round 12
// 380.980 us; speedup vs baseline: 3.9429x; 1.0173x over previous
//
#include <hip/hip_runtime.h>
#include <hip/hip_bf16.h>

#define N_NODES 50000
#define N_EDGES 600000
#define TOT_EDGES (N_EDGES + N_NODES)
#define NPB 1000     // nodes per cond row (N/B)
#define SCAN_BLK 49  // ceil(N_NODES/1024)
#define GEMM_GX 782  // (N_NODES+63)/64
#define CD_BLKS 586  // ceil(N_EDGES/4/256)

// prep_count block ranges (count blocks FIRST so atomics issue earliest)
#define PC_T0 (CD_BLKS + 1563)      // temb: (N+31)/32
#define PC_T1 (PC_T0 + 544)         // prep_weights: 139264/256
#define PC_T2 (PC_T1 + 3125)        // cvt_x: N*64/4/256
#define PC_T3 (PC_T2 + 25)          // cond_proj: 50*128/256
#define PC_T4 (PC_T3 + 3)           // attvec: 768/256  -> total grid

typedef __bf16 bf16x8 __attribute__((ext_vector_type(8)));
typedef float f32x4 __attribute__((ext_vector_type(4)));
typedef unsigned short u16x8 __attribute__((ext_vector_type(8)));

__device__ __forceinline__ float gelu_exact(float v){
  return 0.5f * v * (1.f + erff(v * 0.70710678118654752f));
}
__device__ __forceinline__ float silu(float v){
  return v / (1.f + expf(-v));
}
__device__ __forceinline__ unsigned short f2bf(float f){
  unsigned u = __builtin_bit_cast(unsigned, f);
  unsigned r = (u + 0x7FFFu + ((u >> 16) & 1u)) >> 16;
  return (unsigned short)r;
}
__device__ __forceinline__ float bf2f(unsigned short u){
  return __builtin_bit_cast(float, ((unsigned)u) << 16);
}

// ---------------- merged: count_deg (atomic histogram + rank) AND all prep work ----------------
__global__ __launch_bounds__(256) void prep_count(const int* __restrict__ adj,
                                                  int* __restrict__ counts,
                                                  int* __restrict__ rank,
                                                  const float* __restrict__ timesteps,
                                                  const float* __restrict__ fw,
                                                  const float* __restrict__ tW1,
                                                  const float* __restrict__ tb1,
                                                  unsigned short* __restrict__ hid,
                                                  const float* __restrict__ linW,
                                                  const float* __restrict__ resW,
                                                  const float* __restrict__ tW2,
                                                  const float* __restrict__ pxW,
                                                  const float* __restrict__ dW1,
                                                  unsigned short* __restrict__ Bt2,
                                                  unsigned short* __restrict__ Bt_init,
                                                  unsigned short* __restrict__ Bt_d1,
                                                  const float* __restrict__ x,
                                                  unsigned short* __restrict__ xbf,
                                                  const float* __restrict__ cond,
                                                  const float* __restrict__ pcW,
                                                  const float* __restrict__ pcb,
                                                  float* __restrict__ cproj,
                                                  const float* __restrict__ attS,
                                                  const float* __restrict__ attD,
                                                  float* __restrict__ uv){
  __shared__ float sfour[32][17];
  __shared__ float sW[17][128];
  const int bid = blockIdx.x, tid = threadIdx.x;

  if (bid < CD_BLKS){
    // ---- count_deg: 4 edges/thread, record arrival rank
    int t = bid*256 + tid;
    if (t < N_EDGES/4){
      int j4 = t*4;
      const int4 d4 = *(const int4*)&adj[N_EDGES + j4];
      int4 r4;
      r4.x = atomicAdd(&counts[d4.x], 1);
      r4.y = atomicAdd(&counts[d4.y], 1);
      r4.z = atomicAdd(&counts[d4.z], 1);
      r4.w = atomicAdd(&counts[d4.w], 1);
      *(int4*)&rank[j4] = r4;
    }
  } else if (bid < PC_T0){
    // ---- temb_hidden
    int row0 = (bid - CD_BLKS) * 32;
    if (tid < 32){
      int gr = row0 + tid;
      float t = (gr < N_NODES) ? timesteps[gr] : 0.f;
      sfour[tid][0] = t;
      #pragma unroll
      for (int q = 0; q < 8; q++){
        float f = t * fw[q] * 6.2831853071795864769f;
        float sv, cv;
        sincosf(f, &sv, &cv);
        sfour[tid][1+q] = sv;
        sfour[tid][9+q] = cv;
      }
    }
    for (int i = tid; i < 17*128; i += 256) sW[i>>7][i&127] = tW1[i];
    __syncthreads();
    int j = tid & 127, rg = tid >> 7;
    float b = tb1[j];
    #pragma unroll
    for (int r = 0; r < 16; r++){
      int row = rg*16 + r;
      float acc = b;
      #pragma unroll
      for (int k = 0; k < 17; k++) acc += sfour[row][k]*sW[k][j];
      int gr = row0 + row;
      if (gr < N_NODES) hid[gr*128 + j] = f2bf(silu(acc));
    }
  } else if (bid < PC_T1){
    // ---- prep_weights
    int idx = (bid - PC_T0)*256 + tid;
    if (idx < 98304){
      int j = idx >> 14, e = idx & 16383;
      int l = j >> 1, isres = j & 1;
      int k = e >> 7, c = e & 127;
      const float* src = (isres ? resW : linW) + l*16384;
      Bt2[(size_t)l*32768 + (size_t)(isres*128 + c)*128 + k] = f2bf(src[k*128 + c]);
    } else if (idx < 114688){
      int e = idx - 98304; int k = e >> 7, c = e & 127;
      Bt_init[c*192 + k] = f2bf(tW2[k*128 + c]);
    } else if (idx < 122880){
      int e = idx - 114688; int k = e >> 7, c = e & 127;
      Bt_init[c*192 + 128 + k] = f2bf(pxW[k*128 + c]);
    } else if (idx < 139264){
      int e = idx - 122880; int k = e >> 7, c = e & 127;
      Bt_d1[c*128 + k] = f2bf(dW1[k*128 + c]);
    }
  } else if (bid < PC_T2){
    // ---- cvt_x (float4 -> 4 bf16)
    int i = (bid - PC_T1)*256 + tid;   // < 800000 exactly
    float4 v = ((const float4*)x)[i];
    ushort4 o;
    o.x = f2bf(v.x); o.y = f2bf(v.y); o.z = f2bf(v.z); o.w = f2bf(v.w);
    *(ushort4*)&xbf[(size_t)i*4] = o;
  } else if (bid < PC_T3){
    // ---- cond_proj
    int g = (bid - PC_T2)*256 + tid;   // < 6400
    int b = g >> 7, j = g & 127;
    float acc = pcb[j];
    for (int k = 0; k < 32; k++) acc += cond[b*32+k]*pcW[k*128+j];
    cproj[b*128+j] = acc;
  } else {
    // ---- attvec
    int g = (bid - PC_T3)*256 + tid;   // < 768
    if (g < 768){
      int l = g >> 8, s = (g >> 7) & 1, k = g & 127;
      const float* att = s ? (attD + l*128) : (attS + l*128);
      const float* row = linW + (l*128 + k)*128;
      float acc = 0.f;
      for (int j = 0; j < 128; j++) acc += row[j]*att[j];
      uv[(l*2 + s)*128 + k] = acc;
    }
  }
}

// Per-node slot count = counts[i] + 1 (self loop).
__global__ __launch_bounds__(256) void scan_part(const int* __restrict__ counts, int* __restrict__ blksum){
  int tid = threadIdx.x;
  int base = blockIdx.x*1024 + tid*4;
  int s = 0;
  #pragma unroll
  for (int k = 0; k < 4; k++){ int idx = base+k; if (idx < N_NODES) s += counts[idx] + 1; }
  #pragma unroll
  for (int off = 1; off < 64; off <<= 1) s += __shfl_xor(s, off, 64);
  __shared__ int ws[4];
  int lane = tid & 63, wid = tid >> 6;
  if (lane == 0) ws[wid] = s;
  __syncthreads();
  if (tid == 0) blksum[blockIdx.x] = ws[0]+ws[1]+ws[2]+ws[3];
}

// Computes offsets AND writes the self-loop entry srt_src[offsets[i]] = i.
__global__ __launch_bounds__(256) void scan_final(const int* __restrict__ counts,
                                                  const int* __restrict__ blksum,
                                                  int* __restrict__ offsets,
                                                  int* __restrict__ srt_src){
  int tid = threadIdx.x; int lane = tid & 63, wid = tid >> 6;
  __shared__ int ws[4];
  __shared__ int sbase;
  int base = blockIdx.x*1024 + tid*4;
  int v[4]; int s = 0;
  #pragma unroll
  for (int k = 0; k < 4; k++){ int idx = base+k; v[k] = (idx < N_NODES) ? (counts[idx] + 1) : 0; s += v[k]; }
  int x = s;
  #pragma unroll
  for (int off = 1; off < 64; off <<= 1){
    int y = __shfl_up(x, off, 64);
    if (lane >= off) x += y;
  }
  if (lane == 63) ws[wid] = x;
  if (tid < 64){
    int bv = (tid < SCAN_BLK) ? blksum[tid] : 0;
    int bx = bv;
    #pragma unroll
    for (int off = 1; off < 64; off <<= 1){
      int y = __shfl_up(bx, off, 64);
      if (tid >= off) bx += y;
    }
    int basev = (blockIdx.x == 0) ? 0 : __shfl(bx, blockIdx.x - 1, 64);
    int total = __shfl(bx, SCAN_BLK - 1, 64);
    if (tid == 0){
      sbase = basev;
      if (blockIdx.x == SCAN_BLK-1) offsets[N_NODES] = total;
    }
  }
  __syncthreads();
  int run = sbase;
  for (int q = 0; q < wid; q++) run += ws[q];
  run += x - s;   // exclusive within wave
  #pragma unroll
  for (int k = 0; k < 4; k++){
    int idx = base+k;
    if (idx < N_NODES){
      offsets[idx] = run;
      srt_src[run] = idx;   // self-loop in slot 0 of the segment
    }
    run += v[k];
  }
}

// ---------------- MFMA GEMM: one block per 64-row tile, ALL NC cols ----------------
// A-frag: row=lane&15, k=(lane>>4)*8+i. B-frag same from B^T row = output col.
// D: col=lane&15, row=(lane>>4)*4+reg. A and B both LDS-staged with XOR swizzle.
// DOTS: blocks also compute a_src/a_dst for their 64 rows from the staged A tile.
// SCAT: blocks with blockIdx.x >= GEMM_GX perform the atomic-free edge scatter and exit.
// EPI=3 (fused head): g=gelu(acc+bias0); out=g@dW2+db2 with dW2 passed via `cproj`,
//   db2 via bias1, out via `fout` — per-row 16-lane shfl reduction, no g round-trip.
template<int KD, int NC, int EPI, bool DOTS, bool SCAT>
__global__ __launch_bounds__(256) void mfma_gemm(const unsigned short* __restrict__ A0,
                                                 const unsigned short* __restrict__ A1,
                                                 const unsigned short* __restrict__ Bt,
                                                 const float* __restrict__ bias0,
                                                 const float* __restrict__ bias1,
                                                 const float* __restrict__ cproj,
                                                 unsigned short* __restrict__ O0,
                                                 unsigned short* __restrict__ O1,
                                                 const float* __restrict__ uv_l,
                                                 float* __restrict__ a_srcO,
                                                 float* __restrict__ a_dstO,
                                                 float* __restrict__ fout,
                                                 const int* __restrict__ adj,
                                                 const int* __restrict__ rank,
                                                 const int* __restrict__ offsets,
                                                 int* __restrict__ srt_src){
  constexpr int CHR  = KD / 8;    // 16B chunks per row
  constexpr int ROWB = KD * 2;    // bytes per row
  constexpr int KS   = KD / 32;   // mfma k-steps
  constexpr int NT   = NC / 16;   // 16-col groups
  __shared__ alignas(16) char sA[64 * ROWB];
  __shared__ alignas(16) char sB[NC * ROWB];
  const int tid  = threadIdx.x;

  if constexpr (SCAT){
    if (blockIdx.x >= GEMM_GX){
      int t = (blockIdx.x - GEMM_GX)*256 + tid;
      if (t < N_EDGES/4){
        int j4 = t*4;
        const int4 s4 = *(const int4*)&adj[j4];
        const int4 d4 = *(const int4*)&adj[N_EDGES + j4];
        const int4 r4 = *(const int4*)&rank[j4];
        srt_src[offsets[d4.x] + 1 + r4.x] = s4.x;
        srt_src[offsets[d4.y] + 1 + r4.y] = s4.y;
        srt_src[offsets[d4.z] + 1 + r4.z] = s4.z;
        srt_src[offsets[d4.w] + 1 + r4.w] = s4.w;
      }
      return;   // uniform exit for the whole block
    }
  }

  const int m0   = blockIdx.x * 64;
  const int lane = tid & 63, w = tid >> 6;
  const int lr   = lane & 15, lk = lane >> 4;

  // stage A tile (64 rows x KD bf16)
  for (int i = tid; i < 64*CHR; i += 256){
    int r = i / CHR, ch = i % CHR;
    int grow = m0 + r;
    u16x8 v;
    #pragma unroll
    for (int q = 0; q < 8; q++) v[q] = 0;
    if (grow < N_NODES){
      if constexpr (KD == 128){
        v = *(const u16x8*)&A0[(size_t)grow*128 + ch*8];
      } else {
        if (ch < 16) v = *(const u16x8*)&A0[(size_t)grow*128 + ch*8];
        else         v = *(const u16x8*)&A1[(size_t)grow*64 + (ch-16)*8];
      }
    }
    *(u16x8*)&sA[r*ROWB + ((ch*16) ^ ((r & 7) << 4))] = v;
  }
  // stage B (NC rows x KD bf16), same swizzle
  for (int i = tid; i < NC*CHR; i += 256){
    int r = i / CHR, ch = i % CHR;
    u16x8 v = *(const u16x8*)&Bt[(size_t)r*KD + ch*8];
    *(u16x8*)&sB[r*ROWB + ((ch*16) ^ ((r & 7) << 4))] = v;
  }
  __syncthreads();

  // A-frags in registers for the whole block
  bf16x8 afr[KS];
  const int arow = w*16 + lr;
  #pragma unroll
  for (int ks = 0; ks < KS; ks++)
    afr[ks] = *(const bf16x8*)&sA[arow*ROWB + ((ks*64 + lk*16) ^ ((arow & 7) << 4))];

  f32x4 acc[NT];
  #pragma unroll
  for (int nt = 0; nt < NT; nt++)
    #pragma unroll
    for (int q = 0; q < 4; q++) acc[nt][q] = 0.f;

  #pragma unroll
  for (int nt = 0; nt < NT; nt++){
    const int brow = nt*16 + lr;
    #pragma unroll
    for (int ks = 0; ks < KS; ks++){
      bf16x8 b = *(const bf16x8*)&sB[brow*ROWB + ((ks*64 + lk*16) ^ ((brow & 7) << 4))];
      acc[nt] = __builtin_amdgcn_mfma_f32_16x16x32_bf16(afr[ks], b, acc[nt], 0, 0, 0);
    }
  }

  if constexpr (DOTS){
    // attention dots from the staged h tile: 4 lanes per row, 32 cols each
    int r = tid >> 2;
    int row = m0 + r;
    if (row < N_NODES){
      float ps = 0.f, pd = 0.f;
      #pragma unroll
      for (int cc = 0; cc < 4; cc++){
        int ch = (tid & 3)*4 + cc;
        u16x8 av = *(const u16x8*)&sA[r*ROWB + ((ch*16) ^ ((r & 7) << 4))];
        int c0 = ch*8;
        const float4 u0 = *(const float4*)&uv_l[c0];
        const float4 u1 = *(const float4*)&uv_l[c0+4];
        const float4 v0 = *(const float4*)&uv_l[128+c0];
        const float4 v1 = *(const float4*)&uv_l[128+c0+4];
        const float uu[8] = {u0.x,u0.y,u0.z,u0.w,u1.x,u1.y,u1.z,u1.w};
        const float vv[8] = {v0.x,v0.y,v0.z,v0.w,v1.x,v1.y,v1.z,v1.w};
        #pragma unroll
        for (int q = 0; q < 8; q++){
          float hv = bf2f(av[q]);
          ps += hv*uu[q];
          pd += hv*vv[q];
        }
      }
      ps += __shfl_xor(ps, 1, 64); ps += __shfl_xor(ps, 2, 64);
      pd += __shfl_xor(pd, 1, 64); pd += __shfl_xor(pd, 2, 64);
      if ((tid & 3) == 0){ a_srcO[row] = ps; a_dstO[row] = pd; }
    }
  }

  const int rbase = m0 + w*16 + lk*4;
  if constexpr (EPI < 3){
    #pragma unroll
    for (int nt = 0; nt < NT; nt++){
      int c = nt*16 + lr;
      #pragma unroll
      for (int rg = 0; rg < 4; rg++){
        int row = rbase + rg;
        if (row >= N_NODES) continue;
        float v = acc[nt][rg];
        if constexpr (EPI == 0){
          if (c < 128) O0[(size_t)row*128 + c]       = f2bf(v);
          else         O1[(size_t)row*128 + (c-128)] = f2bf(v);
        } else if constexpr (EPI == 1){
          v += bias0[c] + bias1[c] + cproj[(row/NPB)*128 + c];
          O0[(size_t)row*128 + c] = f2bf(v);
        } else {
          v = gelu_exact(v + bias0[c]);
          O0[(size_t)row*128 + c] = f2bf(v);
        }
      }
    }
  } else {
    // EPI==3: fused head. For row rbase+rg, all 128 cols live in the 16 lanes
    // sharing this lk (lane = lk*16+lr), 8 cols per lane (nt*16+lr).
    float p0[4] = {0.f,0.f,0.f,0.f}, p1[4] = {0.f,0.f,0.f,0.f};
    #pragma unroll
    for (int nt = 0; nt < NT; nt++){
      int c = nt*16 + lr;
      const float2 wv = *(const float2*)&cproj[c*2];   // dW2[c][0..1]
      #pragma unroll
      for (int rg = 0; rg < 4; rg++){
        float g = gelu_exact(acc[nt][rg] + bias0[c]);
        p0[rg] += g * wv.x;
        p1[rg] += g * wv.y;
      }
    }
    #pragma unroll
    for (int off = 1; off < 16; off <<= 1){
      #pragma unroll
      for (int rg = 0; rg < 4; rg++){
        p0[rg] += __shfl_xor(p0[rg], off, 64);
        p1[rg] += __shfl_xor(p1[rg], off, 64);
      }
    }
    if (lr == 0){
      float b0 = bias1[0], b1 = bias1[1];
      #pragma unroll
      for (int rg = 0; rg < 4; rg++){
        int row = rbase + rg;
        if (row < N_NODES){
          float2 o; o.x = p0[rg] + b0; o.y = p1[rg] + b1;
          *(float2*)&fout[row*2] = o;
        }
      }
    }
  }
}

// one gathered edge: broadcast {src,weight} from lane-register via bpermute, 16B gather, 8 FMAs
#define GATH(ADDR, SREG, WREG, ACC) do { \
  int s_ = __builtin_amdgcn_ds_bpermute((ADDR), (SREG)); \
  float w_ = __builtin_bit_cast(float, __builtin_amdgcn_ds_bpermute((ADDR), __builtin_bit_cast(int, (WREG)))); \
  const int4 xv_ = *(const int4*)&xl[((size_t)s_ << 7) + (l16 << 3)]; \
  const int xd_[4] = {xv_.x, xv_.y, xv_.z, xv_.w}; \
  _Pragma("unroll") \
  for (int k_ = 0; k_ < 4; k_++){ \
    ACC[2*k_]   += w_ * __builtin_bit_cast(float, xd_[k_] << 16); \
    ACC[2*k_+1] += w_ * __builtin_bit_cast(float, xd_[k_] & 0xffff0000); \
  } \
} while(0)

// ---------------- GAT aggregation: 16-lane groups; optionally fuse next-layer dots ----------------
// Phase 2 is 2x unrolled (dual accumulators) to double gather MLP.
// NOTE: a_src_o/a_dst_o MUST NOT alias a_src/a_dst (cross-block race) — double-buffered by caller.
template<bool FUSE>
__global__ __launch_bounds__(256) void aggregate(const unsigned short* __restrict__ xl,
                                                 const float* __restrict__ a_src,
                                                 const float* __restrict__ a_dst,
                                                 const unsigned short* __restrict__ hres,
                                                 const float* __restrict__ gbias_l,
                                                 const int* __restrict__ offsets,
                                                 const int* __restrict__ srt_src,
                                                 unsigned short* __restrict__ h_out,
                                                 const float* __restrict__ uv_next,
                                                 float* __restrict__ a_src_o,
                                                 float* __restrict__ a_dst_o){
  const int tid  = threadIdx.x;
  const int lane = tid & 63;
  const int l16  = lane & 15;
  const int i    = blockIdx.x*16 + (tid >> 4);   // grid exactly N/16
  const int beg  = offsets[i];
  const int deg  = offsets[i+1] - beg;
  const float adst = a_dst[i];

  // ---- phase 1: online softmax stats over 16-edge chunks
  int   s0  = 0;
  float ev0 = -INFINITY;
  if (l16 < deg){
    s0 = srt_src[beg + l16];
    float t = a_src[s0] + adst;
    ev0 = (t > 0.f) ? t : 0.2f*t;
  }
  float m = ev0;
  #pragma unroll
  for (int off = 1; off < 16; off <<= 1) m = fmaxf(m, __shfl_xor(m, off, 64));
  float den = (l16 < deg) ? __expf(ev0 - m) : 0.f;
  #pragma unroll
  for (int off = 1; off < 16; off <<= 1) den += __shfl_xor(den, off, 64);
  for (int c0 = 16; c0 < deg; c0 += 16){
    float ev = -INFINITY;
    if (c0 + l16 < deg){
      int s = srt_src[beg + c0 + l16];
      float t = a_src[s] + adst;
      ev = (t > 0.f) ? t : 0.2f*t;
    }
    float cm = ev;
    #pragma unroll
    for (int off = 1; off < 16; off <<= 1) cm = fmaxf(cm, __shfl_xor(cm, off, 64));
    if (cm > m){ den *= __expf(m - cm); m = cm; }
    float wv = (c0 + l16 < deg) ? __expf(ev - m) : 0.f;
    #pragma unroll
    for (int off = 1; off < 16; off <<= 1) wv += __shfl_xor(wv, off, 64);
    den += wv;
  }
  const float inv = 1.f / den;
  float w0 = (l16 < deg) ? __expf(ev0 - m) * inv : 0.f;

  // ---- phase 2: weighted gather, 2x unrolled with dual accumulators
  float accA[8], accB[8];
  #pragma unroll
  for (int k = 0; k < 8; k++){ accA[k] = 0.f; accB[k] = 0.f; }
  const int gbb = (lane & 48) << 2;   // group-base byte addr for bpermute

  int lim0 = deg < 16 ? deg : 16;
  {
    int q = 0;
    for (; q + 2 <= lim0; q += 2){
      GATH(gbb + q*4,     s0, w0, accA);
      GATH(gbb + q*4 + 4, s0, w0, accB);
    }
    if (q < lim0) GATH(gbb + q*4, s0, w0, accA);
  }
  for (int c0 = 16; c0 < deg; c0 += 16){
    int s1 = 0; float w1 = 0.f;
    if (c0 + l16 < deg){
      s1 = srt_src[beg + c0 + l16];
      float t = a_src[s1] + adst;
      float ev = (t > 0.f) ? t : 0.2f*t;
      w1 = __expf(ev - m) * inv;
    }
    int lim = deg - c0; if (lim > 16) lim = 16;
    int q = 0;
    for (; q + 2 <= lim; q += 2){
      GATH(gbb + q*4,     s1, w1, accA);
      GATH(gbb + q*4 + 4, s1, w1, accB);
    }
    if (q < lim) GATH(gbb + q*4, s1, w1, accA);
  }
  float acc[8];
  #pragma unroll
  for (int k = 0; k < 8; k++) acc[k] = accA[k] + accB[k];

  // ---- epilogue: + gbias + hres, gelu, bf16 store; optionally next-layer dots
  const int4 hr = *(const int4*)&hres[((size_t)i << 7) + (l16 << 3)];
  const int hd[4] = {hr.x, hr.y, hr.z, hr.w};
  const float4 gb0 = *(const float4*)&gbias_l[l16*8];
  const float4 gb1 = *(const float4*)&gbias_l[l16*8 + 4];
  const float gbv[8] = {gb0.x, gb0.y, gb0.z, gb0.w, gb1.x, gb1.y, gb1.z, gb1.w};
  float uu[8], vv[8];
  if constexpr (FUSE){
    const float4 a0 = *(const float4*)&uv_next[l16*8];
    const float4 a1 = *(const float4*)&uv_next[l16*8 + 4];
    const float4 b0 = *(const float4*)&uv_next[128 + l16*8];
    const float4 b1 = *(const float4*)&uv_next[128 + l16*8 + 4];
    uu[0]=a0.x; uu[1]=a0.y; uu[2]=a0.z; uu[3]=a0.w; uu[4]=a1.x; uu[5]=a1.y; uu[6]=a1.z; uu[7]=a1.w;
    vv[0]=b0.x; vv[1]=b0.y; vv[2]=b0.z; vv[3]=b0.w; vv[4]=b1.x; vv[5]=b1.y; vv[6]=b1.z; vv[7]=b1.w;
  }
  float ps = 0.f, pd = 0.f;
  int od[4];
  #pragma unroll
  for (int k = 0; k < 4; k++){
    float r0 = acc[2*k]   + gbv[2*k]   + __builtin_bit_cast(float, hd[k] << 16);
    float r1 = acc[2*k+1] + gbv[2*k+1] + __builtin_bit_cast(float, hd[k] & 0xffff0000);
    float g0 = gelu_exact(r0);
    float g1 = gelu_exact(r1);
    if constexpr (FUSE){
      ps += g0*uu[2*k] + g1*uu[2*k+1];
      pd += g0*vv[2*k] + g1*vv[2*k+1];
    }
    unsigned lo = f2bf(g0);
    unsigned hi = f2bf(g1);
    od[k] = (int)(lo | (hi << 16));
  }
  *(int4*)&h_out[((size_t)i << 7) + (l16 << 3)] = make_int4(od[0], od[1], od[2], od[3]);
  if constexpr (FUSE){
    #pragma unroll
    for (int off = 1; off < 16; off <<= 1){
      ps += __shfl_xor(ps, off, 64);
      pd += __shfl_xor(pd, off, 64);
    }
    if (l16 == 0){ a_src_o[i] = ps; a_dst_o[i] = pd; }
  }
}

extern "C" void kernel_launch(void* const* d_in, const int* in_sizes, int n_in,
                              void* d_out, int out_size, void* d_ws, size_t ws_size,
                              hipStream_t stream) {
  const float* x   = (const float*)d_in[0];
  const int*   adj = (const int*)  d_in[1];
  const float* timesteps = (const float*)d_in[3];
  const float* cond = (const float*)d_in[4];
  const float* fw   = (const float*)d_in[5];
  const float* tW1  = (const float*)d_in[6];
  const float* tb1  = (const float*)d_in[7];
  const float* tW2  = (const float*)d_in[8];
  const float* tb2  = (const float*)d_in[9];
  const float* pxW  = (const float*)d_in[10];
  const float* pxb  = (const float*)d_in[11];
  const float* pcW  = (const float*)d_in[12];
  const float* pcb  = (const float*)d_in[13];
  const float* linW = (const float*)d_in[14];
  const float* attS = (const float*)d_in[15];
  const float* attD = (const float*)d_in[16];
  const float* gbias= (const float*)d_in[17];
  const float* resW = (const float*)d_in[18];
  const float* dW1  = (const float*)d_in[19];
  const float* db1  = (const float*)d_in[20];
  const float* dW2  = (const float*)d_in[21];
  const float* db2  = (const float*)d_in[22];
  float* out = (float*)d_out;

  char* w = (char*)d_ws;
  size_t off = 0;
  auto carve = [&](size_t bytes) -> void* {
    void* p = w + off;
    off = (off + bytes + 255) & ~(size_t)255;
    return p;
  };
  unsigned short* h_bf    = (unsigned short*)carve((size_t)N_NODES*128*2);
  unsigned short* xl_bf   = (unsigned short*)carve((size_t)N_NODES*128*2); // also hid_bf
  unsigned short* hres_bf = (unsigned short*)carve((size_t)N_NODES*128*2);
  unsigned short* x_bf    = (unsigned short*)carve((size_t)N_NODES*64*2);
  float* a_src0 = (float*)carve((size_t)N_NODES*4);
  float* a_dst0 = (float*)carve((size_t)N_NODES*4);
  float* a_src1 = (float*)carve((size_t)N_NODES*4);
  float* a_dst1 = (float*)carve((size_t)N_NODES*4);
  float* cproj = (float*)carve(50*128*4);
  float* uv    = (float*)carve(6*128*4);
  int* counts  = (int*)carve((size_t)N_NODES*4);
  int* rank    = (int*)carve((size_t)N_EDGES*4);
  int* offsets = (int*)carve((size_t)(N_NODES+1)*4);
  int* srt_src = (int*)carve((size_t)TOT_EDGES*4);
  int* blksum  = (int*)carve(SCAN_BLK*4);
  unsigned short* Bt2     = (unsigned short*)carve((size_t)3*256*128*2);
  unsigned short* Bt_init = (unsigned short*)carve((size_t)128*192*2);
  unsigned short* Bt_d1   = (unsigned short*)carve((size_t)128*128*2);
  (void)ws_size; (void)in_sizes; (void)n_in; (void)out_size;

  const int grp_blocks = N_NODES/16;   // 3125

  // counts must start zeroed for the atomic histogram
  hipMemsetAsync(counts, 0, (size_t)N_NODES*4, stream);

  // merged: count_deg (first 586 blocks) + temb/weights/cvt_x/cond_proj/attvec
  prep_count<<<PC_T4, 256, 0, stream>>>(adj, counts, rank,
                                        timesteps, fw, tW1, tb1, xl_bf /*hid*/,
                                        linW, resW, tW2, pxW, dW1, Bt2, Bt_init, Bt_d1,
                                        x, x_bf, cond, pcW, pcb, cproj, attS, attD, uv);

  // scan (+1 self-loop slot per node; scan_final also writes the self-loop entries)
  scan_part<<<SCAN_BLK, 256, 0, stream>>>(counts, blksum);
  scan_final<<<SCAN_BLK, 256, 0, stream>>>(counts, blksum, offsets, srt_src);

  // init h = [hid | x] @ [tW2 ; pxW] + biases + cproj  (+ scatter blocks appended)
  mfma_gemm<192,128,1,false,true><<<GEMM_GX + CD_BLKS, 256, 0, stream>>>(
      xl_bf /*hid*/, x_bf, Bt_init, tb2, pxb, cproj, h_bf, nullptr,
      nullptr, nullptr, nullptr, nullptr, adj, rank, offsets, srt_src);

  // GAT layers; layer-0 gemm also computes the layer-0 attention dots from staged h.
  // Logit buffers double-buffered across layers (cross-block race avoidance).
  float* asrc_in = a_src0; float* adst_in = a_dst0;
  float* asrc_out = a_src1; float* adst_out = a_dst1;
  for (int l = 0; l < 3; l++){
    if (l == 0){
      mfma_gemm<128,256,0,true,false><<<GEMM_GX, 256, 0, stream>>>(
          h_bf, nullptr, Bt2, nullptr, nullptr, nullptr, xl_bf, hres_bf,
          uv, asrc_in, adst_in, nullptr, nullptr, nullptr, nullptr, nullptr);
    } else {
      mfma_gemm<128,256,0,false,false><<<GEMM_GX, 256, 0, stream>>>(
          h_bf, nullptr, Bt2 + (size_t)l*32768, nullptr, nullptr, nullptr, xl_bf, hres_bf,
          nullptr, nullptr, nullptr, nullptr, nullptr, nullptr, nullptr, nullptr);
    }
    if (l < 2){
      aggregate<true><<<grp_blocks, 256, 0, stream>>>(xl_bf, asrc_in, adst_in, hres_bf, gbias + l*128,
                                                      offsets, srt_src, h_bf, uv + (l+1)*256, asrc_out, adst_out);
      float* t0 = asrc_in; asrc_in = asrc_out; asrc_out = t0;
      float* t1 = adst_in; adst_in = adst_out; adst_out = t1;
    } else {
      aggregate<false><<<grp_blocks, 256, 0, stream>>>(xl_bf, asrc_in, adst_in, hres_bf, gbias + l*128,
                                                       offsets, srt_src, h_bf, nullptr, nullptr, nullptr);
    }
  }

  // fused head: out = gelu(h@dW1+db1) @ dW2 + db2   (dW2 via cproj slot, db2 via bias1)
  mfma_gemm<128,128,3,false,false><<<GEMM_GX, 256, 0, stream>>>(
      h_bf, nullptr, Bt_d1, db1, db2, dW2, nullptr, nullptr,
      nullptr, nullptr, nullptr, out, nullptr, nullptr, nullptr, nullptr);
}